// Round 1
// 1476.835 us; speedup vs baseline: 4.7033x; 4.7033x over previous
//
#include <hip/hip_runtime.h>
#include <hip/hip_bf16.h>

typedef __hip_bfloat16 bf16;
using short8 = __attribute__((ext_vector_type(8))) short;
using f32x4  = __attribute__((ext_vector_type(4))) float;

__device__ __forceinline__ float b2f(bf16 v){ return __bfloat162float(v); }
__device__ __forceinline__ bf16  f2b(float v){ return __float2bfloat16(v); }

#define EPSV 1e-5f

// async global->LDS, 16B/lane, dest = wave-uniform base + lane*16
__device__ __forceinline__ void gload16(const void* g, void* l) {
  __builtin_amdgcn_global_load_lds(
      (const __attribute__((address_space(1))) unsigned int*)g,
      (__attribute__((address_space(3))) unsigned int*)l, 16, 0, 0);
}

// ===== weight reshape: w [OC=512][CI][3][3] f32 -> WT [9][512][CI] bf16 ====
__global__ __launch_bounds__(256) void k_wtr(const float* __restrict__ w,
                                             bf16* __restrict__ wt, int CI) {
  int oc = blockIdx.x, c0 = blockIdx.y * 128;
  __shared__ float ld[128 * 9];
  const float* src = w + ((size_t)oc * CI + c0) * 9;
  for (int i = threadIdx.x; i < 128 * 9; i += 256) ld[i] = src[i];
  __syncthreads();
  for (int i = threadIdx.x; i < 128 * 9; i += 256) {
    int k9 = i / 128, t = i - k9 * 128;
    wt[((size_t)k9 * 512 + oc) * CI + c0 + t] = f2b(ld[t * 9 + k9]);
  }
}

// ===== M1 NCHW f32 -> NHWC bf16 [4][64][64][2048] (fast path only) =========
__global__ __launch_bounds__(256) void k_m1t(const float* __restrict__ M1,
                                             bf16* __restrict__ M1b) {
  int b = blockIdx.x >> 6, y = blockIdx.x & 63;
  int c0 = blockIdx.y * 64;
  __shared__ float t[64][65];
  for (int i = threadIdx.x; i < 4096; i += 256) {
    int cc = i >> 6, x = i & 63;
    t[x][cc] = M1[((size_t)(b * 2048 + c0 + cc) * 64 + y) * 64 + x];
  }
  __syncthreads();
  for (int i = threadIdx.x; i < 4096; i += 256) {
    int x = i >> 6, cc = i & 63;
    M1b[((size_t)((b * 64 + y) * 64 + x)) * 2048 + c0 + cc] = f2b(t[x][cc]);
  }
}

// ===== R2-proven: F (NCHW f32) -> FP (b,p,n,c) bf16 ========================
__global__ __launch_bounds__(256) void k_fp(const float* __restrict__ F,
                                            bf16* __restrict__ FP) {
  int bp = blockIdx.x, b = bp >> 6, p = bp & 63;
  int py = (p >> 3) * 8, px = (p & 7) * 8;
  for (int i = threadIdx.x; i < 64 * 512; i += 256) {
    int n = i >> 9, c = i & 511;
    int y = py + (n >> 3), x = px + (n & 7);
    FP[(size_t)bp * 32768 + i] = f2b(F[((size_t)(b * 512 + c) * 64 + y) * 64 + x]);
  }
}

// ===== R2-proven: softmax(I) ; F_l0 = bc * pix @ Fp ========================
__global__ __launch_bounds__(256) void k_flocal(const float* __restrict__ I,
        const float* __restrict__ R, const bf16* __restrict__ FP,
        float* __restrict__ FL0) {
  int bp = blockIdx.x, b = bp >> 6, p = bp & 63;
  int tid = threadIdx.x;
  __shared__ float pix[19][64];
  __shared__ float bc[19];
  int py = (p >> 3) * 8, px = (p & 7) * 8;
  for (int i = tid; i < 19 * 64; i += 256) {
    int k = i >> 6, n = i & 63;
    int y = py + (n >> 3), x = px + (n & 7);
    pix[k][n] = I[((size_t)(b * 19 + k) * 64 + y) * 64 + x];
  }
  if (tid < 19) bc[tid] = R[(size_t)(b * 19 + tid) * 64 + p];
  __syncthreads();
  if (tid < 19) {
    float mx = -1e30f;
    for (int n = 0; n < 64; n++) mx = fmaxf(mx, pix[tid][n]);
    float s = 0.f;
    for (int n = 0; n < 64; n++) { float e = __expf(pix[tid][n] - mx); pix[tid][n] = e; s += e; }
    float inv = 1.f / s;
    for (int n = 0; n < 64; n++) pix[tid][n] *= inv;
  }
  __syncthreads();
  for (int i = tid; i < 19 * 512; i += 256) {
    int k = i >> 9, c = i & 511;
    const bf16* fp = FP + (size_t)bp * 32768 + c;
    float s = 0.f;
    for (int n = 0; n < 64; n++) s += pix[k][n] * b2f(fp[n << 9]);
    FL0[((size_t)(b * 64 + p) * 19 + k) * 512 + c] = s * bc[k];
  }
}

// ===== R2-proven: LG part 1 ================================================
__global__ __launch_bounds__(256) void k_lg1(const float* __restrict__ FL0,
        const float* __restrict__ w1, float* __restrict__ H) {
  int tid = threadIdx.x;
  int b = blockIdx.y;
  int n0 = blockIdx.x * 256;
  __shared__ float W[64][64];
  __shared__ float Xs[16][256];
  for (int i = tid; i < 4096; i += 256) W[i >> 6][i & 63] = w1[i];
  float acc[64];
  #pragma unroll
  for (int po = 0; po < 64; po++) acc[po] = 0.f;
  for (int q0 = 0; q0 < 64; q0 += 16) {
    __syncthreads();
    for (int i = tid; i < 4096; i += 256) {
      int q = i >> 8, j = i & 255;
      Xs[q][j] = FL0[(size_t)(b * 64 + q0 + q) * 9728 + n0 + j];
    }
    __syncthreads();
    for (int q = 0; q < 16; q++) {
      float xv = Xs[q][tid];
      #pragma unroll
      for (int po = 0; po < 64; po++) acc[po] += W[po][q0 + q] * xv;
    }
  }
  for (int po = 0; po < 64; po++) {
    float r = acc[po] + FL0[(size_t)(b * 64 + po) * 9728 + n0 + tid];
    H[(size_t)(b * 64 + po) * 9728 + n0 + tid] = fmaxf(r, 0.f);
  }
}

// ===== R2-proven: generic GEMM C = A @ W^T (+bias) =========================
template<bool ABF16, bool BIAS>
__global__ __launch_bounds__(256) void k_gemm_wt(const void* __restrict__ A_,
        const float* __restrict__ W, const float* __restrict__ bias,
        float* __restrict__ C, int Kd, int Nn) {
  int tid = threadIdx.x;
  int m0 = blockIdx.x * 64, n0 = blockIdx.y * 64;
  int tx = tid & 15, ty = tid >> 4;
  __shared__ __align__(16) float As[32][68];
  __shared__ __align__(16) float Bs[32][68];
  float acc[4][4] = {};
  for (int k0 = 0; k0 < Kd; k0 += 32) {
    for (int i = tid; i < 2048; i += 256) {
      int m = i >> 5, kk = i & 31;
      float v;
      if (ABF16) v = b2f(((const bf16*)A_)[(size_t)(m0 + m) * Kd + k0 + kk]);
      else       v = ((const float*)A_)[(size_t)(m0 + m) * Kd + k0 + kk];
      As[kk][m] = v;
    }
    for (int i = tid; i < 2048; i += 256) {
      int n = i >> 5, kk = i & 31;
      Bs[kk][n] = W[(size_t)(n0 + n) * Kd + k0 + kk];
    }
    __syncthreads();
    #pragma unroll
    for (int kk = 0; kk < 32; kk++) {
      float a[4], bv[4];
      *(float4*)a  = *(const float4*)&As[kk][ty * 4];
      *(float4*)bv = *(const float4*)&Bs[kk][tx * 4];
      #pragma unroll
      for (int ii = 0; ii < 4; ii++)
        #pragma unroll
        for (int jj = 0; jj < 4; jj++)
          acc[ii][jj] += a[ii] * bv[jj];
    }
    __syncthreads();
  }
  for (int ii = 0; ii < 4; ii++) {
    int m = m0 + ty * 4 + ii;
    float ov[4];
    #pragma unroll
    for (int jj = 0; jj < 4; jj++) {
      float v = acc[ii][jj];
      if (BIAS) v += bias[n0 + tx * 4 + jj];
      ov[jj] = v;
    }
    *(float4*)&C[(size_t)m * Nn + n0 + tx * 4] = *(float4*)ov;
  }
}

// ===== R2-proven: fuse + value =============================================
__global__ __launch_bounds__(256) void k_fusev(const float* __restrict__ FL,
        const float* __restrict__ fw, const float* __restrict__ fbv,
        const float* __restrict__ vw, const float* __restrict__ vb,
        float* __restrict__ VAL) {
  int tid = threadIdx.x;
  int bk = blockIdx.x, b = bk / 19, k = bk % 19;
  __shared__ float fwl[64];
  __shared__ float fg[512];
  if (tid < 64) fwl[tid] = fw[tid];
  __syncthreads();
  float fbias = fbv[0];
  for (int c = tid; c < 512; c += 256) {
    float s = 0.f;
    for (int p = 0; p < 64; p++)
      s += fwl[p] * FL[((size_t)(b * 64 + p) * 19 + k) * 512 + c];
    fg[c] = s + fbias;
  }
  __syncthreads();
  int d = tid;
  float s = vb[d];
  for (int c = 0; c < 512; c++) s += fg[c] * vw[(size_t)d * 512 + c];
  VAL[(size_t)bk * 256 + d] = s;
}

// ===== R2-proven: per-patch attention -> FS NHWC bf16 (C=256) ==============
__global__ __launch_bounds__(256) void k_attn(const float* __restrict__ Q,
        const float* __restrict__ KEY, const float* __restrict__ VAL,
        bf16* __restrict__ FS) {
  int tid = threadIdx.x;
  int bp = blockIdx.x, b = bp >> 6, p = bp & 63;
  __shared__ float ks[19][256];
  __shared__ float vs[19][256];
  __shared__ float Ss[64][20];
  for (int i = tid; i < 19 * 256; i += 256) {
    ks[i >> 8][i & 255] = KEY[(size_t)bp * 19 * 256 + i];
    vs[i >> 8][i & 255] = VAL[(size_t)b * 19 * 256 + i];
  }
  __syncthreads();
  {
    int n = tid >> 2, kq = tid & 3;
    const float* qrow = Q + ((size_t)bp * 64 + n) * 256;
    for (int k = kq; k < 19; k += 4) {
      float s = 0.f;
      for (int d = 0; d < 256; d++) s += qrow[d] * ks[k][d];
      Ss[n][k] = s;
    }
  }
  __syncthreads();
  if (tid < 64) {
    float mx = -1e30f;
    for (int k = 0; k < 19; k++) mx = fmaxf(mx, Ss[tid][k]);
    float sum = 0.f;
    for (int k = 0; k < 19; k++) { float e = __expf(Ss[tid][k] - mx); Ss[tid][k] = e; sum += e; }
    float inv = 1.f / sum;
    for (int k = 0; k < 19; k++) Ss[tid][k] *= inv;
  }
  __syncthreads();
  {
    int d = tid;
    int py = (p >> 3) * 8, px = (p & 7) * 8;
    for (int nn = 0; nn < 64; nn++) {
      float s = 0.f;
      #pragma unroll
      for (int k = 0; k < 19; k++) s += Ss[nn][k] * vs[k][d];
      int y = py + (nn >> 3), x = px + (nn & 7);
      FS[(((size_t)(b * 64 + y) * 64) + x) * 256 + d] = f2b(s);
    }
  }
}

// ===== conv1x1 256->512 + BN + ReLU + residual F ; out NHWC bf16 ===========
__global__ __launch_bounds__(256) void k_conv1(const bf16* __restrict__ FSi,
        const float* __restrict__ w, const float* __restrict__ g,
        const float* __restrict__ bb, const float* __restrict__ F,
        bf16* __restrict__ out) {
  int tid = threadIdx.x;
  int b = blockIdx.x >> 6, y = blockIdx.x & 63;
  int oc0 = blockIdx.y * 64;
  int tx = tid & 15, ty = tid >> 4;
  __shared__ __align__(16) float As[32][68];
  __shared__ __align__(16) float Bs[32][68];
  float acc[4][4] = {};
  for (int c0 = 0; c0 < 256; c0 += 32) {
    for (int i = tid; i < 2048; i += 256) {
      int oc = i >> 5, kk = i & 31;
      As[kk][oc] = w[(size_t)(oc0 + oc) * 256 + c0 + kk];
    }
    for (int i = tid; i < 2048; i += 256) {
      int x = i >> 5, kk = i & 31;
      Bs[kk][x] = b2f(FSi[(((size_t)(b * 64 + y) * 64) + x) * 256 + c0 + kk]);
    }
    __syncthreads();
    #pragma unroll
    for (int kk = 0; kk < 32; kk++) {
      float a[4], bv[4];
      *(float4*)a  = *(const float4*)&As[kk][ty * 4];
      *(float4*)bv = *(const float4*)&Bs[kk][tx * 4];
      #pragma unroll
      for (int ii = 0; ii < 4; ii++)
        #pragma unroll
        for (int jj = 0; jj < 4; jj++)
          acc[ii][jj] += a[ii] * bv[jj];
    }
    __syncthreads();
  }
  // epilogue via LDS transpose -> coalesced NHWC stores
  __syncthreads();
  bf16* EP = (bf16*)As;   // [64 x][64 ocl] = 8KB
  #pragma unroll
  for (int ii = 0; ii < 4; ii++) {
    int oc = oc0 + ty * 4 + ii;
    float sc = g[oc] * rsqrtf(1.f + EPSV);
    float bt = bb[oc];
    #pragma unroll
    for (int jj = 0; jj < 4; jj++) {
      int x = tx * 4 + jj;
      float v = fmaxf(acc[ii][jj] * sc + bt, 0.f)
              + F[((size_t)(b * 512 + oc) * 64 + y) * 64 + x];
      EP[x * 64 + ty * 4 + ii] = f2b(v);
    }
  }
  __syncthreads();
  int x = tid >> 2, q = tid & 3;
  size_t gb = (((size_t)(b * 64 + y) * 64) + x) * 512 + oc0 + q * 16;
  *(short8*)&out[gb]     = *(const short8*)&EP[x * 64 + q * 16];
  *(short8*)&out[gb + 8] = *(const short8*)&EP[x * 64 + q * 16 + 8];
}

// ===== NEW: MFMA conv3x3 pad1, NHWC in/out, global_load_lds staging ========
// block = 128oc x 64x x 2y ; 4 waves, wave = 64oc x 64x (4x4 of 16x16x32).
// A: WT [9][512][Ct] staged per-ky (3 kx) into double-buffered [3][128][32].
// B: 4 input rows (y halo) staged once per c0 into [4][66][32], x halo
//    rows 0/65 zeroed once. Per-lane SOURCE chunk-XOR swizzle makes the
//    stride-64B ds_read_b128 fragment reads full-bank-coverage (no conflicts).
__global__ __launch_bounds__(256) void k_conv3(
    const bf16* __restrict__ Xin, int Cin,
    const bf16* __restrict__ M1b, const float* __restrict__ M1f, int C2,
    const bf16* __restrict__ WT,
    const float* __restrict__ g, const float* __restrict__ bb,
    bf16* __restrict__ out, int Cos) {
  int tid = threadIdx.x;
  int b = blockIdx.x >> 5, y0 = (blockIdx.x & 31) * 2;
  int oc0 = blockIdx.y * 128;
  int w = tid >> 6, lane = tid & 63, ln = lane & 15, qd = lane >> 4;
  int wocg = w & 1, wy = w >> 1;
  int Ct = Cin + C2;

  __shared__ __align__(16) char smem[2 * 24576 + 16896];
  char* smA = smem;            // Aw[2][3][128][32] bf16, rows of 64B
  char* smB = smem + 49152;    // Bs[4][66][32] bf16, rows of 64B

  // zero x-halo rows (xr = 0, 65) once
  {
    int ryy = tid >> 6, hh = (tid >> 5) & 1, kk = tid & 31;
    *(bf16*)(smB + ((ryy * 66 + (hh ? 65 : 0)) * 64) + kk * 2) = f2b(0.f);
  }

  f32x4 acc[4][4];
  #pragma unroll
  for (int i = 0; i < 4; i++)
    #pragma unroll
    for (int j = 0; j < 4; j++) acc[i][j] = (f32x4){0.f, 0.f, 0.f, 0.f};

  int NPH = (Ct >> 5) * 3;

  auto stageA = [&](int p) {
    int c0 = (p / 3) << 5, ky = p % 3;
    char* base = smA + (p & 1) * 24576;
    int j = w;
    #pragma unroll
    for (int t = 0; t < 6; t++, j += 4) {
      int kx = j >> 3, i8 = j & 7;
      int ocl = i8 * 16 + (lane >> 2);
      const bf16* src = WT + ((size_t)((ky * 3 + kx) * 512 + oc0 + ocl) * Ct + c0)
                      + (((lane & 3) ^ (ocl & 3)) << 3);
      gload16(src, base + (kx * 128 + i8 * 16) * 64);
    }
  };
  auto stageB = [&](int gi) {
    int c0 = gi << 5;
    if (c0 < Cin || M1b != nullptr) {
      const bf16* T; int Cs, cb;
      if (c0 < Cin) { T = Xin; Cs = Cin; cb = c0; }
      else          { T = M1b; Cs = C2;  cb = c0 - Cin; }
      int j = w;
      #pragma unroll
      for (int t = 0; t < 4; t++, j += 4) {
        int ryy = j >> 2, i4 = j & 3;
        int yy = y0 + ryy - 1;
        if ((unsigned)yy < 64u) {
          int xx = i4 * 16 + (lane >> 2), xr = xx + 1;
          const bf16* src = T + ((size_t)((b * 64 + yy) * 64 + xx) * Cs + cb)
                          + (((lane & 3) ^ (xr & 3)) << 3);
          gload16(src, smB + ((ryy * 66 + 1 + i4 * 16) * 64));
        }
      }
    } else {
      // slow fallback: transpose M1 f32 NCHW in-register (ws too small for M1b)
      int ryy = w, yy = y0 + ryy - 1;
      if ((unsigned)yy < 64u) {
        int xx = lane, xr = xx + 1;
        const float* mp = M1f + ((size_t)(b * 2048 + (c0 - Cin)) * 64 + yy) * 64 + xx;
        #pragma unroll
        for (int q = 0; q < 8; q++) {
          union { ushort4 u; bf16 h[4]; } pk;
          #pragma unroll
          for (int jj = 0; jj < 4; jj++) pk.h[jj] = f2b(mp[(size_t)(q * 4 + jj) * 4096]);
          *(ushort4*)(smB + ((ryy * 66 + xr) * 64)
                      + ((((q >> 1) ^ (xr & 3)) << 4) | ((q & 1) << 3))) = pk.u;
        }
      }
    }
  };
  auto computeP = [&](int p) {
    int ky = p % 3;
    int yyw = y0 + wy + ky - 1;
    if ((unsigned)yyw >= 64u) return;
    const char* base = smA + (p & 1) * 24576;
    #pragma unroll
    for (int kx = 0; kx < 3; kx++) {
      short8 af[4], bv[4];
      #pragma unroll
      for (int mi = 0; mi < 4; mi++) {
        int ocl = wocg * 64 + mi * 16 + ln;
        af[mi] = *(const short8*)(base + (kx * 128 + ocl) * 64 + ((qd ^ (ln & 3)) << 4));
      }
      #pragma unroll
      for (int ni = 0; ni < 4; ni++) {
        int xr = ni * 16 + ln + kx;
        bv[ni] = *(const short8*)(smB + ((wy + ky) * 66 + xr) * 64 + ((qd ^ (xr & 3)) << 4));
      }
      #pragma unroll
      for (int mi = 0; mi < 4; mi++)
        #pragma unroll
        for (int ni = 0; ni < 4; ni++)
          acc[mi][ni] = __builtin_amdgcn_mfma_f32_16x16x32_bf16(af[mi], bv[ni], acc[mi][ni], 0, 0, 0);
    }
  };

  stageB(0);
  stageA(0);
  __syncthreads();
  for (int p = 0; p < NPH; p++) {
    if (p + 1 < NPH && (p + 1) % 3 != 0) stageA(p + 1);   // prefetch under compute
    computeP(p);
    __syncthreads();
    if (p + 1 < NPH && (p + 1) % 3 == 0) {                // c0 boundary: restage B
      stageA(p + 1);
      stageB((p + 1) / 3);
      __syncthreads();
    }
  }

  // epilogue: BN+ReLU, LDS transpose -> coalesced NHWC stores
  {
    bf16* EP = (bf16*)smem;   // [2 wy][64 x][128 ocl]
    #pragma unroll
    for (int mi = 0; mi < 4; mi++) {
      int oclb = wocg * 64 + mi * 16 + qd * 4;
      float sc[4], bt[4];
      #pragma unroll
      for (int r = 0; r < 4; r++) {
        int oc = oc0 + oclb + r;
        sc[r] = g[oc] * rsqrtf(1.f + EPSV);
        bt[r] = bb[oc];
      }
      #pragma unroll
      for (int ni = 0; ni < 4; ni++) {
        int x = ni * 16 + ln;
        union { ushort4 u; bf16 h[4]; } pk;
        #pragma unroll
        for (int r = 0; r < 4; r++)
          pk.h[r] = f2b(fmaxf(acc[mi][ni][r] * sc[r] + bt[r], 0.f));
        *(ushort4*)&EP[(wy * 64 + x) * 128 + oclb] = pk.u;
      }
    }
    __syncthreads();
    int p2 = tid >> 1, hh = tid & 1;
    int wy2 = p2 >> 6, x = p2 & 63;
    size_t gb = ((size_t)((b * 64 + y0 + wy2) * 64 + x)) * Cos + oc0 + hh * 64;
    const bf16* row = &EP[p2 * 128 + hh * 64];
    #pragma unroll
    for (int k = 0; k < 8; k++)
      *(short8*)(out + gb + k * 8) = *(const short8*)(row + k * 8);
  }
}

// ===== final 1x1 (512->19) from NHWC X3 ====================================
__global__ __launch_bounds__(256) void k_final(const bf16* __restrict__ X3,
        const float* __restrict__ dw, float* __restrict__ out) {
  int tid = threadIdx.x;
  int b = blockIdx.x >> 6, y = blockIdx.x & 63;
  __shared__ float W[19 * 512];
  for (int i = tid; i < 19 * 512; i += 256) W[i] = dw[i];
  __syncthreads();
  int x = tid & 63, kg = tid >> 6;
  const bf16* px = X3 + (((size_t)(b * 64 + y) * 64) + x) * 512;
  float acc[5] = {0.f, 0.f, 0.f, 0.f, 0.f};
  for (int c8 = 0; c8 < 512; c8 += 8) {
    union { short8 s; bf16 h[8]; } v;
    v.s = *(const short8*)(px + c8);
    float f[8];
    #pragma unroll
    for (int j = 0; j < 8; j++) f[j] = b2f(v.h[j]);
    #pragma unroll
    for (int i = 0; i < 5; i++) {
      int k = kg * 5 + i;
      if (k < 19) {
        const float* wr = &W[k * 512 + c8];
        #pragma unroll
        for (int j = 0; j < 8; j++) acc[i] += f[j] * wr[j];
      }
    }
  }
  for (int i = 0; i < 5; i++) {
    int k = kg * 5 + i;
    if (k < 19) out[((size_t)(b * 19 + k) * 64 + y) * 64 + x] = acc[i];
  }
}

extern "C" void kernel_launch(void* const* d_in, const int* in_sizes, int n_in,
                              void* d_out, int out_size, void* d_ws, size_t ws_size,
                              hipStream_t stream) {
  (void)in_sizes; (void)n_in; (void)out_size;
  const float* M1 = (const float*)d_in[0];
  const float* F  = (const float*)d_in[1];
  const float* Iin= (const float*)d_in[2];
  const float* R  = (const float*)d_in[3];
  const float* w1 = (const float*)d_in[4];
  const float* w2 = (const float*)d_in[5];
  const float* fw = (const float*)d_in[6];
  const float* fb = (const float*)d_in[7];
  const float* qw = (const float*)d_in[8];
  const float* qb = (const float*)d_in[9];
  const float* kw = (const float*)d_in[10];
  const float* kb = (const float*)d_in[11];
  const float* vw = (const float*)d_in[12];
  const float* vb = (const float*)d_in[13];
  const float* c1 = (const float*)d_in[14];
  const float* g1 = (const float*)d_in[15];
  const float* b1 = (const float*)d_in[16];
  const float* c2 = (const float*)d_in[17];
  const float* g2 = (const float*)d_in[18];
  const float* b2 = (const float*)d_in[19];
  const float* c3 = (const float*)d_in[20];
  const float* g3 = (const float*)d_in[21];
  const float* b3 = (const float*)d_in[22];
  const float* dw = (const float*)d_in[23];

  char* ws = (char*)d_ws;
  // fast path (M1 materialized as NHWC bf16) needs 137,363,456 B;
  // fallback fits in the R2-proven 112,013,312 B.
  bool fast = ws_size >= (size_t)137363456ULL;

  bf16*  WT2  = (bf16*)(ws + 0);           //  4,718,592
  bf16*  WT3  = (bf16*)(ws + 4718592);     // 23,592,960
  bf16*  FS   = (bf16*)(ws + 28311552);    //  8,388,608  NHWC (C=256)
  bf16*  FO1  = (bf16*)(ws + 36700160);    // 16,777,216  NHWC (C=512)
  bf16*  X2   = (bf16*)(ws + 53477376);    // 16,777,216  NHWC (C=512)
  bf16*  M1bf = fast ? (bf16*)(ws + 70254592) : nullptr;  // 67,108,864 NHWC
  bf16*  X3   = (bf16*)(ws + 28311552);    // overlay FS+FO1 (dead by then)
  // attention temporaries (dead before k_m1t / conv phase overwrites them)
  bf16*  FP    = (bf16*) (ws + 53477376);  // X2 region
  float* QUERY = (float*)(ws + 70254592);
  float* FL0   = (float*)(ws + 87031808);
  float* H     = (float*)(ws + 96993280);
  float* KEY   = (float*)(ws + 106954752);
  float* VAL   = (float*)(ws + 111935488);
  float* FL    = FL0;

  k_fp<<<256, 256, 0, stream>>>(F, FP);
  k_flocal<<<256, 256, 0, stream>>>(Iin, R, FP, FL0);
  k_lg1<<<dim3(38, 4), 256, 0, stream>>>(FL0, w1, H);
  k_gemm_wt<false,false><<<dim3(76, 8), 256, 0, stream>>>(H,  w2, nullptr, FL,    512, 512);
  k_fusev<<<76, 256, 0, stream>>>(FL, fw, fb, vw, vb, VAL);
  k_gemm_wt<false,true ><<<dim3(76, 4), 256, 0, stream>>>(FL, kw, kb,      KEY,   512, 256);
  k_gemm_wt<true, true ><<<dim3(256, 4), 256, 0, stream>>>(FP, qw, qb,     QUERY, 512, 256);
  k_attn<<<256, 256, 0, stream>>>(QUERY, KEY, VAL, FS);
  if (fast) k_m1t<<<dim3(256, 32), 256, 0, stream>>>(M1, M1bf);
  k_wtr<<<dim3(512, 4),  256, 0, stream>>>(c2, WT2, 512);
  k_wtr<<<dim3(512, 20), 256, 0, stream>>>(c3, WT3, 2560);
  k_conv1<<<dim3(256, 8), 256, 0, stream>>>(FS, c1, g1, b1, F, FO1);
  k_conv3<<<dim3(128, 4), 256, 0, stream>>>(FO1, 512, nullptr, nullptr, 0,
                                            WT2, g2, b2, X2, 512);
  k_conv3<<<dim3(128, 4), 256, 0, stream>>>(X2, 512, M1bf, M1, 2048,
                                            WT3, g3, b3, X3, 512);
  k_final<<<256, 256, 0, stream>>>(X3, dw, (float*)d_out);
}

// Round 2
// 1142.954 us; speedup vs baseline: 6.0772x; 1.2921x over previous
//
#include <hip/hip_runtime.h>
#include <hip/hip_bf16.h>

typedef __hip_bfloat16 bf16;
using short8 = __attribute__((ext_vector_type(8))) short;
using f32x4  = __attribute__((ext_vector_type(4))) float;

__device__ __forceinline__ float b2f(bf16 v){ return __bfloat162float(v); }
__device__ __forceinline__ bf16  f2b(float v){ return __float2bfloat16(v); }

#define EPSV 1e-5f

// async global->LDS, 16B/lane, dest = wave-uniform base + lane*16
__device__ __forceinline__ void gload16(const void* g, void* l) {
  __builtin_amdgcn_global_load_lds(
      (const __attribute__((address_space(1))) unsigned int*)g,
      (__attribute__((address_space(3))) unsigned int*)l, 16, 0, 0);
}

// ===== f32 -> bf16 flat cast (n4 = count/4) ================================
__global__ __launch_bounds__(256) void k_cast(const float* __restrict__ in,
                                              bf16* __restrict__ out, int n4) {
  int i = blockIdx.x * 256 + threadIdx.x;
  if (i < n4) {
    float4 v = ((const float4*)in)[i];
    union { ushort4 u; bf16 h[4]; } o;
    o.h[0] = f2b(v.x); o.h[1] = f2b(v.y); o.h[2] = f2b(v.z); o.h[3] = f2b(v.w);
    ((ushort4*)out)[i] = o.u;
  }
}

// ===== weight reshape: w [OC=512][CI][3][3] f32 -> WT [9][512][CI] bf16 ====
__global__ __launch_bounds__(256) void k_wtr(const float* __restrict__ w,
                                             bf16* __restrict__ wt, int CI) {
  int oc = blockIdx.x, c0 = blockIdx.y * 128;
  __shared__ float ld[128 * 9];
  const float* src = w + ((size_t)oc * CI + c0) * 9;
  for (int i = threadIdx.x; i < 128 * 9; i += 256) ld[i] = src[i];
  __syncthreads();
  for (int i = threadIdx.x; i < 128 * 9; i += 256) {
    int k9 = i / 128, t = i - k9 * 128;
    wt[((size_t)k9 * 512 + oc) * CI + c0 + t] = f2b(ld[t * 9 + k9]);
  }
}

// ===== M1 NCHW f32 -> NHWC bf16 [4][64][64][2048] (fast path only) =========
__global__ __launch_bounds__(256) void k_m1t(const float* __restrict__ M1,
                                             bf16* __restrict__ M1b) {
  int b = blockIdx.x >> 6, y = blockIdx.x & 63;
  int c0 = blockIdx.y * 64;
  __shared__ float t[64][65];
  for (int i = threadIdx.x; i < 4096; i += 256) {
    int cc = i >> 6, x = i & 63;
    t[x][cc] = M1[((size_t)(b * 2048 + c0 + cc) * 64 + y) * 64 + x];
  }
  __syncthreads();
  for (int i = threadIdx.x; i < 4096; i += 256) {
    int x = i >> 6, cc = i & 63;
    M1b[((size_t)((b * 64 + y) * 64 + x)) * 2048 + c0 + cc] = f2b(t[x][cc]);
  }
}

// ===== F (NCHW f32) -> FP (b,p,n,c) bf16 ===================================
__global__ __launch_bounds__(256) void k_fp(const float* __restrict__ F,
                                            bf16* __restrict__ FP) {
  int bp = blockIdx.x, b = bp >> 6, p = bp & 63;
  int py = (p >> 3) * 8, px = (p & 7) * 8;
  for (int i = threadIdx.x; i < 64 * 512; i += 256) {
    int n = i >> 9, c = i & 511;
    int y = py + (n >> 3), x = px + (n & 7);
    FP[(size_t)bp * 32768 + i] = f2b(F[((size_t)(b * 512 + c) * 64 + y) * 64 + x]);
  }
}

// ===== softmax(I) ; F_l0 = bc * pix @ Fp ===================================
__global__ __launch_bounds__(256) void k_flocal(const float* __restrict__ I,
        const float* __restrict__ R, const bf16* __restrict__ FP,
        float* __restrict__ FL0) {
  int bp = blockIdx.x, b = bp >> 6, p = bp & 63;
  int tid = threadIdx.x;
  __shared__ float pix[19][64];
  __shared__ float bc[19];
  int py = (p >> 3) * 8, px = (p & 7) * 8;
  for (int i = tid; i < 19 * 64; i += 256) {
    int k = i >> 6, n = i & 63;
    int y = py + (n >> 3), x = px + (n & 7);
    pix[k][n] = I[((size_t)(b * 19 + k) * 64 + y) * 64 + x];
  }
  if (tid < 19) bc[tid] = R[(size_t)(b * 19 + tid) * 64 + p];
  __syncthreads();
  if (tid < 19) {
    float mx = -1e30f;
    for (int n = 0; n < 64; n++) mx = fmaxf(mx, pix[tid][n]);
    float s = 0.f;
    for (int n = 0; n < 64; n++) { float e = __expf(pix[tid][n] - mx); pix[tid][n] = e; s += e; }
    float inv = 1.f / s;
    for (int n = 0; n < 64; n++) pix[tid][n] *= inv;
  }
  __syncthreads();
  for (int i = tid; i < 19 * 512; i += 256) {
    int k = i >> 9, c = i & 511;
    const bf16* fp = FP + (size_t)bp * 32768 + c;
    float s = 0.f;
    for (int n = 0; n < 64; n++) s += pix[k][n] * b2f(fp[n << 9]);
    FL0[((size_t)(b * 64 + p) * 19 + k) * 512 + c] = s * bc[k];
  }
}

// ===== LG part 1 (now emits bf16 H) ========================================
__global__ __launch_bounds__(256) void k_lg1(const float* __restrict__ FL0,
        const float* __restrict__ w1, bf16* __restrict__ Hb) {
  int tid = threadIdx.x;
  int b = blockIdx.y;
  int n0 = blockIdx.x * 256;
  __shared__ float W[64][64];
  __shared__ float Xs[16][256];
  for (int i = tid; i < 4096; i += 256) W[i >> 6][i & 63] = w1[i];
  float acc[64];
  #pragma unroll
  for (int po = 0; po < 64; po++) acc[po] = 0.f;
  for (int q0 = 0; q0 < 64; q0 += 16) {
    __syncthreads();
    for (int i = tid; i < 4096; i += 256) {
      int q = i >> 8, j = i & 255;
      Xs[q][j] = FL0[(size_t)(b * 64 + q0 + q) * 9728 + n0 + j];
    }
    __syncthreads();
    for (int q = 0; q < 16; q++) {
      float xv = Xs[q][tid];
      #pragma unroll
      for (int po = 0; po < 64; po++) acc[po] += W[po][q0 + q] * xv;
    }
  }
  for (int po = 0; po < 64; po++) {
    float r = acc[po] + FL0[(size_t)(b * 64 + po) * 9728 + n0 + tid];
    Hb[(size_t)(b * 64 + po) * 9728 + n0 + tid] = f2b(fmaxf(r, 0.f));
  }
}

// ===== NEW: generic MFMA GEMM C[m][n] = sum_k A[m][k]*B[n][k] ==============
// block 128m x 128n, 4 waves (2m x 2n), wave 64x64 = 4x4 frags of 16x16x32.
// MODE 0: C f32 (+bias). MODE 1: C f32 + Cb bf16 (no bias).
// MODE 2: conv1 epilogue: m=oc (M=512), n=pixel; BN+ReLU+residual(F NCHW f32),
//         out NHWC bf16 via padded LDS transpose.
template<int MODE>
__global__ __launch_bounds__(256) void k_gmm(
    const bf16* __restrict__ A, const bf16* __restrict__ B,
    const float* __restrict__ bias, float* __restrict__ C,
    bf16* __restrict__ Cb, int N, int K,
    const float* __restrict__ g, const float* __restrict__ bb,
    const float* __restrict__ Fres, bf16* __restrict__ outb) {
  int tid = threadIdx.x;
  int m0 = blockIdx.x * 128, n0 = blockIdx.y * 128;
  int w = tid >> 6, lane = tid & 63, ln = lane & 15, qd = lane >> 4;
  int wm = w & 1, wn = w >> 1;
  __shared__ __align__(16) char smem[34816]; // staging 2x16KB | EP 128*136*2

  f32x4 acc[4][4];
  #pragma unroll
  for (int i = 0; i < 4; i++)
    #pragma unroll
    for (int j = 0; j < 4; j++) acc[i][j] = (f32x4){0.f, 0.f, 0.f, 0.f};

  int rsub = lane >> 2, ch = lane & 3;
  auto stage = [&](int p) {
    char* base = smem + (p & 1) * 16384;
    int k0 = p << 5;
    #pragma unroll
    for (int t = 0; t < 2; t++) {
      int ii = w + t * 4;
      int r = ii * 16 + rsub;
      int sw = (ch ^ (r & 3)) << 3;
      gload16(A + (size_t)(m0 + r) * K + k0 + sw, base + ii * 1024);
      gload16(B + (size_t)(n0 + r) * K + k0 + sw, base + 8192 + ii * 1024);
    }
  };
  auto compute = [&](int p) {
    const char* base = smem + (p & 1) * 16384;
    short8 af[4], bv[4];
    #pragma unroll
    for (int mi = 0; mi < 4; mi++) {
      int r = wm * 64 + mi * 16 + ln;
      af[mi] = *(const short8*)(base + r * 64 + ((qd ^ (r & 3)) << 4));
    }
    #pragma unroll
    for (int ni = 0; ni < 4; ni++) {
      int r = wn * 64 + ni * 16 + ln;
      bv[ni] = *(const short8*)(base + 8192 + r * 64 + ((qd ^ (r & 3)) << 4));
    }
    #pragma unroll
    for (int mi = 0; mi < 4; mi++)
      #pragma unroll
      for (int ni = 0; ni < 4; ni++)
        acc[mi][ni] = __builtin_amdgcn_mfma_f32_16x16x32_bf16(
            af[mi], bv[ni], acc[mi][ni], 0, 0, 0);
  };

  int KT = K >> 5;
  stage(0);
  __syncthreads();
  for (int p = 0; p < KT; p++) {
    if (p + 1 < KT) stage(p + 1);
    compute(p);
    __syncthreads();
  }

  if (MODE <= 1) {
    #pragma unroll
    for (int mi = 0; mi < 4; mi++) {
      #pragma unroll
      for (int r = 0; r < 4; r++) {
        int m = m0 + wm * 64 + mi * 16 + qd * 4 + r;
        #pragma unroll
        for (int ni = 0; ni < 4; ni++) {
          int n = n0 + wn * 64 + ni * 16 + ln;
          float v = acc[mi][ni][r];
          if (bias) v += bias[n];
          C[(size_t)m * N + n] = v;
          if (MODE == 1) Cb[(size_t)m * N + n] = f2b(v);
        }
      }
    }
  } else {
    bf16* EP = (bf16*)smem;  // [128 pix][136 oc-padded]
    int b = n0 >> 12;
    #pragma unroll
    for (int mi = 0; mi < 4; mi++) {
      #pragma unroll
      for (int r = 0; r < 4; r++) {
        int ml = wm * 64 + mi * 16 + qd * 4 + r;
        int oc = m0 + ml;
        float sc = g[oc] * rsqrtf(1.f + EPSV);
        float bt = bb[oc];
        #pragma unroll
        for (int ni = 0; ni < 4; ni++) {
          int nl = wn * 64 + ni * 16 + ln;
          int pix = n0 + nl;
          int y = (pix >> 6) & 63, x = pix & 63;
          float v = fmaxf(acc[mi][ni][r] * sc + bt, 0.f)
                  + Fres[((size_t)(b * 512 + oc) * 64 + y) * 64 + x];
          EP[nl * 136 + ml] = f2b(v);
        }
      }
    }
    __syncthreads();
    int pl = tid >> 1, half = tid & 1;
    size_t gb = (size_t)(n0 + pl) * 512 + m0 + half * 64;
    const bf16* row = &EP[pl * 136 + half * 64];
    #pragma unroll
    for (int j2 = 0; j2 < 8; j2++)
      *(short8*)(outb + gb + j2 * 8) = *(const short8*)(row + j2 * 8);
  }
}

// ===== fuse + value ========================================================
__global__ __launch_bounds__(256) void k_fusev(const float* __restrict__ FL,
        const float* __restrict__ fw, const float* __restrict__ fbv,
        const float* __restrict__ vw, const float* __restrict__ vb,
        float* __restrict__ VAL) {
  int tid = threadIdx.x;
  int bk = blockIdx.x, b = bk / 19, k = bk % 19;
  __shared__ float fwl[64];
  __shared__ float fg[512];
  if (tid < 64) fwl[tid] = fw[tid];
  __syncthreads();
  float fbias = fbv[0];
  for (int c = tid; c < 512; c += 256) {
    float s = 0.f;
    for (int p = 0; p < 64; p++)
      s += fwl[p] * FL[((size_t)(b * 64 + p) * 19 + k) * 512 + c];
    fg[c] = s + fbias;
  }
  __syncthreads();
  int d = tid;
  float s = vb[d];
  for (int c = 0; c < 512; c++) s += fg[c] * vw[(size_t)d * 512 + c];
  VAL[(size_t)bk * 256 + d] = s;
}

// ===== per-patch attention -> FS NHWC bf16 (C=256) =========================
__global__ __launch_bounds__(256) void k_attn(const float* __restrict__ Q,
        const float* __restrict__ KEY, const float* __restrict__ VAL,
        bf16* __restrict__ FS) {
  int tid = threadIdx.x;
  int bp = blockIdx.x, b = bp >> 6, p = bp & 63;
  __shared__ float ks[19][256];
  __shared__ float vs[19][256];
  __shared__ float Ss[64][20];
  for (int i = tid; i < 19 * 256; i += 256) {
    ks[i >> 8][i & 255] = KEY[(size_t)bp * 19 * 256 + i];
    vs[i >> 8][i & 255] = VAL[(size_t)b * 19 * 256 + i];
  }
  __syncthreads();
  {
    int n = tid >> 2, kq = tid & 3;
    const float* qrow = Q + ((size_t)bp * 64 + n) * 256;
    for (int k = kq; k < 19; k += 4) {
      float s = 0.f;
      for (int d = 0; d < 256; d++) s += qrow[d] * ks[k][d];
      Ss[n][k] = s;
    }
  }
  __syncthreads();
  if (tid < 64) {
    float mx = -1e30f;
    for (int k = 0; k < 19; k++) mx = fmaxf(mx, Ss[tid][k]);
    float sum = 0.f;
    for (int k = 0; k < 19; k++) { float e = __expf(Ss[tid][k] - mx); Ss[tid][k] = e; sum += e; }
    float inv = 1.f / sum;
    for (int k = 0; k < 19; k++) Ss[tid][k] *= inv;
  }
  __syncthreads();
  {
    int d = tid;
    int py = (p >> 3) * 8, px = (p & 7) * 8;
    for (int nn = 0; nn < 64; nn++) {
      float s = 0.f;
      #pragma unroll
      for (int k = 0; k < 19; k++) s += Ss[nn][k] * vs[k][d];
      int y = py + (nn >> 3), x = px + (nn & 7);
      FS[(((size_t)(b * 64 + y) * 64) + x) * 256 + d] = f2b(s);
    }
  }
}

// ===== MFMA conv3x3 pad1, NHWC in/out, global_load_lds staging =============
__global__ __launch_bounds__(256) void k_conv3(
    const bf16* __restrict__ Xin, int Cin,
    const bf16* __restrict__ M1b, const float* __restrict__ M1f, int C2,
    const bf16* __restrict__ WT,
    const float* __restrict__ g, const float* __restrict__ bb,
    bf16* __restrict__ out, int Cos) {
  int tid = threadIdx.x;
  int b = blockIdx.x >> 5, y0 = (blockIdx.x & 31) * 2;
  int oc0 = blockIdx.y * 128;
  int w = tid >> 6, lane = tid & 63, ln = lane & 15, qd = lane >> 4;
  int wocg = w & 1, wy = w >> 1;
  int Ct = Cin + C2;

  __shared__ __align__(16) char smem[2 * 24576 + 16896];
  char* smA = smem;            // Aw[2][3][128][32] bf16, rows of 64B
  char* smB = smem + 49152;    // Bs[4][66][32] bf16, rows of 64B

  {
    int ryy = tid >> 6, hh = (tid >> 5) & 1, kk = tid & 31;
    *(bf16*)(smB + ((ryy * 66 + (hh ? 65 : 0)) * 64) + kk * 2) = f2b(0.f);
  }

  f32x4 acc[4][4];
  #pragma unroll
  for (int i = 0; i < 4; i++)
    #pragma unroll
    for (int j = 0; j < 4; j++) acc[i][j] = (f32x4){0.f, 0.f, 0.f, 0.f};

  int NPH = (Ct >> 5) * 3;

  auto stageA = [&](int p) {
    int c0 = (p / 3) << 5, ky = p % 3;
    char* base = smA + (p & 1) * 24576;
    int j = w;
    #pragma unroll
    for (int t = 0; t < 6; t++, j += 4) {
      int kx = j >> 3, i8 = j & 7;
      int ocl = i8 * 16 + (lane >> 2);
      const bf16* src = WT + ((size_t)((ky * 3 + kx) * 512 + oc0 + ocl) * Ct + c0)
                      + (((lane & 3) ^ (ocl & 3)) << 3);
      gload16(src, base + (kx * 128 + i8 * 16) * 64);
    }
  };
  auto stageB = [&](int gi) {
    int c0 = gi << 5;
    if (c0 < Cin || M1b != nullptr) {
      const bf16* T; int Cs, cb;
      if (c0 < Cin) { T = Xin; Cs = Cin; cb = c0; }
      else          { T = M1b; Cs = C2;  cb = c0 - Cin; }
      int j = w;
      #pragma unroll
      for (int t = 0; t < 4; t++, j += 4) {
        int ryy = j >> 2, i4 = j & 3;
        int yy = y0 + ryy - 1;
        if ((unsigned)yy < 64u) {
          int xx = i4 * 16 + (lane >> 2), xr = xx + 1;
          const bf16* src = T + ((size_t)((b * 64 + yy) * 64 + xx) * Cs + cb)
                          + (((lane & 3) ^ (xr & 3)) << 3);
          gload16(src, smB + ((ryy * 66 + 1 + i4 * 16) * 64));
        }
      }
    } else {
      int ryy = w, yy = y0 + ryy - 1;
      if ((unsigned)yy < 64u) {
        int xx = lane, xr = xx + 1;
        const float* mp = M1f + ((size_t)(b * 2048 + (c0 - Cin)) * 64 + yy) * 64 + xx;
        #pragma unroll
        for (int q = 0; q < 8; q++) {
          union { ushort4 u; bf16 h[4]; } pk;
          #pragma unroll
          for (int jj = 0; jj < 4; jj++) pk.h[jj] = f2b(mp[(size_t)(q * 4 + jj) * 4096]);
          *(ushort4*)(smB + ((ryy * 66 + xr) * 64)
                      + ((((q >> 1) ^ (xr & 3)) << 4) | ((q & 1) << 3))) = pk.u;
        }
      }
    }
  };
  auto computeP = [&](int p) {
    int ky = p % 3;
    int yyw = y0 + wy + ky - 1;
    if ((unsigned)yyw >= 64u) return;
    const char* base = smA + (p & 1) * 24576;
    #pragma unroll
    for (int kx = 0; kx < 3; kx++) {
      short8 af[4], bv[4];
      #pragma unroll
      for (int mi = 0; mi < 4; mi++) {
        int ocl = wocg * 64 + mi * 16 + ln;
        af[mi] = *(const short8*)(base + (kx * 128 + ocl) * 64 + ((qd ^ (ln & 3)) << 4));
      }
      #pragma unroll
      for (int ni = 0; ni < 4; ni++) {
        int xr = ni * 16 + ln + kx;
        bv[ni] = *(const short8*)(smB + ((wy + ky) * 66 + xr) * 64 + ((qd ^ (xr & 3)) << 4));
      }
      #pragma unroll
      for (int mi = 0; mi < 2; mi++)
        #pragma unroll
        for (int ni = 0; ni < 4; ni++)
          acc[mi][ni] = __builtin_amdgcn_mfma_f32_16x16x32_bf16(af[mi], bv[ni], acc[mi][ni], 0, 0, 0);
      #pragma unroll
      for (int mi = 2; mi < 4; mi++)
        #pragma unroll
        for (int ni = 0; ni < 4; ni++)
          acc[mi][ni] = __builtin_amdgcn_mfma_f32_16x16x32_bf16(af[mi], bv[ni], acc[mi][ni], 0, 0, 0);
    }
  };

  stageB(0);
  stageA(0);
  __syncthreads();
  for (int p = 0; p < NPH; p++) {
    if (p + 1 < NPH && (p + 1) % 3 != 0) stageA(p + 1);
    computeP(p);
    __syncthreads();
    if (p + 1 < NPH && (p + 1) % 3 == 0) {
      stageA(p + 1);
      stageB((p + 1) / 3);
      __syncthreads();
    }
  }

  {
    bf16* EP = (bf16*)smem;   // [2 wy][64 x][128 ocl]
    #pragma unroll
    for (int mi = 0; mi < 4; mi++) {
      int oclb = wocg * 64 + mi * 16 + qd * 4;
      float sc[4], bt[4];
      #pragma unroll
      for (int r = 0; r < 4; r++) {
        int oc = oc0 + oclb + r;
        sc[r] = g[oc] * rsqrtf(1.f + EPSV);
        bt[r] = bb[oc];
      }
      #pragma unroll
      for (int ni = 0; ni < 4; ni++) {
        int x = ni * 16 + ln;
        union { ushort4 u; bf16 h[4]; } pk;
        #pragma unroll
        for (int r = 0; r < 4; r++)
          pk.h[r] = f2b(fmaxf(acc[mi][ni][r] * sc[r] + bt[r], 0.f));
        *(ushort4*)&EP[(wy * 64 + x) * 128 + oclb] = pk.u;
      }
    }
    __syncthreads();
    int p2 = tid >> 1, hh = tid & 1;
    int wy2 = p2 >> 6, x = p2 & 63;
    size_t gb = ((size_t)((b * 64 + y0 + wy2) * 64 + x)) * Cos + oc0 + hh * 64;
    const bf16* row = &EP[p2 * 128 + hh * 64];
    #pragma unroll
    for (int k = 0; k < 8; k++)
      *(short8*)(out + gb + k * 8) = *(const short8*)(row + k * 8);
  }
}

// ===== final 1x1 (512->19) from NHWC X3 ====================================
__global__ __launch_bounds__(256) void k_final(const bf16* __restrict__ X3,
        const float* __restrict__ dw, float* __restrict__ out) {
  int tid = threadIdx.x;
  int b = blockIdx.x >> 6, y = blockIdx.x & 63;
  __shared__ float W[19 * 512];
  for (int i = tid; i < 19 * 512; i += 256) W[i] = dw[i];
  __syncthreads();
  int x = tid & 63, kg = tid >> 6;
  const bf16* px = X3 + (((size_t)(b * 64 + y) * 64) + x) * 512;
  float acc[5] = {0.f, 0.f, 0.f, 0.f, 0.f};
  for (int c8 = 0; c8 < 512; c8 += 8) {
    union { short8 s; bf16 h[8]; } v;
    v.s = *(const short8*)(px + c8);
    float f[8];
    #pragma unroll
    for (int j = 0; j < 8; j++) f[j] = b2f(v.h[j]);
    #pragma unroll
    for (int i = 0; i < 5; i++) {
      int k = kg * 5 + i;
      if (k < 19) {
        const float* wr = &W[k * 512 + c8];
        #pragma unroll
        for (int j = 0; j < 8; j++) acc[i] += f[j] * wr[j];
      }
    }
  }
  for (int i = 0; i < 5; i++) {
    int k = kg * 5 + i;
    if (k < 19) out[((size_t)(b * 19 + k) * 64 + y) * 64 + x] = acc[i];
  }
}

extern "C" void kernel_launch(void* const* d_in, const int* in_sizes, int n_in,
                              void* d_out, int out_size, void* d_ws, size_t ws_size,
                              hipStream_t stream) {
  (void)in_sizes; (void)n_in; (void)out_size;
  const float* M1 = (const float*)d_in[0];
  const float* F  = (const float*)d_in[1];
  const float* Iin= (const float*)d_in[2];
  const float* R  = (const float*)d_in[3];
  const float* w1 = (const float*)d_in[4];
  const float* w2 = (const float*)d_in[5];
  const float* fw = (const float*)d_in[6];
  const float* fb = (const float*)d_in[7];
  const float* qw = (const float*)d_in[8];
  const float* qb = (const float*)d_in[9];
  const float* kw = (const float*)d_in[10];
  const float* kb = (const float*)d_in[11];
  const float* vw = (const float*)d_in[12];
  const float* vb = (const float*)d_in[13];
  const float* c1 = (const float*)d_in[14];
  const float* g1 = (const float*)d_in[15];
  const float* b1 = (const float*)d_in[16];
  const float* c2 = (const float*)d_in[17];
  const float* g2 = (const float*)d_in[18];
  const float* b2 = (const float*)d_in[19];
  const float* c3 = (const float*)d_in[20];
  const float* g3 = (const float*)d_in[21];
  const float* b3 = (const float*)d_in[22];
  const float* dw = (const float*)d_in[23];

  char* ws = (char*)d_ws;
  bool fast = ws_size >= (size_t)137363456ULL;

  // weight bf16 casts live in the (currently dead) WT2 region; all are
  // consumed before k_wtr writes WT2 (k_wtr now launches after conv1).
  bf16*  qwb  = (bf16*)(ws + 0);           //   262,144
  bf16*  kwb  = (bf16*)(ws + 262144);      //   262,144
  bf16*  w2b  = (bf16*)(ws + 524288);      //   524,288
  bf16*  c1b  = (bf16*)(ws + 1048576);     //   262,144
  bf16*  WT2  = (bf16*)(ws + 0);           //  4,718,592 (after conv1)
  bf16*  WT3  = (bf16*)(ws + 4718592);     // 23,592,960
  bf16*  FS   = (bf16*)(ws + 28311552);    //  8,388,608  NHWC (C=256)
  bf16*  FO1  = (bf16*)(ws + 36700160);    // 16,777,216  NHWC (C=512)
  bf16*  X2   = (bf16*)(ws + 53477376);    // 16,777,216  NHWC (C=512)
  bf16*  M1bf = fast ? (bf16*)(ws + 70254592) : nullptr;  // 67,108,864 NHWC
  bf16*  X3   = (bf16*)(ws + 28311552);    // overlay FS+FO1 (dead by then)
  // attention temporaries (all dead before k_m1t writes M1bf over them)
  bf16*  FP    = (bf16*) (ws + 53477376);  // X2 region
  float* QUERY = (float*)(ws + 70254592);  // 16,777,216
  float* FL0   = (float*)(ws + 87031808);  //  9,961,472
  bf16*  Hb    = (bf16*) (ws + 96993280);  //  4,980,736
  bf16*  FLb   = (bf16*) (ws + 101974016); //  4,980,736
  float* KEY   = (float*)(ws + 106954752); //  4,980,736
  float* VAL   = (float*)(ws + 111935488); //     77,824
  float* FL    = FL0;

  k_cast<<<128, 256, 0, stream>>>(qw, qwb, 32768);
  k_cast<<<128, 256, 0, stream>>>(kw, kwb, 32768);
  k_cast<<<256, 256, 0, stream>>>(w2, w2b, 65536);
  k_cast<<<128, 256, 0, stream>>>(c1, c1b, 32768);
  k_fp<<<256, 256, 0, stream>>>(F, FP);
  k_flocal<<<256, 256, 0, stream>>>(Iin, R, FP, FL0);
  k_lg1<<<dim3(38, 4), 256, 0, stream>>>(FL0, w1, Hb);
  k_gmm<1><<<dim3(38, 4), 256, 0, stream>>>(Hb, w2b, nullptr, FL, FLb, 512, 512,
                                            nullptr, nullptr, nullptr, nullptr);
  k_fusev<<<76, 256, 0, stream>>>(FL, fw, fb, vw, vb, VAL);
  k_gmm<0><<<dim3(38, 2), 256, 0, stream>>>(FLb, kwb, kb, KEY, nullptr, 256, 512,
                                            nullptr, nullptr, nullptr, nullptr);
  k_gmm<0><<<dim3(128, 2), 256, 0, stream>>>(FP, qwb, qb, QUERY, nullptr, 256, 512,
                                             nullptr, nullptr, nullptr, nullptr);
  k_attn<<<256, 256, 0, stream>>>(QUERY, KEY, VAL, FS);
  if (fast) k_m1t<<<dim3(256, 32), 256, 0, stream>>>(M1, M1bf);
  k_gmm<2><<<dim3(4, 128), 256, 0, stream>>>(c1b, FS, nullptr, nullptr, nullptr,
                                             16384, 256, g1, b1, F, FO1);
  k_wtr<<<dim3(512, 4),  256, 0, stream>>>(c2, WT2, 512);
  k_wtr<<<dim3(512, 20), 256, 0, stream>>>(c3, WT3, 2560);
  k_conv3<<<dim3(128, 4), 256, 0, stream>>>(FO1, 512, nullptr, nullptr, 0,
                                            WT2, g2, b2, X2, 512);
  k_conv3<<<dim3(128, 4), 256, 0, stream>>>(X2, 512, M1bf, M1, 2048,
                                            WT3, g3, b3, X3, 512);
  k_final<<<256, 256, 0, stream>>>(X3, dw, (float*)d_out);
}

// Round 4
// 1092.570 us; speedup vs baseline: 6.3575x; 1.0461x over previous
//
#include <hip/hip_runtime.h>
#include <hip/hip_bf16.h>

typedef __hip_bfloat16 bf16;
using short8 = __attribute__((ext_vector_type(8))) short;
using f32x4  = __attribute__((ext_vector_type(4))) float;

__device__ __forceinline__ float b2f(bf16 v){ return __bfloat162float(v); }
__device__ __forceinline__ bf16  f2b(float v){ return __float2bfloat16(v); }

#define EPSV 1e-5f

// async global->LDS, 16B/lane, dest = wave-uniform base + lane*16
__device__ __forceinline__ void gload16(const void* g, void* l) {
  __builtin_amdgcn_global_load_lds(
      (const __attribute__((address_space(1))) unsigned int*)g,
      (__attribute__((address_space(3))) unsigned int*)l, 16, 0, 0);
}

// ===== f32 -> bf16 flat cast (n4 = count/4) ================================
__global__ __launch_bounds__(256) void k_cast(const float* __restrict__ in,
                                              bf16* __restrict__ out, int n4) {
  int i = blockIdx.x * 256 + threadIdx.x;
  if (i < n4) {
    float4 v = ((const float4*)in)[i];
    union { ushort4 u; bf16 h[4]; } o;
    o.h[0] = f2b(v.x); o.h[1] = f2b(v.y); o.h[2] = f2b(v.z); o.h[3] = f2b(v.w);
    ((ushort4*)out)[i] = o.u;
  }
}

// ===== weight reshape: w [OC=512][CI][3][3] f32 -> WT [9][512][CI] bf16 ====
__global__ __launch_bounds__(256) void k_wtr(const float* __restrict__ w,
                                             bf16* __restrict__ wt, int CI) {
  int oc = blockIdx.x, c0 = blockIdx.y * 128;
  __shared__ float ld[128 * 9];
  const float* src = w + ((size_t)oc * CI + c0) * 9;
  for (int i = threadIdx.x; i < 128 * 9; i += 256) ld[i] = src[i];
  __syncthreads();
  for (int i = threadIdx.x; i < 128 * 9; i += 256) {
    int k9 = i / 128, t = i - k9 * 128;
    wt[((size_t)k9 * 512 + oc) * CI + c0 + t] = f2b(ld[t * 9 + k9]);
  }
}

// ===== M1 NCHW f32 -> NHWC bf16 [4][64][64][2048] (fast path only) =========
__global__ __launch_bounds__(256) void k_m1t(const float* __restrict__ M1,
                                             bf16* __restrict__ M1b) {
  int b = blockIdx.x >> 6, y = blockIdx.x & 63;
  int c0 = blockIdx.y * 64;
  __shared__ float t[64][65];
  for (int i = threadIdx.x; i < 4096; i += 256) {
    int cc = i >> 6, x = i & 63;
    t[x][cc] = M1[((size_t)(b * 2048 + c0 + cc) * 64 + y) * 64 + x];
  }
  __syncthreads();
  for (int i = threadIdx.x; i < 4096; i += 256) {
    int x = i >> 6, cc = i & 63;
    M1b[((size_t)((b * 64 + y) * 64 + x)) * 2048 + c0 + cc] = f2b(t[x][cc]);
  }
}

// ===== F (NCHW f32) -> FP (b,p,n,c) bf16 via LDS transpose =================
__global__ __launch_bounds__(256) void k_fp2(const float* __restrict__ F,
                                             bf16* __restrict__ FP) {
  int b = blockIdx.x >> 6, y = blockIdx.x & 63;
  int tid = threadIdx.x;
  __shared__ float t[256][65];
  int p_hi = (y >> 3) << 3, n_hi = (y & 7) << 3;
  for (int half = 0; half < 2; half++) {
    int c0 = half << 8;
    for (int i = tid; i < 256 * 64; i += 256) {
      int cc = i >> 6, x = i & 63;
      t[cc][x] = F[((size_t)(b * 512 + c0 + cc) * 64 + y) * 64 + x];
    }
    __syncthreads();
    // thread = cc (lane-consecutive), loop x: coalesced bf16 writes
    for (int x = 0; x < 64; x++) {
      int p = p_hi + (x >> 3), n = n_hi + (x & 7);
      FP[((size_t)(b * 64 + p)) * 32768 + n * 512 + c0 + tid] = f2b(t[tid][x]);
    }
    __syncthreads();
  }
}

// ===== softmax(I); FL0 = (bc*pix) @ FP  with FP slice in LDS ===============
__global__ __launch_bounds__(256) void k_flocal2(const float* __restrict__ I,
        const float* __restrict__ R, const bf16* __restrict__ FP,
        float* __restrict__ FL0) {
  int bp = blockIdx.x, b = bp >> 6, p = bp & 63;
  int tid = threadIdx.x, w = tid >> 6, lane = tid & 63;
  __shared__ __align__(16) bf16 fps[64 * 512];   // 64 KB
  __shared__ float pix[19][64];
  __shared__ float bc[19];
  // stage FP slice (64n x 512c bf16) via global_load_lds, 1KB/wave/call
  {
    const bf16* src = FP + (size_t)bp * 32768 + lane * 8;
    #pragma unroll
    for (int t = 0; t < 16; t++) {
      int chunk = w + t * 4;
      gload16(src + chunk * 512, (char*)fps + chunk * 1024);
    }
  }
  int py = (p >> 3) * 8, px = (p & 7) * 8;
  for (int i = tid; i < 19 * 64; i += 256) {
    int k = i >> 6, n = i & 63;
    int y = py + (n >> 3), x = px + (n & 7);
    pix[k][n] = I[((size_t)(b * 19 + k) * 64 + y) * 64 + x];
  }
  if (tid < 19) bc[tid] = R[(size_t)(b * 19 + tid) * 64 + p];
  __syncthreads();
  if (tid < 19) {
    float mx = -1e30f;
    for (int n = 0; n < 64; n++) mx = fmaxf(mx, pix[tid][n]);
    float s = 0.f;
    for (int n = 0; n < 64; n++) { float e = __expf(pix[tid][n] - mx); pix[tid][n] = e; s += e; }
    float sc = bc[tid] / s;           // fold bin_conf into normalized pix
    for (int n = 0; n < 64; n++) pix[tid][n] *= sc;
  }
  __syncthreads();
  // tasks (k, c8-block): 19*64; per task 64 ds_read_b128 + 8 FMA each
  for (int task = tid; task < 19 * 64; task += 256) {
    int k = task >> 6, c8 = (task & 63) << 3;
    float acc[8] = {};
    for (int n = 0; n < 64; n++) {
      float pv = pix[k][n];
      union { short8 s; bf16 h[8]; } v;
      v.s = *(const short8*)&fps[n * 512 + c8];
      #pragma unroll
      for (int j = 0; j < 8; j++) acc[j] += pv * b2f(v.h[j]);
    }
    float* dst = FL0 + ((size_t)(b * 64 + p) * 19 + k) * 512 + c8;
    #pragma unroll
    for (int j = 0; j < 8; j++) dst[j] = acc[j];
  }
}

// ===== LG part 1 (emits bf16 H) ============================================
__global__ __launch_bounds__(256) void k_lg1(const float* __restrict__ FL0,
        const float* __restrict__ w1, bf16* __restrict__ Hb) {
  int tid = threadIdx.x;
  int b = blockIdx.y;
  int n0 = blockIdx.x * 256;
  __shared__ float W[64][64];
  __shared__ float Xs[16][256];
  for (int i = tid; i < 4096; i += 256) W[i >> 6][i & 63] = w1[i];
  float acc[64];
  #pragma unroll
  for (int po = 0; po < 64; po++) acc[po] = 0.f;
  for (int q0 = 0; q0 < 64; q0 += 16) {
    __syncthreads();
    for (int i = tid; i < 4096; i += 256) {
      int q = i >> 8, j = i & 255;
      Xs[q][j] = FL0[(size_t)(b * 64 + q0 + q) * 9728 + n0 + j];
    }
    __syncthreads();
    for (int q = 0; q < 16; q++) {
      float xv = Xs[q][tid];
      #pragma unroll
      for (int po = 0; po < 64; po++) acc[po] += W[po][q0 + q] * xv;
    }
  }
  for (int po = 0; po < 64; po++) {
    float r = acc[po] + FL0[(size_t)(b * 64 + po) * 9728 + n0 + tid];
    Hb[(size_t)(b * 64 + po) * 9728 + n0 + tid] = f2b(fmaxf(r, 0.f));
  }
}

// ===== generic MFMA GEMM C[m][n] = sum_k A[m][k]*B[n][k] ===================
template<int MODE>
__global__ __launch_bounds__(256) void k_gmm(
    const bf16* __restrict__ A, const bf16* __restrict__ B,
    const float* __restrict__ bias, float* __restrict__ C,
    bf16* __restrict__ Cb, int N, int K,
    const float* __restrict__ g, const float* __restrict__ bb,
    const float* __restrict__ Fres, bf16* __restrict__ outb) {
  int tid = threadIdx.x;
  int m0 = blockIdx.x * 128, n0 = blockIdx.y * 128;
  int w = tid >> 6, lane = tid & 63, ln = lane & 15, qd = lane >> 4;
  int wm = w & 1, wn = w >> 1;
  __shared__ __align__(16) char smem[34816]; // staging 2x16KB | EP 128*136*2

  f32x4 acc[4][4];
  #pragma unroll
  for (int i = 0; i < 4; i++)
    #pragma unroll
    for (int j = 0; j < 4; j++) acc[i][j] = (f32x4){0.f, 0.f, 0.f, 0.f};

  int rsub = lane >> 2, ch = lane & 3;
  auto stage = [&](int p) {
    char* base = smem + (p & 1) * 16384;
    int k0 = p << 5;
    #pragma unroll
    for (int t = 0; t < 2; t++) {
      int ii = w + t * 4;
      int r = ii * 16 + rsub;
      int sw = (ch ^ (r & 3)) << 3;
      gload16(A + (size_t)(m0 + r) * K + k0 + sw, base + ii * 1024);
      gload16(B + (size_t)(n0 + r) * K + k0 + sw, base + 8192 + ii * 1024);
    }
  };
  auto compute = [&](int p) {
    const char* base = smem + (p & 1) * 16384;
    short8 af[4], bv[4];
    #pragma unroll
    for (int mi = 0; mi < 4; mi++) {
      int r = wm * 64 + mi * 16 + ln;
      af[mi] = *(const short8*)(base + r * 64 + ((qd ^ (r & 3)) << 4));
    }
    #pragma unroll
    for (int ni = 0; ni < 4; ni++) {
      int r = wn * 64 + ni * 16 + ln;
      bv[ni] = *(const short8*)(base + 8192 + r * 64 + ((qd ^ (r & 3)) << 4));
    }
    #pragma unroll
    for (int mi = 0; mi < 4; mi++)
      #pragma unroll
      for (int ni = 0; ni < 4; ni++)
        acc[mi][ni] = __builtin_amdgcn_mfma_f32_16x16x32_bf16(
            af[mi], bv[ni], acc[mi][ni], 0, 0, 0);
  };

  int KT = K >> 5;
  stage(0);
  __syncthreads();
  for (int p = 0; p < KT; p++) {
    if (p + 1 < KT) stage(p + 1);
    compute(p);
    __syncthreads();
  }

  if (MODE <= 1) {
    #pragma unroll
    for (int mi = 0; mi < 4; mi++) {
      #pragma unroll
      for (int r = 0; r < 4; r++) {
        int m = m0 + wm * 64 + mi * 16 + qd * 4 + r;
        #pragma unroll
        for (int ni = 0; ni < 4; ni++) {
          int n = n0 + wn * 64 + ni * 16 + ln;
          float v = acc[mi][ni][r];
          if (bias) v += bias[n];
          C[(size_t)m * N + n] = v;
          if (MODE == 1) Cb[(size_t)m * N + n] = f2b(v);
        }
      }
    }
  } else {
    bf16* EP = (bf16*)smem;  // [128 pix][136 oc-padded]
    int b = n0 >> 12;
    #pragma unroll
    for (int mi = 0; mi < 4; mi++) {
      #pragma unroll
      for (int r = 0; r < 4; r++) {
        int ml = wm * 64 + mi * 16 + qd * 4 + r;
        int oc = m0 + ml;
        float sc = g[oc] * rsqrtf(1.f + EPSV);
        float bt = bb[oc];
        #pragma unroll
        for (int ni = 0; ni < 4; ni++) {
          int nl = wn * 64 + ni * 16 + ln;
          int pix = n0 + nl;
          int y = (pix >> 6) & 63, x = pix & 63;
          float v = fmaxf(acc[mi][ni][r] * sc + bt, 0.f)
                  + Fres[((size_t)(b * 512 + oc) * 64 + y) * 64 + x];
          EP[nl * 136 + ml] = f2b(v);
        }
      }
    }
    __syncthreads();
    int pl = tid >> 1, half = tid & 1;
    size_t gb = (size_t)(n0 + pl) * 512 + m0 + half * 64;
    const bf16* row = &EP[pl * 136 + half * 64];
    #pragma unroll
    for (int j2 = 0; j2 < 8; j2++)
      *(short8*)(outb + gb + j2 * 8) = *(const short8*)(row + j2 * 8);
  }
}

// ===== fuse + value (float4 vw/fg) =========================================
__global__ __launch_bounds__(256) void k_fusev(const float* __restrict__ FL,
        const float* __restrict__ fw, const float* __restrict__ fbv,
        const float* __restrict__ vw, const float* __restrict__ vb,
        float* __restrict__ VAL) {
  int tid = threadIdx.x;
  int bk = blockIdx.x, b = bk / 19, k = bk % 19;
  __shared__ float fwl[64];
  __shared__ __align__(16) float fg[512];
  if (tid < 64) fwl[tid] = fw[tid];
  __syncthreads();
  float fbias = fbv[0];
  for (int c = tid; c < 512; c += 256) {
    float s = 0.f;
    for (int p = 0; p < 64; p++)
      s += fwl[p] * FL[((size_t)(b * 64 + p) * 19 + k) * 512 + c];
    fg[c] = s + fbias;
  }
  __syncthreads();
  int d = tid;
  float s = vb[d];
  const float4* vr = (const float4*)(vw + (size_t)d * 512);
  const float4* fr = (const float4*)fg;
  for (int c4 = 0; c4 < 128; c4++) {
    float4 wv = vr[c4], f = fr[c4];
    s += f.x * wv.x + f.y * wv.y + f.z * wv.z + f.w * wv.w;
  }
  VAL[(size_t)bk * 256 + d] = s;
}

// ===== per-patch attention -> FS NHWC bf16 (C=256), coalesced stores =======
__global__ __launch_bounds__(256) void k_attn(const float* __restrict__ Q,
        const float* __restrict__ KEY, const float* __restrict__ VAL,
        bf16* __restrict__ FS) {
  int tid = threadIdx.x;
  int bp = blockIdx.x, b = bp >> 6, p = bp & 63;
  __shared__ __align__(16) float ks[19][256];
  __shared__ __align__(16) float vs[19][256];
  __shared__ float Ss[64][20];
  __shared__ bf16 ot[64][256];
  for (int i = tid; i < 19 * 256; i += 256) {
    ks[i >> 8][i & 255] = KEY[(size_t)bp * 19 * 256 + i];
    vs[i >> 8][i & 255] = VAL[(size_t)b * 19 * 256 + i];
  }
  __syncthreads();
  {
    int n = tid >> 2, kq = tid & 3;
    const float4* qrow = (const float4*)(Q + ((size_t)bp * 64 + n) * 256);
    for (int k = kq; k < 19; k += 4) {
      const float4* kr = (const float4*)&ks[k][0];
      float s = 0.f;
      for (int d4 = 0; d4 < 64; d4++) {
        float4 qv = qrow[d4], kv = kr[d4];
        s += qv.x * kv.x + qv.y * kv.y + qv.z * kv.z + qv.w * kv.w;
      }
      Ss[n][k] = s;
    }
  }
  __syncthreads();
  if (tid < 64) {
    float mx = -1e30f;
    for (int k = 0; k < 19; k++) mx = fmaxf(mx, Ss[tid][k]);
    float sum = 0.f;
    for (int k = 0; k < 19; k++) { float e = __expf(Ss[tid][k] - mx); Ss[tid][k] = e; sum += e; }
    float inv = 1.f / sum;
    for (int k = 0; k < 19; k++) Ss[tid][k] *= inv;
  }
  __syncthreads();
  {
    int d = tid;
    for (int nn = 0; nn < 64; nn++) {
      float s = 0.f;
      #pragma unroll
      for (int k = 0; k < 19; k++) s += Ss[nn][k] * vs[k][d];
      ot[nn][d] = f2b(s);
    }
  }
  __syncthreads();
  {
    int py = (p >> 3) * 8, px = (p & 7) * 8;
    int nn = tid >> 2, q = tid & 3;
    int y = py + (nn >> 3), x = px + (nn & 7);
    size_t gb = (((size_t)(b * 64 + y) * 64) + x) * 256 + q * 64;
    const bf16* row = &ot[nn][q * 64];
    #pragma unroll
    for (int j = 0; j < 8; j++)
      *(short8*)(FS + gb + j * 8) = *(const short8*)(row + j * 8);
  }
}

// ===== MFMA conv3x3 pad1, NHWC in/out; XCD-aware 1D grid (512 blocks) ======
// wgid&7 = XCD; oc-slice = (wgid&7)>>1  -> each 128-oc weight slice owned by
// exactly 2 XCDs (WT3 slice 5.9MB streams through 2 L2s, not 8).
__global__ __launch_bounds__(256) void k_conv3(
    const bf16* __restrict__ Xin, int Cin,
    const bf16* __restrict__ M1b, const float* __restrict__ M1f, int C2,
    const bf16* __restrict__ WT,
    const float* __restrict__ g, const float* __restrict__ bb,
    bf16* __restrict__ out, int Cos) {
  int tid = threadIdx.x;
  int wg = blockIdx.x;
  int xcd = wg & 7;
  int sp = ((wg >> 3) << 1) + (xcd & 1);
  int b = sp >> 5, y0 = (sp & 31) * 2;
  int oc0 = (xcd >> 1) * 128;
  int w = tid >> 6, lane = tid & 63, ln = lane & 15, qd = lane >> 4;
  int wocg = w & 1, wy = w >> 1;
  int Ct = Cin + C2;

  __shared__ __align__(16) char smem[2 * 24576 + 16896];
  char* smA = smem;            // Aw[2][3][128][32] bf16, rows of 64B
  char* smB = smem + 49152;    // Bs[4][66][32] bf16, rows of 64B

  {
    int ryy = tid >> 6, hh = (tid >> 5) & 1, kk = tid & 31;
    *(bf16*)(smB + ((ryy * 66 + (hh ? 65 : 0)) * 64) + kk * 2) = f2b(0.f);
  }

  f32x4 acc[4][4];
  #pragma unroll
  for (int i = 0; i < 4; i++)
    #pragma unroll
    for (int j = 0; j < 4; j++) acc[i][j] = (f32x4){0.f, 0.f, 0.f, 0.f};

  int NPH = (Ct >> 5) * 3;

  auto stageA = [&](int p) {
    int c0 = (p / 3) << 5, ky = p % 3;
    char* base = smA + (p & 1) * 24576;
    int j = w;
    #pragma unroll
    for (int t = 0; t < 6; t++, j += 4) {
      int kx = j >> 3, i8 = j & 7;
      int ocl = i8 * 16 + (lane >> 2);
      const bf16* src = WT + ((size_t)((ky * 3 + kx) * 512 + oc0 + ocl) * Ct + c0)
                      + (((lane & 3) ^ (ocl & 3)) << 3);
      gload16(src, base + (kx * 128 + i8 * 16) * 64);
    }
  };
  auto stageB = [&](int gi) {
    int c0 = gi << 5;
    if (c0 < Cin || M1b != nullptr) {
      const bf16* T; int Cs, cb;
      if (c0 < Cin) { T = Xin; Cs = Cin; cb = c0; }
      else          { T = M1b; Cs = C2;  cb = c0 - Cin; }
      int j = w;
      #pragma unroll
      for (int t = 0; t < 4; t++, j += 4) {
        int ryy = j >> 2, i4 = j & 3;
        int yy = y0 + ryy - 1;
        if ((unsigned)yy < 64u) {
          int xx = i4 * 16 + (lane >> 2), xr = xx + 1;
          const bf16* src = T + ((size_t)((b * 64 + yy) * 64 + xx) * Cs + cb)
                          + (((lane & 3) ^ (xr & 3)) << 3);
          gload16(src, smB + ((ryy * 66 + 1 + i4 * 16) * 64));
        }
      }
    } else {
      int ryy = w, yy = y0 + ryy - 1;
      if ((unsigned)yy < 64u) {
        int xx = lane, xr = xx + 1;
        const float* mp = M1f + ((size_t)(b * 2048 + (c0 - Cin)) * 64 + yy) * 64 + xx;
        #pragma unroll
        for (int q = 0; q < 8; q++) {
          union { ushort4 u; bf16 h[4]; } pk;
          #pragma unroll
          for (int jj = 0; jj < 4; jj++) pk.h[jj] = f2b(mp[(size_t)(q * 4 + jj) * 4096]);
          *(ushort4*)(smB + ((ryy * 66 + xr) * 64)
                      + ((((q >> 1) ^ (xr & 3)) << 4) | ((q & 1) << 3))) = pk.u;
        }
      }
    }
  };
  auto computeP = [&](int p) {
    int ky = p % 3;
    int yyw = y0 + wy + ky - 1;
    if ((unsigned)yyw >= 64u) return;
    const char* base = smA + (p & 1) * 24576;
    #pragma unroll
    for (int kx = 0; kx < 3; kx++) {
      short8 af[4], bv[4];
      #pragma unroll
      for (int mi = 0; mi < 4; mi++) {
        int ocl = wocg * 64 + mi * 16 + ln;
        af[mi] = *(const short8*)(base + (kx * 128 + ocl) * 64 + ((qd ^ (ln & 3)) << 4));
      }
      #pragma unroll
      for (int ni = 0; ni < 4; ni++) {
        int xr = ni * 16 + ln + kx;
        bv[ni] = *(const short8*)(smB + ((wy + ky) * 66 + xr) * 64 + ((qd ^ (xr & 3)) << 4));
      }
      #pragma unroll
      for (int mi = 0; mi < 2; mi++)
        #pragma unroll
        for (int ni = 0; ni < 4; ni++)
          acc[mi][ni] = __builtin_amdgcn_mfma_f32_16x16x32_bf16(af[mi], bv[ni], acc[mi][ni], 0, 0, 0);
      #pragma unroll
      for (int mi = 2; mi < 4; mi++)
        #pragma unroll
        for (int ni = 0; ni < 4; ni++)
          acc[mi][ni] = __builtin_amdgcn_mfma_f32_16x16x32_bf16(af[mi], bv[ni], acc[mi][ni], 0, 0, 0);
    }
  };

  stageB(0);
  stageA(0);
  __syncthreads();
  for (int p = 0; p < NPH; p++) {
    if (p + 1 < NPH && (p + 1) % 3 != 0) stageA(p + 1);
    computeP(p);
    __syncthreads();
    if (p + 1 < NPH && (p + 1) % 3 == 0) {
      stageA(p + 1);
      stageB((p + 1) / 3);
      __syncthreads();
    }
  }

  {
    bf16* EP = (bf16*)smem;   // [2 wy][64 x][128 ocl]
    #pragma unroll
    for (int mi = 0; mi < 4; mi++) {
      int oclb = wocg * 64 + mi * 16 + qd * 4;
      float sc[4], bt[4];
      #pragma unroll
      for (int r = 0; r < 4; r++) {
        int oc = oc0 + oclb + r;
        sc[r] = g[oc] * rsqrtf(1.f + EPSV);
        bt[r] = bb[oc];
      }
      #pragma unroll
      for (int ni = 0; ni < 4; ni++) {
        int x = ni * 16 + ln;
        union { ushort4 u; bf16 h[4]; } pk;
        #pragma unroll
        for (int r = 0; r < 4; r++)
          pk.h[r] = f2b(fmaxf(acc[mi][ni][r] * sc[r] + bt[r], 0.f));
        *(ushort4*)&EP[(wy * 64 + x) * 128 + oclb] = pk.u;
      }
    }
    __syncthreads();
    int p2 = tid >> 1, hh = tid & 1;
    int wy2 = p2 >> 6, x = p2 & 63;
    size_t gb = ((size_t)((b * 64 + y0 + wy2) * 64 + x)) * Cos + oc0 + hh * 64;
    const bf16* row = &EP[p2 * 128 + hh * 64];
    #pragma unroll
    for (int k = 0; k < 8; k++)
      *(short8*)(out + gb + k * 8) = *(const short8*)(row + k * 8);
  }
}

// ===== final 1x1 (512->19) from NHWC X3 ====================================
__global__ __launch_bounds__(256) void k_final(const bf16* __restrict__ X3,
        const float* __restrict__ dw, float* __restrict__ out) {
  int tid = threadIdx.x;
  int b = blockIdx.x >> 6, y = blockIdx.x & 63;
  __shared__ float W[19 * 512];
  for (int i = tid; i < 19 * 512; i += 256) W[i] = dw[i];
  __syncthreads();
  int x = tid & 63, kg = tid >> 6;
  const bf16* px = X3 + (((size_t)(b * 64 + y) * 64) + x) * 512;
  float acc[5] = {0.f, 0.f, 0.f, 0.f, 0.f};
  for (int c8 = 0; c8 < 512; c8 += 8) {
    union { short8 s; bf16 h[8]; } v;
    v.s = *(const short8*)(px + c8);
    float f[8];
    #pragma unroll
    for (int j = 0; j < 8; j++) f[j] = b2f(v.h[j]);
    #pragma unroll
    for (int i = 0; i < 5; i++) {
      int k = kg * 5 + i;
      if (k < 19) {
        const float* wr = &W[k * 512 + c8];
        #pragma unroll
        for (int j = 0; j < 8; j++) acc[i] += f[j] * wr[j];
      }
    }
  }
  for (int i = 0; i < 5; i++) {
    int k = kg * 5 + i;
    if (k < 19) out[((size_t)(b * 19 + k) * 64 + y) * 64 + x] = acc[i];
  }
}

extern "C" void kernel_launch(void* const* d_in, const int* in_sizes, int n_in,
                              void* d_out, int out_size, void* d_ws, size_t ws_size,
                              hipStream_t stream) {
  (void)in_sizes; (void)n_in; (void)out_size;
  const float* M1 = (const float*)d_in[0];
  const float* F  = (const float*)d_in[1];
  const float* Iin= (const float*)d_in[2];
  const float* R  = (const float*)d_in[3];
  const float* w1 = (const float*)d_in[4];
  const float* w2 = (const float*)d_in[5];
  const float* fw = (const float*)d_in[6];
  const float* fb = (const float*)d_in[7];
  const float* qw = (const float*)d_in[8];
  const float* qb = (const float*)d_in[9];
  const float* kw = (const float*)d_in[10];
  const float* kb = (const float*)d_in[11];
  const float* vw = (const float*)d_in[12];
  const float* vb = (const float*)d_in[13];
  const float* c1 = (const float*)d_in[14];
  const float* g1 = (const float*)d_in[15];
  const float* b1 = (const float*)d_in[16];
  const float* c2 = (const float*)d_in[17];
  const float* g2 = (const float*)d_in[18];
  const float* b2 = (const float*)d_in[19];
  const float* c3 = (const float*)d_in[20];
  const float* g3 = (const float*)d_in[21];
  const float* b3 = (const float*)d_in[22];
  const float* dw = (const float*)d_in[23];

  char* ws = (char*)d_ws;
  bool fast = ws_size >= (size_t)137363456ULL;

  bf16*  qwb  = (bf16*)(ws + 0);           //   262,144
  bf16*  kwb  = (bf16*)(ws + 262144);      //   262,144
  bf16*  w2b  = (bf16*)(ws + 524288);      //   524,288
  bf16*  c1b  = (bf16*)(ws + 1048576);     //   262,144
  bf16*  WT2  = (bf16*)(ws + 0);           //  4,718,592 (after conv1)
  bf16*  WT3  = (bf16*)(ws + 4718592);     // 23,592,960
  bf16*  FS   = (bf16*)(ws + 28311552);    //  8,388,608  NHWC (C=256)
  bf16*  FO1  = (bf16*)(ws + 36700160);    // 16,777,216  NHWC (C=512)
  bf16*  X2   = (bf16*)(ws + 53477376);    // 16,777,216  NHWC (C=512)
  bf16*  M1bf = fast ? (bf16*)(ws + 70254592) : nullptr;  // 67,108,864 NHWC
  bf16*  X3   = (bf16*)(ws + 28311552);    // overlay FS+FO1 (dead by then)
  bf16*  FP    = (bf16*) (ws + 53477376);  // X2 region
  float* QUERY = (float*)(ws + 70254592);  // 16,777,216
  float* FL0   = (float*)(ws + 87031808);  //  9,961,472
  bf16*  Hb    = (bf16*) (ws + 96993280);  //  4,980,736
  bf16*  FLb   = (bf16*) (ws + 101974016); //  4,980,736
  float* KEY   = (float*)(ws + 106954752); //  4,980,736
  float* VAL   = (float*)(ws + 111935488); //     77,824
  float* FL    = FL0;

  k_cast<<<128, 256, 0, stream>>>(qw, qwb, 32768);
  k_cast<<<128, 256, 0, stream>>>(kw, kwb, 32768);
  k_cast<<<256, 256, 0, stream>>>(w2, w2b, 65536);
  k_cast<<<128, 256, 0, stream>>>(c1, c1b, 32768);
  k_fp2<<<256, 256, 0, stream>>>(F, FP);
  k_flocal2<<<256, 256, 0, stream>>>(Iin, R, FP, FL0);
  k_lg1<<<dim3(38, 4), 256, 0, stream>>>(FL0, w1, Hb);
  k_gmm<1><<<dim3(38, 4), 256, 0, stream>>>(Hb, w2b, nullptr, FL, FLb, 512, 512,
                                            nullptr, nullptr, nullptr, nullptr);
  k_fusev<<<76, 256, 0, stream>>>(FL, fw, fb, vw, vb, VAL);
  k_gmm<0><<<dim3(38, 2), 256, 0, stream>>>(FLb, kwb, kb, KEY, nullptr, 256, 512,
                                            nullptr, nullptr, nullptr, nullptr);
  k_gmm<0><<<dim3(128, 2), 256, 0, stream>>>(FP, qwb, qb, QUERY, nullptr, 256, 512,
                                             nullptr, nullptr, nullptr, nullptr);
  k_attn<<<256, 256, 0, stream>>>(QUERY, KEY, VAL, FS);
  if (fast) k_m1t<<<dim3(256, 32), 256, 0, stream>>>(M1, M1bf);
  k_gmm<2><<<dim3(4, 128), 256, 0, stream>>>(c1b, FS, nullptr, nullptr, nullptr,
                                             16384, 256, g1, b1, F, FO1);
  k_wtr<<<dim3(512, 4),  256, 0, stream>>>(c2, WT2, 512);
  k_wtr<<<dim3(512, 20), 256, 0, stream>>>(c3, WT3, 2560);
  k_conv3<<<512, 256, 0, stream>>>(FO1, 512, nullptr, nullptr, 0,
                                   WT2, g2, b2, X2, 512);
  k_conv3<<<512, 256, 0, stream>>>(X2, 512, M1bf, M1, 2048,
                                   WT3, g3, b3, X3, 512);
  k_final<<<256, 256, 0, stream>>>(X3, dw, (float*)d_out);
}

// Round 5
// 1047.942 us; speedup vs baseline: 6.6282x; 1.0426x over previous
//
#include <hip/hip_runtime.h>
#include <hip/hip_bf16.h>

typedef __hip_bfloat16 bf16;
using short8 = __attribute__((ext_vector_type(8))) short;
using f32x4  = __attribute__((ext_vector_type(4))) float;

__device__ __forceinline__ float b2f(bf16 v){ return __bfloat162float(v); }
__device__ __forceinline__ bf16  f2b(float v){ return __float2bfloat16(v); }

#define EPSV 1e-5f

// async global->LDS, 16B/lane, dest = wave-uniform base + lane*16
__device__ __forceinline__ void gload16(const void* g, void* l) {
  __builtin_amdgcn_global_load_lds(
      (const __attribute__((address_space(1))) unsigned int*)g,
      (__attribute__((address_space(3))) unsigned int*)l, 16, 0, 0);
}

// ===== f32 -> bf16 flat cast (n4 = count/4) ================================
__global__ __launch_bounds__(256) void k_cast(const float* __restrict__ in,
                                              bf16* __restrict__ out, int n4) {
  int i = blockIdx.x * 256 + threadIdx.x;
  if (i < n4) {
    float4 v = ((const float4*)in)[i];
    union { ushort4 u; bf16 h[4]; } o;
    o.h[0] = f2b(v.x); o.h[1] = f2b(v.y); o.h[2] = f2b(v.z); o.h[3] = f2b(v.w);
    ((ushort4*)out)[i] = o.u;
  }
}

// ===== weight reshape: w [OC=512][CI][3][3] f32 -> WT [9][512][CI] bf16 ====
__global__ __launch_bounds__(256) void k_wtr(const float* __restrict__ w,
                                             bf16* __restrict__ wt, int CI) {
  int oc = blockIdx.x, c0 = blockIdx.y * 128;
  __shared__ float ld[128 * 9];
  const float* src = w + ((size_t)oc * CI + c0) * 9;
  for (int i = threadIdx.x; i < 128 * 9; i += 256) ld[i] = src[i];
  __syncthreads();
  for (int i = threadIdx.x; i < 128 * 9; i += 256) {
    int k9 = i / 128, t = i - k9 * 128;
    wt[((size_t)k9 * 512 + oc) * CI + c0 + t] = f2b(ld[t * 9 + k9]);
  }
}

// ===== M1 NCHW f32 -> NHWC bf16 [4][64][64][2048] (fast path only) =========
__global__ __launch_bounds__(256) void k_m1t(const float* __restrict__ M1,
                                             bf16* __restrict__ M1b) {
  int b = blockIdx.x >> 6, y = blockIdx.x & 63;
  int c0 = blockIdx.y * 64;
  __shared__ float t[64][65];
  for (int i = threadIdx.x; i < 4096; i += 256) {
    int cc = i >> 6, x = i & 63;
    t[x][cc] = M1[((size_t)(b * 2048 + c0 + cc) * 64 + y) * 64 + x];
  }
  __syncthreads();
  for (int i = threadIdx.x; i < 4096; i += 256) {
    int x = i >> 6, cc = i & 63;
    M1b[((size_t)((b * 64 + y) * 64 + x)) * 2048 + c0 + cc] = f2b(t[x][cc]);
  }
}

// ===== F (NCHW f32) -> FP (b,p,n,c) bf16 via LDS transpose =================
__global__ __launch_bounds__(256) void k_fp2(const float* __restrict__ F,
                                             bf16* __restrict__ FP) {
  int b = blockIdx.x >> 6, y = blockIdx.x & 63;
  int tid = threadIdx.x;
  __shared__ float t[256][65];
  int p_hi = (y >> 3) << 3, n_hi = (y & 7) << 3;
  for (int half = 0; half < 2; half++) {
    int c0 = half << 8;
    for (int i = tid; i < 256 * 64; i += 256) {
      int cc = i >> 6, x = i & 63;
      t[cc][x] = F[((size_t)(b * 512 + c0 + cc) * 64 + y) * 64 + x];
    }
    __syncthreads();
    for (int x = 0; x < 64; x++) {
      int p = p_hi + (x >> 3), n = n_hi + (x & 7);
      FP[((size_t)(b * 64 + p)) * 32768 + n * 512 + c0 + tid] = f2b(t[tid][x]);
    }
    __syncthreads();
  }
}

// ===== softmax(I); FL0 = (bc*pix) @ FP  with FP slice in LDS ===============
__global__ __launch_bounds__(256) void k_flocal2(const float* __restrict__ I,
        const float* __restrict__ R, const bf16* __restrict__ FP,
        float* __restrict__ FL0) {
  int bp = blockIdx.x, b = bp >> 6, p = bp & 63;
  int tid = threadIdx.x, w = tid >> 6, lane = tid & 63;
  __shared__ __align__(16) bf16 fps[64 * 512];   // 64 KB
  __shared__ float pix[19][64];
  __shared__ float bc[19];
  {
    const bf16* src = FP + (size_t)bp * 32768 + lane * 8;
    #pragma unroll
    for (int t = 0; t < 16; t++) {
      int chunk = w + t * 4;
      gload16(src + chunk * 512, (char*)fps + chunk * 1024);
    }
  }
  int py = (p >> 3) * 8, px = (p & 7) * 8;
  for (int i = tid; i < 19 * 64; i += 256) {
    int k = i >> 6, n = i & 63;
    int y = py + (n >> 3), x = px + (n & 7);
    pix[k][n] = I[((size_t)(b * 19 + k) * 64 + y) * 64 + x];
  }
  if (tid < 19) bc[tid] = R[(size_t)(b * 19 + tid) * 64 + p];
  __syncthreads();
  if (tid < 19) {
    float mx = -1e30f;
    for (int n = 0; n < 64; n++) mx = fmaxf(mx, pix[tid][n]);
    float s = 0.f;
    for (int n = 0; n < 64; n++) { float e = __expf(pix[tid][n] - mx); pix[tid][n] = e; s += e; }
    float sc = bc[tid] / s;
    for (int n = 0; n < 64; n++) pix[tid][n] *= sc;
  }
  __syncthreads();
  for (int task = tid; task < 19 * 64; task += 256) {
    int k = task >> 6, c8 = (task & 63) << 3;
    float acc[8] = {};
    for (int n = 0; n < 64; n++) {
      float pv = pix[k][n];
      union { short8 s; bf16 h[8]; } v;
      v.s = *(const short8*)&fps[n * 512 + c8];
      #pragma unroll
      for (int j = 0; j < 8; j++) acc[j] += pv * b2f(v.h[j]);
    }
    float* dst = FL0 + ((size_t)(b * 64 + p) * 19 + k) * 512 + c8;
    #pragma unroll
    for (int j = 0; j < 8; j++) dst[j] = acc[j];
  }
}

// ===== LG part 1 (emits bf16 H) ============================================
__global__ __launch_bounds__(256) void k_lg1(const float* __restrict__ FL0,
        const float* __restrict__ w1, bf16* __restrict__ Hb) {
  int tid = threadIdx.x;
  int b = blockIdx.y;
  int n0 = blockIdx.x * 256;
  __shared__ float W[64][64];
  __shared__ float Xs[16][256];
  for (int i = tid; i < 4096; i += 256) W[i >> 6][i & 63] = w1[i];
  float acc[64];
  #pragma unroll
  for (int po = 0; po < 64; po++) acc[po] = 0.f;
  for (int q0 = 0; q0 < 64; q0 += 16) {
    __syncthreads();
    for (int i = tid; i < 4096; i += 256) {
      int q = i >> 8, j = i & 255;
      Xs[q][j] = FL0[(size_t)(b * 64 + q0 + q) * 9728 + n0 + j];
    }
    __syncthreads();
    for (int q = 0; q < 16; q++) {
      float xv = Xs[q][tid];
      #pragma unroll
      for (int po = 0; po < 64; po++) acc[po] += W[po][q0 + q] * xv;
    }
  }
  for (int po = 0; po < 64; po++) {
    float r = acc[po] + FL0[(size_t)(b * 64 + po) * 9728 + n0 + tid];
    Hb[(size_t)(b * 64 + po) * 9728 + n0 + tid] = f2b(fmaxf(r, 0.f));
  }
}

// ===== generic MFMA GEMM C[m][n] = sum_k A[m][k]*B[n][k] ===================
template<int MODE>
__global__ __launch_bounds__(256) void k_gmm(
    const bf16* __restrict__ A, const bf16* __restrict__ B,
    const float* __restrict__ bias, float* __restrict__ C,
    bf16* __restrict__ Cb, int N, int K,
    const float* __restrict__ g, const float* __restrict__ bb,
    const float* __restrict__ Fres, bf16* __restrict__ outb) {
  int tid = threadIdx.x;
  int m0 = blockIdx.x * 128, n0 = blockIdx.y * 128;
  int w = tid >> 6, lane = tid & 63, ln = lane & 15, qd = lane >> 4;
  int wm = w & 1, wn = w >> 1;
  __shared__ __align__(16) char smem[34816]; // staging 2x16KB | EP 128*136*2

  f32x4 acc[4][4];
  #pragma unroll
  for (int i = 0; i < 4; i++)
    #pragma unroll
    for (int j = 0; j < 4; j++) acc[i][j] = (f32x4){0.f, 0.f, 0.f, 0.f};

  int rsub = lane >> 2, ch = lane & 3;
  auto stage = [&](int p) {
    char* base = smem + (p & 1) * 16384;
    int k0 = p << 5;
    #pragma unroll
    for (int t = 0; t < 2; t++) {
      int ii = w + t * 4;
      int r = ii * 16 + rsub;
      int sw = (ch ^ ((r >> 1) & 3)) << 3;
      gload16(A + (size_t)(m0 + r) * K + k0 + sw, base + ii * 1024);
      gload16(B + (size_t)(n0 + r) * K + k0 + sw, base + 8192 + ii * 1024);
    }
  };
  auto compute = [&](int p) {
    const char* base = smem + (p & 1) * 16384;
    short8 af[4], bv[4];
    #pragma unroll
    for (int mi = 0; mi < 4; mi++) {
      int r = wm * 64 + mi * 16 + ln;
      af[mi] = *(const short8*)(base + r * 64 + ((qd ^ ((r >> 1) & 3)) << 4));
    }
    #pragma unroll
    for (int ni = 0; ni < 4; ni++) {
      int r = wn * 64 + ni * 16 + ln;
      bv[ni] = *(const short8*)(base + 8192 + r * 64 + ((qd ^ ((r >> 1) & 3)) << 4));
    }
    #pragma unroll
    for (int mi = 0; mi < 4; mi++)
      #pragma unroll
      for (int ni = 0; ni < 4; ni++)
        acc[mi][ni] = __builtin_amdgcn_mfma_f32_16x16x32_bf16(
            af[mi], bv[ni], acc[mi][ni], 0, 0, 0);
  };

  int KT = K >> 5;
  stage(0);
  __syncthreads();
  for (int p = 0; p < KT; p++) {
    if (p + 1 < KT) stage(p + 1);
    compute(p);
    __syncthreads();
  }

  if (MODE <= 1) {
    #pragma unroll
    for (int mi = 0; mi < 4; mi++) {
      #pragma unroll
      for (int r = 0; r < 4; r++) {
        int m = m0 + wm * 64 + mi * 16 + qd * 4 + r;
        #pragma unroll
        for (int ni = 0; ni < 4; ni++) {
          int n = n0 + wn * 64 + ni * 16 + ln;
          float v = acc[mi][ni][r];
          if (bias) v += bias[n];
          C[(size_t)m * N + n] = v;
          if (MODE == 1) Cb[(size_t)m * N + n] = f2b(v);
        }
      }
    }
  } else {
    bf16* EP = (bf16*)smem;  // [128 pix][136 oc-padded]
    int b = n0 >> 12;
    #pragma unroll
    for (int mi = 0; mi < 4; mi++) {
      #pragma unroll
      for (int r = 0; r < 4; r++) {
        int ml = wm * 64 + mi * 16 + qd * 4 + r;
        int oc = m0 + ml;
        float sc = g[oc] * rsqrtf(1.f + EPSV);
        float bt = bb[oc];
        #pragma unroll
        for (int ni = 0; ni < 4; ni++) {
          int nl = wn * 64 + ni * 16 + ln;
          int pix = n0 + nl;
          int y = (pix >> 6) & 63, x = pix & 63;
          float v = fmaxf(acc[mi][ni][r] * sc + bt, 0.f)
                  + Fres[((size_t)(b * 512 + oc) * 64 + y) * 64 + x];
          EP[nl * 136 + ml] = f2b(v);
        }
      }
    }
    __syncthreads();
    int pl = tid >> 1, half = tid & 1;
    size_t gb = (size_t)(n0 + pl) * 512 + m0 + half * 64;
    const bf16* row = &EP[pl * 136 + half * 64];
    #pragma unroll
    for (int j2 = 0; j2 < 8; j2++)
      *(short8*)(outb + gb + j2 * 8) = *(const short8*)(row + j2 * 8);
  }
}

// ===== fuse + value (float4 vw/fg) =========================================
__global__ __launch_bounds__(256) void k_fusev(const float* __restrict__ FL,
        const float* __restrict__ fw, const float* __restrict__ fbv,
        const float* __restrict__ vw, const float* __restrict__ vb,
        float* __restrict__ VAL) {
  int tid = threadIdx.x;
  int bk = blockIdx.x, b = bk / 19, k = bk % 19;
  __shared__ float fwl[64];
  __shared__ __align__(16) float fg[512];
  if (tid < 64) fwl[tid] = fw[tid];
  __syncthreads();
  float fbias = fbv[0];
  for (int c = tid; c < 512; c += 256) {
    float s = 0.f;
    for (int p = 0; p < 64; p++)
      s += fwl[p] * FL[((size_t)(b * 64 + p) * 19 + k) * 512 + c];
    fg[c] = s + fbias;
  }
  __syncthreads();
  int d = tid;
  float s = vb[d];
  const float4* vr = (const float4*)(vw + (size_t)d * 512);
  const float4* fr = (const float4*)fg;
  for (int c4 = 0; c4 < 128; c4++) {
    float4 wv = vr[c4], f = fr[c4];
    s += f.x * wv.x + f.y * wv.y + f.z * wv.z + f.w * wv.w;
  }
  VAL[(size_t)bk * 256 + d] = s;
}

// ===== per-patch attention -> FS NHWC bf16 (C=256), coalesced stores =======
__global__ __launch_bounds__(256) void k_attn(const float* __restrict__ Q,
        const float* __restrict__ KEY, const float* __restrict__ VAL,
        bf16* __restrict__ FS) {
  int tid = threadIdx.x;
  int bp = blockIdx.x, b = bp >> 6, p = bp & 63;
  __shared__ __align__(16) float ks[19][256];
  __shared__ __align__(16) float vs[19][256];
  __shared__ float Ss[64][20];
  __shared__ bf16 ot[64][256];
  for (int i = tid; i < 19 * 256; i += 256) {
    ks[i >> 8][i & 255] = KEY[(size_t)bp * 19 * 256 + i];
    vs[i >> 8][i & 255] = VAL[(size_t)b * 19 * 256 + i];
  }
  __syncthreads();
  {
    int n = tid >> 2, kq = tid & 3;
    const float4* qrow = (const float4*)(Q + ((size_t)bp * 64 + n) * 256);
    for (int k = kq; k < 19; k += 4) {
      const float4* kr = (const float4*)&ks[k][0];
      float s = 0.f;
      for (int d4 = 0; d4 < 64; d4++) {
        float4 qv = qrow[d4], kv = kr[d4];
        s += qv.x * kv.x + qv.y * kv.y + qv.z * kv.z + qv.w * kv.w;
      }
      Ss[n][k] = s;
    }
  }
  __syncthreads();
  if (tid < 64) {
    float mx = -1e30f;
    for (int k = 0; k < 19; k++) mx = fmaxf(mx, Ss[tid][k]);
    float sum = 0.f;
    for (int k = 0; k < 19; k++) { float e = __expf(Ss[tid][k] - mx); Ss[tid][k] = e; sum += e; }
    float inv = 1.f / sum;
    for (int k = 0; k < 19; k++) Ss[tid][k] *= inv;
  }
  __syncthreads();
  {
    int d = tid;
    for (int nn = 0; nn < 64; nn++) {
      float s = 0.f;
      #pragma unroll
      for (int k = 0; k < 19; k++) s += Ss[nn][k] * vs[k][d];
      ot[nn][d] = f2b(s);
    }
  }
  __syncthreads();
  {
    int py = (p >> 3) * 8, px = (p & 7) * 8;
    int nn = tid >> 2, q = tid & 3;
    int y = py + (nn >> 3), x = px + (nn & 7);
    size_t gb = (((size_t)(b * 64 + y) * 64) + x) * 256 + q * 64;
    const bf16* row = &ot[nn][q * 64];
    #pragma unroll
    for (int j = 0; j < 8; j++)
      *(short8*)(FS + gb + j * 8) = *(const short8*)(row + j * 8);
  }
}

// ===== MFMA conv3x3 pad1, NHWC in/out ======================================
// block = 128oc x 4y x 64x, 4 waves (2ocg x 2yp), wave = 64oc x (2y*64x=128n)
// = 4x8 frags of 16x16x32. B staged once per c0 ([6 rows][66 x][32 k]),
// y-halo rows pre-zeroed (W*0 = pad). Swizzle (r>>1)&3: 2-way max conflicts.
__global__ __launch_bounds__(256) void k_conv3(
    const bf16* __restrict__ Xin, int Cin,
    const bf16* __restrict__ M1b, const float* __restrict__ M1f, int C2,
    const bf16* __restrict__ WT,
    const float* __restrict__ g, const float* __restrict__ bb,
    bf16* __restrict__ out, int Cos) {
  int tid = threadIdx.x;
  int b = blockIdx.x >> 4, y0 = (blockIdx.x & 15) * 4;
  int oc0 = blockIdx.y * 128;
  int w = tid >> 6, lane = tid & 63, ln = lane & 15, qd = lane >> 4;
  int wocg = w & 1, wyp = w >> 1;
  int Ct = Cin + C2;

  __shared__ __align__(16) char smem[49152 + 25344];
  char* smA = smem;            // Aw[2][3][128][32] bf16, rows of 64B
  char* smB = smem + 49152;    // Bs[6][66][32] bf16, rows of 64B

  // zero x-halo cols (xr = 0, 65) for all 6 rows
  for (int i = tid; i < 6 * 2 * 32; i += 256) {
    int rl = i >> 6, hh = (i >> 5) & 1, kk = i & 31;
    *(bf16*)(smB + (rl * 66 + (hh ? 65 : 0)) * 64 + kk * 2) = f2b(0.f);
  }
  // zero y-halo rows (stage always skips them -> they stay zero)
  if (y0 == 0)
    for (int i = tid; i < 66 * 16; i += 256) ((float*)smB)[i] = 0.f;
  if (y0 == 60)
    for (int i = tid; i < 66 * 16; i += 256)
      ((float*)(smB + 5 * 66 * 64))[i] = 0.f;

  f32x4 acc[4][8];
  #pragma unroll
  for (int i = 0; i < 4; i++)
    #pragma unroll
    for (int j = 0; j < 8; j++) acc[i][j] = (f32x4){0.f, 0.f, 0.f, 0.f};

  int NPH = (Ct >> 5) * 3;

  auto stageA = [&](int p) {
    int c0 = (p / 3) << 5, ky = p % 3;
    char* base = smA + (p & 1) * 24576;
    int j = w;
    #pragma unroll
    for (int t = 0; t < 6; t++, j += 4) {
      int kx = j >> 3, i8 = j & 7;
      int ocl = i8 * 16 + (lane >> 2);
      const bf16* src = WT + ((size_t)((ky * 3 + kx) * 512 + oc0 + ocl) * Ct + c0)
                      + (((lane & 3) ^ ((ocl >> 1) & 3)) << 3);
      gload16(src, base + (kx * 128 + i8 * 16) * 64);
    }
  };
  auto stageB = [&](int gi) {
    int c0 = gi << 5;
    if (c0 < Cin || M1b != nullptr) {
      const bf16* T; int Cs, cb;
      if (c0 < Cin) { T = Xin; Cs = Cin; cb = c0; }
      else          { T = M1b; Cs = C2;  cb = c0 - Cin; }
      int j = w;
      #pragma unroll
      for (int t = 0; t < 6; t++, j += 4) {
        int rl = j >> 2, i4 = j & 3;
        int yy = y0 + rl - 1;
        if ((unsigned)yy < 64u) {
          int xx = i4 * 16 + (lane >> 2), xr = xx + 1;
          const bf16* src = T + ((size_t)((b * 64 + yy) * 64 + xx) * Cs + cb)
                          + (((lane & 3) ^ ((xr >> 1) & 3)) << 3);
          gload16(src, smB + (rl * 66 + 1 + i4 * 16) * 64);
        }
      }
    } else {
      // slow fallback: transpose M1 f32 NCHW in-register (ws too small)
      #pragma unroll
      for (int t = 0; t < 2; t++) {
        int rl = w + t * 4;
        if (rl < 6) {
          int yy = y0 + rl - 1;
          if ((unsigned)yy < 64u) {
            int xx = lane, xr = xx + 1;
            const float* mp = M1f + ((size_t)(b * 2048 + (c0 - Cin)) * 64 + yy) * 64 + xx;
            #pragma unroll
            for (int q = 0; q < 8; q++) {
              union { ushort4 u; bf16 h[4]; } pk;
              #pragma unroll
              for (int jj = 0; jj < 4; jj++) pk.h[jj] = f2b(mp[(size_t)(q * 4 + jj) * 4096]);
              *(ushort4*)(smB + (rl * 66 + xr) * 64
                          + ((((q >> 1) ^ ((xr >> 1) & 3)) << 4) | ((q & 1) << 3))) = pk.u;
            }
          }
        }
      }
    }
  };
  auto computeP = [&](int p) {
    int ky = p % 3;
    const char* base = smA + (p & 1) * 24576;
    int rl0 = 2 * wyp + ky;   // lds rows rl0, rl0+1 (0..5)
    #pragma unroll
    for (int kx = 0; kx < 3; kx++) {
      short8 af[4], bv[8];
      #pragma unroll
      for (int mi = 0; mi < 4; mi++) {
        int ocl = wocg * 64 + mi * 16 + ln;
        af[mi] = *(const short8*)(base + (kx * 128 + ocl) * 64
                                  + ((qd ^ ((ocl >> 1) & 3)) << 4));
      }
      #pragma unroll
      for (int ni = 0; ni < 8; ni++) {
        int rl = rl0 + (ni >> 2);
        int xr = (ni & 3) * 16 + ln + kx;
        bv[ni] = *(const short8*)(smB + (rl * 66 + xr) * 64
                                  + ((qd ^ ((xr >> 1) & 3)) << 4));
      }
      #pragma unroll
      for (int mi = 0; mi < 4; mi++)
        #pragma unroll
        for (int ni = 0; ni < 8; ni++)
          acc[mi][ni] = __builtin_amdgcn_mfma_f32_16x16x32_bf16(
              af[mi], bv[ni], acc[mi][ni], 0, 0, 0);
    }
  };

  stageB(0);
  stageA(0);
  __syncthreads();
  for (int p = 0; p < NPH; p++) {
    if (p + 1 < NPH && (p + 1) % 3 != 0) stageA(p + 1);
    computeP(p);
    __syncthreads();
    if (p + 1 < NPH && (p + 1) % 3 == 0) {
      stageA(p + 1);
      stageB((p + 1) / 3);
      __syncthreads();
    }
  }

  // epilogue: BN+ReLU, LDS transpose -> coalesced NHWC stores
  {
    bf16* EP = (bf16*)smem;   // [4y][64x][128 ocl] = 64 KB
    #pragma unroll
    for (int mi = 0; mi < 4; mi++) {
      int oclb = wocg * 64 + mi * 16 + qd * 4;
      float sc[4], bt[4];
      #pragma unroll
      for (int r = 0; r < 4; r++) {
        int oc = oc0 + oclb + r;
        sc[r] = g[oc] * rsqrtf(1.f + EPSV);
        bt[r] = bb[oc];
      }
      #pragma unroll
      for (int ni = 0; ni < 8; ni++) {
        int yloc = 2 * wyp + (ni >> 2), x = (ni & 3) * 16 + ln;
        union { ushort4 u; bf16 h[4]; } pk;
        #pragma unroll
        for (int r = 0; r < 4; r++)
          pk.h[r] = f2b(fmaxf(acc[mi][ni][r] * sc[r] + bt[r], 0.f));
        *(ushort4*)&EP[(yloc * 64 + x) * 128 + oclb] = pk.u;
      }
    }
    __syncthreads();
    int p2 = tid >> 1, hh = tid & 1;
    #pragma unroll
    for (int pp = 0; pp < 2; pp++) {
      int pixl = pp * 128 + p2;
      int yloc = pixl >> 6, x = pixl & 63;
      size_t gb = ((size_t)((b * 64 + y0 + yloc) * 64 + x)) * Cos + oc0 + hh * 64;
      const bf16* row = &EP[pixl * 128 + hh * 64];
      #pragma unroll
      for (int k = 0; k < 8; k++)
        *(short8*)(out + gb + k * 8) = *(const short8*)(row + k * 8);
    }
  }
}

// ===== final 1x1 (512->19) from NHWC X3 ====================================
__global__ __launch_bounds__(256) void k_final(const bf16* __restrict__ X3,
        const float* __restrict__ dw, float* __restrict__ out) {
  int tid = threadIdx.x;
  int b = blockIdx.x >> 6, y = blockIdx.x & 63;
  __shared__ float W[19 * 512];
  for (int i = tid; i < 19 * 512; i += 256) W[i] = dw[i];
  __syncthreads();
  int x = tid & 63, kg = tid >> 6;
  const bf16* px = X3 + (((size_t)(b * 64 + y) * 64) + x) * 512;
  float acc[5] = {0.f, 0.f, 0.f, 0.f, 0.f};
  for (int c8 = 0; c8 < 512; c8 += 8) {
    union { short8 s; bf16 h[8]; } v;
    v.s = *(const short8*)(px + c8);
    float f[8];
    #pragma unroll
    for (int j = 0; j < 8; j++) f[j] = b2f(v.h[j]);
    #pragma unroll
    for (int i = 0; i < 5; i++) {
      int k = kg * 5 + i;
      if (k < 19) {
        const float* wr = &W[k * 512 + c8];
        #pragma unroll
        for (int j = 0; j < 8; j++) acc[i] += f[j] * wr[j];
      }
    }
  }
  for (int i = 0; i < 5; i++) {
    int k = kg * 5 + i;
    if (k < 19) out[((size_t)(b * 19 + k) * 64 + y) * 64 + x] = acc[i];
  }
}

extern "C" void kernel_launch(void* const* d_in, const int* in_sizes, int n_in,
                              void* d_out, int out_size, void* d_ws, size_t ws_size,
                              hipStream_t stream) {
  (void)in_sizes; (void)n_in; (void)out_size;
  const float* M1 = (const float*)d_in[0];
  const float* F  = (const float*)d_in[1];
  const float* Iin= (const float*)d_in[2];
  const float* R  = (const float*)d_in[3];
  const float* w1 = (const float*)d_in[4];
  const float* w2 = (const float*)d_in[5];
  const float* fw = (const float*)d_in[6];
  const float* fb = (const float*)d_in[7];
  const float* qw = (const float*)d_in[8];
  const float* qb = (const float*)d_in[9];
  const float* kw = (const float*)d_in[10];
  const float* kb = (const float*)d_in[11];
  const float* vw = (const float*)d_in[12];
  const float* vb = (const float*)d_in[13];
  const float* c1 = (const float*)d_in[14];
  const float* g1 = (const float*)d_in[15];
  const float* b1 = (const float*)d_in[16];
  const float* c2 = (const float*)d_in[17];
  const float* g2 = (const float*)d_in[18];
  const float* b2 = (const float*)d_in[19];
  const float* c3 = (const float*)d_in[20];
  const float* g3 = (const float*)d_in[21];
  const float* b3 = (const float*)d_in[22];
  const float* dw = (const float*)d_in[23];

  char* ws = (char*)d_ws;
  bool fast = ws_size >= (size_t)137363456ULL;

  bf16*  qwb  = (bf16*)(ws + 0);           //   262,144
  bf16*  kwb  = (bf16*)(ws + 262144);      //   262,144
  bf16*  w2b  = (bf16*)(ws + 524288);      //   524,288
  bf16*  c1b  = (bf16*)(ws + 1048576);     //   262,144
  bf16*  WT2  = (bf16*)(ws + 0);           //  4,718,592 (after conv1)
  bf16*  WT3  = (bf16*)(ws + 4718592);     // 23,592,960
  bf16*  FS   = (bf16*)(ws + 28311552);    //  8,388,608  NHWC (C=256)
  bf16*  FO1  = (bf16*)(ws + 36700160);    // 16,777,216  NHWC (C=512)
  bf16*  X2   = (bf16*)(ws + 53477376);    // 16,777,216  NHWC (C=512)
  bf16*  M1bf = fast ? (bf16*)(ws + 70254592) : nullptr;  // 67,108,864 NHWC
  bf16*  X3   = (bf16*)(ws + 28311552);    // overlay FS+FO1 (dead by then)
  bf16*  FP    = (bf16*) (ws + 53477376);  // X2 region
  float* QUERY = (float*)(ws + 70254592);  // 16,777,216
  float* FL0   = (float*)(ws + 87031808);  //  9,961,472
  bf16*  Hb    = (bf16*) (ws + 96993280);  //  4,980,736
  bf16*  FLb   = (bf16*) (ws + 101974016); //  4,980,736
  float* KEY   = (float*)(ws + 106954752); //  4,980,736
  float* VAL   = (float*)(ws + 111935488); //     77,824
  float* FL    = FL0;

  k_cast<<<128, 256, 0, stream>>>(qw, qwb, 32768);
  k_cast<<<128, 256, 0, stream>>>(kw, kwb, 32768);
  k_cast<<<256, 256, 0, stream>>>(w2, w2b, 65536);
  k_cast<<<128, 256, 0, stream>>>(c1, c1b, 32768);
  k_fp2<<<256, 256, 0, stream>>>(F, FP);
  k_flocal2<<<256, 256, 0, stream>>>(Iin, R, FP, FL0);
  k_lg1<<<dim3(38, 4), 256, 0, stream>>>(FL0, w1, Hb);
  k_gmm<1><<<dim3(38, 4), 256, 0, stream>>>(Hb, w2b, nullptr, FL, FLb, 512, 512,
                                            nullptr, nullptr, nullptr, nullptr);
  k_fusev<<<76, 256, 0, stream>>>(FL, fw, fb, vw, vb, VAL);
  k_gmm<0><<<dim3(38, 2), 256, 0, stream>>>(FLb, kwb, kb, KEY, nullptr, 256, 512,
                                            nullptr, nullptr, nullptr, nullptr);
  k_gmm<0><<<dim3(128, 2), 256, 0, stream>>>(FP, qwb, qb, QUERY, nullptr, 256, 512,
                                             nullptr, nullptr, nullptr, nullptr);
  k_attn<<<256, 256, 0, stream>>>(QUERY, KEY, VAL, FS);
  if (fast) k_m1t<<<dim3(256, 32), 256, 0, stream>>>(M1, M1bf);
  k_gmm<2><<<dim3(4, 128), 256, 0, stream>>>(c1b, FS, nullptr, nullptr, nullptr,
                                             16384, 256, g1, b1, F, FO1);
  k_wtr<<<dim3(512, 4),  256, 0, stream>>>(c2, WT2, 512);
  k_wtr<<<dim3(512, 20), 256, 0, stream>>>(c3, WT3, 2560);
  k_conv3<<<dim3(64, 4), 256, 0, stream>>>(FO1, 512, nullptr, nullptr, 0,
                                           WT2, g2, b2, X2, 512);
  k_conv3<<<dim3(64, 4), 256, 0, stream>>>(X2, 512, M1bf, M1, 2048,
                                           WT3, g3, b3, X3, 512);
  k_final<<<256, 256, 0, stream>>>(X3, dw, (float*)d_out);
}

// Round 6
// 1018.768 us; speedup vs baseline: 6.8180x; 1.0286x over previous
//
#include <hip/hip_runtime.h>
#include <hip/hip_bf16.h>

typedef __hip_bfloat16 bf16;
using short8 = __attribute__((ext_vector_type(8))) short;
using f32x4  = __attribute__((ext_vector_type(4))) float;

__device__ __forceinline__ float b2f(bf16 v){ return __bfloat162float(v); }
__device__ __forceinline__ bf16  f2b(float v){ return __float2bfloat16(v); }

#define EPSV 1e-5f

// async global->LDS, 16B/lane, dest = wave-uniform base + lane*16
__device__ __forceinline__ void gload16(const void* g, void* l) {
  __builtin_amdgcn_global_load_lds(
      (const __attribute__((address_space(1))) unsigned int*)g,
      (__attribute__((address_space(3))) unsigned int*)l, 16, 0, 0);
}

// ===== f32 -> bf16 flat cast (n4 = count/4) ================================
__global__ __launch_bounds__(256) void k_cast(const float* __restrict__ in,
                                              bf16* __restrict__ out, int n4) {
  int i = blockIdx.x * 256 + threadIdx.x;
  if (i < n4) {
    float4 v = ((const float4*)in)[i];
    union { ushort4 u; bf16 h[4]; } o;
    o.h[0] = f2b(v.x); o.h[1] = f2b(v.y); o.h[2] = f2b(v.z); o.h[3] = f2b(v.w);
    ((ushort4*)out)[i] = o.u;
  }
}

// ===== weight reshape: w [OC=512][CI][3][3] f32 -> WT [9][512][CI] bf16 ====
__global__ __launch_bounds__(256) void k_wtr(const float* __restrict__ w,
                                             bf16* __restrict__ wt, int CI) {
  int oc = blockIdx.x, c0 = blockIdx.y * 128;
  __shared__ float ld[128 * 9];
  const float* src = w + ((size_t)oc * CI + c0) * 9;
  for (int i = threadIdx.x; i < 128 * 9; i += 256) ld[i] = src[i];
  __syncthreads();
  for (int i = threadIdx.x; i < 128 * 9; i += 256) {
    int k9 = i / 128, t = i - k9 * 128;
    wt[((size_t)k9 * 512 + oc) * CI + c0 + t] = f2b(ld[t * 9 + k9]);
  }
}

// ===== M1 NCHW f32 -> NHWC bf16 [4][64][64][2048] (fast path only) =========
__global__ __launch_bounds__(256) void k_m1t(const float* __restrict__ M1,
                                             bf16* __restrict__ M1b) {
  int b = blockIdx.x >> 6, y = blockIdx.x & 63;
  int c0 = blockIdx.y * 64;
  __shared__ float t[64][65];
  for (int i = threadIdx.x; i < 4096; i += 256) {
    int cc = i >> 6, x = i & 63;
    t[x][cc] = M1[((size_t)(b * 2048 + c0 + cc) * 64 + y) * 64 + x];
  }
  __syncthreads();
  for (int i = threadIdx.x; i < 4096; i += 256) {
    int x = i >> 6, cc = i & 63;
    M1b[((size_t)((b * 64 + y) * 64 + x)) * 2048 + c0 + cc] = f2b(t[x][cc]);
  }
}

// ===== F (NCHW f32) -> FP (b,p,n,c) bf16 via LDS transpose =================
__global__ __launch_bounds__(256) void k_fp2(const float* __restrict__ F,
                                             bf16* __restrict__ FP) {
  int b = blockIdx.x >> 6, y = blockIdx.x & 63;
  int tid = threadIdx.x;
  __shared__ float t[256][65];
  int p_hi = (y >> 3) << 3, n_hi = (y & 7) << 3;
  for (int half = 0; half < 2; half++) {
    int c0 = half << 8;
    for (int i = tid; i < 256 * 64; i += 256) {
      int cc = i >> 6, x = i & 63;
      t[cc][x] = F[((size_t)(b * 512 + c0 + cc) * 64 + y) * 64 + x];
    }
    __syncthreads();
    for (int x = 0; x < 64; x++) {
      int p = p_hi + (x >> 3), n = n_hi + (x & 7);
      FP[((size_t)(b * 64 + p)) * 32768 + n * 512 + c0 + tid] = f2b(t[tid][x]);
    }
    __syncthreads();
  }
}

// ===== softmax(I); FL0 = (bc*pix) @ FP  with FP slice in LDS ===============
__global__ __launch_bounds__(256) void k_flocal2(const float* __restrict__ I,
        const float* __restrict__ R, const bf16* __restrict__ FP,
        float* __restrict__ FL0) {
  int bp = blockIdx.x, b = bp >> 6, p = bp & 63;
  int tid = threadIdx.x, w = tid >> 6, lane = tid & 63;
  __shared__ __align__(16) bf16 fps[64 * 512];   // 64 KB
  __shared__ float pix[19][64];
  __shared__ float bc[19];
  {
    const bf16* src = FP + (size_t)bp * 32768 + lane * 8;
    #pragma unroll
    for (int t = 0; t < 16; t++) {
      int chunk = w + t * 4;
      gload16(src + chunk * 512, (char*)fps + chunk * 1024);
    }
  }
  int py = (p >> 3) * 8, px = (p & 7) * 8;
  for (int i = tid; i < 19 * 64; i += 256) {
    int k = i >> 6, n = i & 63;
    int y = py + (n >> 3), x = px + (n & 7);
    pix[k][n] = I[((size_t)(b * 19 + k) * 64 + y) * 64 + x];
  }
  if (tid < 19) bc[tid] = R[(size_t)(b * 19 + tid) * 64 + p];
  __syncthreads();
  if (tid < 19) {
    float mx = -1e30f;
    for (int n = 0; n < 64; n++) mx = fmaxf(mx, pix[tid][n]);
    float s = 0.f;
    for (int n = 0; n < 64; n++) { float e = __expf(pix[tid][n] - mx); pix[tid][n] = e; s += e; }
    float sc = bc[tid] / s;
    for (int n = 0; n < 64; n++) pix[tid][n] *= sc;
  }
  __syncthreads();
  for (int task = tid; task < 19 * 64; task += 256) {
    int k = task >> 6, c8 = (task & 63) << 3;
    float acc[8] = {};
    for (int n = 0; n < 64; n++) {
      float pv = pix[k][n];
      union { short8 s; bf16 h[8]; } v;
      v.s = *(const short8*)&fps[n * 512 + c8];
      #pragma unroll
      for (int j = 0; j < 8; j++) acc[j] += pv * b2f(v.h[j]);
    }
    float* dst = FL0 + ((size_t)(b * 64 + p) * 19 + k) * 512 + c8;
    #pragma unroll
    for (int j = 0; j < 8; j++) dst[j] = acc[j];
  }
}

// ===== LG part 1 (emits bf16 H) ============================================
__global__ __launch_bounds__(256) void k_lg1(const float* __restrict__ FL0,
        const float* __restrict__ w1, bf16* __restrict__ Hb) {
  int tid = threadIdx.x;
  int b = blockIdx.y;
  int n0 = blockIdx.x * 256;
  __shared__ float W[64][64];
  __shared__ float Xs[16][256];
  for (int i = tid; i < 4096; i += 256) W[i >> 6][i & 63] = w1[i];
  float acc[64];
  #pragma unroll
  for (int po = 0; po < 64; po++) acc[po] = 0.f;
  for (int q0 = 0; q0 < 64; q0 += 16) {
    __syncthreads();
    for (int i = tid; i < 4096; i += 256) {
      int q = i >> 8, j = i & 255;
      Xs[q][j] = FL0[(size_t)(b * 64 + q0 + q) * 9728 + n0 + j];
    }
    __syncthreads();
    for (int q = 0; q < 16; q++) {
      float xv = Xs[q][tid];
      #pragma unroll
      for (int po = 0; po < 64; po++) acc[po] += W[po][q0 + q] * xv;
    }
  }
  for (int po = 0; po < 64; po++) {
    float r = acc[po] + FL0[(size_t)(b * 64 + po) * 9728 + n0 + tid];
    Hb[(size_t)(b * 64 + po) * 9728 + n0 + tid] = f2b(fmaxf(r, 0.f));
  }
}

// ===== generic MFMA GEMM C[m][n] = sum_k A[m][k]*B[n][k] ===================
template<int MODE>
__global__ __launch_bounds__(256) void k_gmm(
    const bf16* __restrict__ A, const bf16* __restrict__ B,
    const float* __restrict__ bias, float* __restrict__ C,
    bf16* __restrict__ Cb, int N, int K,
    const float* __restrict__ g, const float* __restrict__ bb,
    const float* __restrict__ Fres, bf16* __restrict__ outb) {
  int tid = threadIdx.x;
  int m0 = blockIdx.x * 128, n0 = blockIdx.y * 128;
  int w = tid >> 6, lane = tid & 63, ln = lane & 15, qd = lane >> 4;
  int wm = w & 1, wn = w >> 1;
  __shared__ __align__(16) char smem[34816]; // staging 2x16KB | EP 128*136*2

  f32x4 acc[4][4];
  #pragma unroll
  for (int i = 0; i < 4; i++)
    #pragma unroll
    for (int j = 0; j < 4; j++) acc[i][j] = (f32x4){0.f, 0.f, 0.f, 0.f};

  int rsub = lane >> 2, ch = lane & 3;
  auto stage = [&](int p) {
    char* base = smem + (p & 1) * 16384;
    int k0 = p << 5;
    #pragma unroll
    for (int t = 0; t < 2; t++) {
      int ii = w + t * 4;
      int r = ii * 16 + rsub;
      int sw = (ch ^ ((r >> 1) & 3)) << 3;
      gload16(A + (size_t)(m0 + r) * K + k0 + sw, base + ii * 1024);
      gload16(B + (size_t)(n0 + r) * K + k0 + sw, base + 8192 + ii * 1024);
    }
  };
  auto compute = [&](int p) {
    const char* base = smem + (p & 1) * 16384;
    short8 af[4], bv[4];
    #pragma unroll
    for (int mi = 0; mi < 4; mi++) {
      int r = wm * 64 + mi * 16 + ln;
      af[mi] = *(const short8*)(base + r * 64 + ((qd ^ ((r >> 1) & 3)) << 4));
    }
    #pragma unroll
    for (int ni = 0; ni < 4; ni++) {
      int r = wn * 64 + ni * 16 + ln;
      bv[ni] = *(const short8*)(base + 8192 + r * 64 + ((qd ^ ((r >> 1) & 3)) << 4));
    }
    #pragma unroll
    for (int mi = 0; mi < 4; mi++)
      #pragma unroll
      for (int ni = 0; ni < 4; ni++)
        acc[mi][ni] = __builtin_amdgcn_mfma_f32_16x16x32_bf16(
            af[mi], bv[ni], acc[mi][ni], 0, 0, 0);
  };

  int KT = K >> 5;
  stage(0);
  __syncthreads();
  for (int p = 0; p < KT; p++) {
    if (p + 1 < KT) stage(p + 1);
    compute(p);
    __syncthreads();
  }

  if (MODE <= 1) {
    #pragma unroll
    for (int mi = 0; mi < 4; mi++) {
      #pragma unroll
      for (int r = 0; r < 4; r++) {
        int m = m0 + wm * 64 + mi * 16 + qd * 4 + r;
        #pragma unroll
        for (int ni = 0; ni < 4; ni++) {
          int n = n0 + wn * 64 + ni * 16 + ln;
          float v = acc[mi][ni][r];
          if (bias) v += bias[n];
          C[(size_t)m * N + n] = v;
          if (MODE == 1) Cb[(size_t)m * N + n] = f2b(v);
        }
      }
    }
  } else {
    bf16* EP = (bf16*)smem;  // [128 pix][136 oc-padded]
    int b = n0 >> 12;
    #pragma unroll
    for (int mi = 0; mi < 4; mi++) {
      #pragma unroll
      for (int r = 0; r < 4; r++) {
        int ml = wm * 64 + mi * 16 + qd * 4 + r;
        int oc = m0 + ml;
        float sc = g[oc] * rsqrtf(1.f + EPSV);
        float bt = bb[oc];
        #pragma unroll
        for (int ni = 0; ni < 4; ni++) {
          int nl = wn * 64 + ni * 16 + ln;
          int pix = n0 + nl;
          int y = (pix >> 6) & 63, x = pix & 63;
          float v = fmaxf(acc[mi][ni][r] * sc + bt, 0.f)
                  + Fres[((size_t)(b * 512 + oc) * 64 + y) * 64 + x];
          EP[nl * 136 + ml] = f2b(v);
        }
      }
    }
    __syncthreads();
    int pl = tid >> 1, half = tid & 1;
    size_t gb = (size_t)(n0 + pl) * 512 + m0 + half * 64;
    const bf16* row = &EP[pl * 136 + half * 64];
    #pragma unroll
    for (int j2 = 0; j2 < 8; j2++)
      *(short8*)(outb + gb + j2 * 8) = *(const short8*)(row + j2 * 8);
  }
}

// ===== fuse + value (float4 vw/fg) =========================================
__global__ __launch_bounds__(256) void k_fusev(const float* __restrict__ FL,
        const float* __restrict__ fw, const float* __restrict__ fbv,
        const float* __restrict__ vw, const float* __restrict__ vb,
        float* __restrict__ VAL) {
  int tid = threadIdx.x;
  int bk = blockIdx.x, b = bk / 19, k = bk % 19;
  __shared__ float fwl[64];
  __shared__ __align__(16) float fg[512];
  if (tid < 64) fwl[tid] = fw[tid];
  __syncthreads();
  float fbias = fbv[0];
  for (int c = tid; c < 512; c += 256) {
    float s = 0.f;
    for (int p = 0; p < 64; p++)
      s += fwl[p] * FL[((size_t)(b * 64 + p) * 19 + k) * 512 + c];
    fg[c] = s + fbias;
  }
  __syncthreads();
  int d = tid;
  float s = vb[d];
  const float4* vr = (const float4*)(vw + (size_t)d * 512);
  const float4* fr = (const float4*)fg;
  for (int c4 = 0; c4 < 128; c4++) {
    float4 wv = vr[c4], f = fr[c4];
    s += f.x * wv.x + f.y * wv.y + f.z * wv.z + f.w * wv.w;
  }
  VAL[(size_t)bk * 256 + d] = s;
}

// ===== per-patch attention -> FS NHWC bf16 (C=256), coalesced stores =======
__global__ __launch_bounds__(256) void k_attn(const float* __restrict__ Q,
        const float* __restrict__ KEY, const float* __restrict__ VAL,
        bf16* __restrict__ FS) {
  int tid = threadIdx.x;
  int bp = blockIdx.x, b = bp >> 6, p = bp & 63;
  __shared__ __align__(16) float ks[19][256];
  __shared__ __align__(16) float vs[19][256];
  __shared__ float Ss[64][20];
  __shared__ bf16 ot[64][256];
  for (int i = tid; i < 19 * 256; i += 256) {
    ks[i >> 8][i & 255] = KEY[(size_t)bp * 19 * 256 + i];
    vs[i >> 8][i & 255] = VAL[(size_t)b * 19 * 256 + i];
  }
  __syncthreads();
  {
    int n = tid >> 2, kq = tid & 3;
    const float4* qrow = (const float4*)(Q + ((size_t)bp * 64 + n) * 256);
    for (int k = kq; k < 19; k += 4) {
      const float4* kr = (const float4*)&ks[k][0];
      float s = 0.f;
      for (int d4 = 0; d4 < 64; d4++) {
        float4 qv = qrow[d4], kv = kr[d4];
        s += qv.x * kv.x + qv.y * kv.y + qv.z * kv.z + qv.w * kv.w;
      }
      Ss[n][k] = s;
    }
  }
  __syncthreads();
  if (tid < 64) {
    float mx = -1e30f;
    for (int k = 0; k < 19; k++) mx = fmaxf(mx, Ss[tid][k]);
    float sum = 0.f;
    for (int k = 0; k < 19; k++) { float e = __expf(Ss[tid][k] - mx); Ss[tid][k] = e; sum += e; }
    float inv = 1.f / sum;
    for (int k = 0; k < 19; k++) Ss[tid][k] *= inv;
  }
  __syncthreads();
  {
    int d = tid;
    for (int nn = 0; nn < 64; nn++) {
      float s = 0.f;
      #pragma unroll
      for (int k = 0; k < 19; k++) s += Ss[nn][k] * vs[k][d];
      ot[nn][d] = f2b(s);
    }
  }
  __syncthreads();
  {
    int py = (p >> 3) * 8, px = (p & 7) * 8;
    int nn = tid >> 2, q = tid & 3;
    int y = py + (nn >> 3), x = px + (nn & 7);
    size_t gb = (((size_t)(b * 64 + y) * 64) + x) * 256 + q * 64;
    const bf16* row = &ot[nn][q * 64];
    #pragma unroll
    for (int j = 0; j < 8; j++)
      *(short8*)(FS + gb + j * 8) = *(const short8*)(row + j * 8);
  }
}

// ===== MFMA conv3x3 pad1, NHWC in/out; counted-vmcnt pipeline ==============
// block = 128oc x 4y x 64x, 4 waves (2ocg x 2yp), wave = 64oc x 128n
// A dbuf [2][3][128][32], B dbuf [2][6][66][32]; every stage call issues
// exactly 6 gload16/wave (OOB rows -> dump) so s_waitcnt vmcnt(N) is exact.
// Loop: issue next stages -> vmcnt(n_new) -> s_barrier -> compute ->
// lgkmcnt(0) -> s_barrier.  Prefetch stays in flight across barriers (T3/T4).
__global__ __launch_bounds__(256) void k_conv3(
    const bf16* __restrict__ Xin, int Cin,
    const bf16* __restrict__ M1b, const float* __restrict__ M1f, int C2,
    const bf16* __restrict__ WT,
    const float* __restrict__ g, const float* __restrict__ bb,
    bf16* __restrict__ out, int Cos) {
  int tid = threadIdx.x;
  int b = blockIdx.x >> 4, y0 = (blockIdx.x & 15) * 4;
  int oc0 = blockIdx.y * 128;
  int w = tid >> 6, lane = tid & 63, ln = lane & 15, qd = lane >> 4;
  int wocg = w & 1, wyp = w >> 1;
  int Ct = Cin + C2;

  __shared__ __align__(16) char smem[103936];
  char* smA  = smem;                    // A[2][3][128][32] bf16 (2x24576)
  char* smB  = smem + 49152;            // B[2][6][66][32] bf16 (2x25344)
  char* dump = smem + 99840;            // 4 x 1024 dummy-load sink

  // zero halos in BOTH B buffers (stage never writes them)
  for (int bufi = 0; bufi < 2; bufi++) {
    char* bbuf = smB + bufi * 25344;
    for (int i = tid; i < 6 * 2 * 32; i += 256) {
      int rl = i >> 6, hh = (i >> 5) & 1, kk = i & 31;
      *(bf16*)(bbuf + (rl * 66 + (hh ? 65 : 0)) * 64 + kk * 2) = f2b(0.f);
    }
    if (y0 == 0)
      for (int i = tid; i < 66 * 16; i += 256) ((float*)bbuf)[i] = 0.f;
    if (y0 == 60)
      for (int i = tid; i < 66 * 16; i += 256)
        ((float*)(bbuf + 5 * 66 * 64))[i] = 0.f;
  }

  f32x4 acc[4][8];
  #pragma unroll
  for (int i = 0; i < 4; i++)
    #pragma unroll
    for (int j = 0; j < 8; j++) acc[i][j] = (f32x4){0.f, 0.f, 0.f, 0.f};

  int NPH = (Ct >> 5) * 3;

  auto stageA = [&](int p) {   // always 6 gload16 per wave
    int c0 = (p / 3) << 5, ky = p % 3;
    char* base = smA + (p & 1) * 24576;
    int j = w;
    #pragma unroll
    for (int t = 0; t < 6; t++, j += 4) {
      int kx = j >> 3, i8 = j & 7;
      int ocl = i8 * 16 + (lane >> 2);
      const bf16* src = WT + ((size_t)((ky * 3 + kx) * 512 + oc0 + ocl) * Ct + c0)
                      + (((lane & 3) ^ ((ocl >> 1) & 3)) << 3);
      gload16(src, base + (kx * 128 + i8 * 16) * 64);
    }
  };
  auto stageB = [&](int gi) {  // fast path: exactly 6 gload16 per wave
    int c0 = gi << 5;
    char* bbuf = smB + (gi & 1) * 25344;
    if (c0 < Cin || M1b != nullptr) {
      const bf16* T; int Cs, cb;
      if (c0 < Cin) { T = Xin; Cs = Cin; cb = c0; }
      else          { T = M1b; Cs = C2;  cb = c0 - Cin; }
      #pragma unroll
      for (int rl = 0; rl < 6; rl++) {
        int yy = y0 + rl - 1;
        bool ok = (unsigned)yy < 64u;
        int yc = ok ? yy : y0;
        int xx = w * 16 + (lane >> 2), xr = xx + 1;
        const bf16* src = T + ((size_t)((b * 64 + yc) * 64 + xx) * Cs + cb)
                        + (((lane & 3) ^ ((xr >> 1) & 3)) << 3);
        char* dst = ok ? (bbuf + (rl * 66 + 1 + w * 16) * 64) : (dump + w * 1024);
        gload16(src, dst);
      }
    } else {
      // slow fallback: transpose M1 f32 NCHW in-register (ws too small)
      #pragma unroll
      for (int t = 0; t < 2; t++) {
        int rl = w + t * 4;
        if (rl < 6) {
          int yy = y0 + rl - 1;
          if ((unsigned)yy < 64u) {
            int xx = lane, xr = xx + 1;
            const float* mp = M1f + ((size_t)(b * 2048 + (c0 - Cin)) * 64 + yy) * 64 + xx;
            #pragma unroll
            for (int q = 0; q < 8; q++) {
              union { ushort4 u; bf16 h[4]; } pk;
              #pragma unroll
              for (int jj = 0; jj < 4; jj++) pk.h[jj] = f2b(mp[(size_t)(q * 4 + jj) * 4096]);
              *(ushort4*)(bbuf + (rl * 66 + xr) * 64
                          + ((((q >> 1) ^ ((xr >> 1) & 3)) << 4) | ((q & 1) << 3))) = pk.u;
            }
          }
        }
      }
    }
  };
  auto computeP = [&](int p) {
    int ky = p % 3;
    const char* base = smA + (p & 1) * 24576;
    const char* bB   = smB + ((p / 3) & 1) * 25344;
    int rl0 = 2 * wyp + ky;
    #pragma unroll
    for (int kx = 0; kx < 3; kx++) {
      short8 af[4], bv[8];
      #pragma unroll
      for (int mi = 0; mi < 4; mi++) {
        int ocl = wocg * 64 + mi * 16 + ln;
        af[mi] = *(const short8*)(base + (kx * 128 + ocl) * 64
                                  + ((qd ^ ((ocl >> 1) & 3)) << 4));
      }
      #pragma unroll
      for (int ni = 0; ni < 8; ni++) {
        int rl = rl0 + (ni >> 2);
        int xr = (ni & 3) * 16 + ln + kx;
        bv[ni] = *(const short8*)(bB + (rl * 66 + xr) * 64
                                  + ((qd ^ ((xr >> 1) & 3)) << 4));
      }
      #pragma unroll
      for (int mi = 0; mi < 4; mi++)
        #pragma unroll
        for (int ni = 0; ni < 8; ni++)
          acc[mi][ni] = __builtin_amdgcn_mfma_f32_16x16x32_bf16(
              af[mi], bv[ni], acc[mi][ni], 0, 0, 0);
    }
  };

  // prologue
  stageB(0);
  stageA(0);
  asm volatile("s_waitcnt vmcnt(0)" ::: "memory");
  __syncthreads();

  for (int p = 0; p < NPH; p++) {
    int pn = p + 1;
    bool hasA = pn < NPH;
    bool hasB = hasA && (pn % 3 == 0);
    bool bfast = false;
    if (hasA) stageA(pn);
    if (hasB) {
      int gi = pn / 3;
      bfast = ((gi << 5) < Cin) || (M1b != nullptr);
      stageB(gi);
    }
    __builtin_amdgcn_sched_barrier(0);
    if (!hasA)              asm volatile("s_waitcnt vmcnt(0)"  ::: "memory");
    else if (hasB && bfast) asm volatile("s_waitcnt vmcnt(12)" ::: "memory");
    else                    asm volatile("s_waitcnt vmcnt(6)"  ::: "memory");
    __builtin_amdgcn_s_barrier();
    __builtin_amdgcn_sched_barrier(0);
    computeP(p);
    __builtin_amdgcn_sched_barrier(0);
    asm volatile("s_waitcnt lgkmcnt(0)" ::: "memory");
    __builtin_amdgcn_s_barrier();
  }
  __syncthreads();

  // epilogue: BN+ReLU, LDS transpose -> coalesced NHWC stores
  {
    bf16* EP = (bf16*)smem;   // [4y][64x][128 ocl] = 64 KB
    #pragma unroll
    for (int mi = 0; mi < 4; mi++) {
      int oclb = wocg * 64 + mi * 16 + qd * 4;
      float sc[4], bt[4];
      #pragma unroll
      for (int r = 0; r < 4; r++) {
        int oc = oc0 + oclb + r;
        sc[r] = g[oc] * rsqrtf(1.f + EPSV);
        bt[r] = bb[oc];
      }
      #pragma unroll
      for (int ni = 0; ni < 8; ni++) {
        int yloc = 2 * wyp + (ni >> 2), x = (ni & 3) * 16 + ln;
        union { ushort4 u; bf16 h[4]; } pk;
        #pragma unroll
        for (int r = 0; r < 4; r++)
          pk.h[r] = f2b(fmaxf(acc[mi][ni][r] * sc[r] + bt[r], 0.f));
        *(ushort4*)&EP[(yloc * 64 + x) * 128 + oclb] = pk.u;
      }
    }
    __syncthreads();
    int p2 = tid >> 1, hh = tid & 1;
    #pragma unroll
    for (int pp = 0; pp < 2; pp++) {
      int pixl = pp * 128 + p2;
      int yloc = pixl >> 6, x = pixl & 63;
      size_t gb = ((size_t)((b * 64 + y0 + yloc) * 64 + x)) * Cos + oc0 + hh * 64;
      const bf16* row = &EP[pixl * 128 + hh * 64];
      #pragma unroll
      for (int k = 0; k < 8; k++)
        *(short8*)(out + gb + k * 8) = *(const short8*)(row + k * 8);
    }
  }
}

// ===== final 1x1 (512->19) from NHWC X3 ====================================
__global__ __launch_bounds__(256) void k_final(const bf16* __restrict__ X3,
        const float* __restrict__ dw, float* __restrict__ out) {
  int tid = threadIdx.x;
  int b = blockIdx.x >> 6, y = blockIdx.x & 63;
  __shared__ float W[19 * 512];
  for (int i = tid; i < 19 * 512; i += 256) W[i] = dw[i];
  __syncthreads();
  int x = tid & 63, kg = tid >> 6;
  const bf16* px = X3 + (((size_t)(b * 64 + y) * 64) + x) * 512;
  float acc[5] = {0.f, 0.f, 0.f, 0.f, 0.f};
  for (int c8 = 0; c8 < 512; c8 += 8) {
    union { short8 s; bf16 h[8]; } v;
    v.s = *(const short8*)(px + c8);
    float f[8];
    #pragma unroll
    for (int j = 0; j < 8; j++) f[j] = b2f(v.h[j]);
    #pragma unroll
    for (int i = 0; i < 5; i++) {
      int k = kg * 5 + i;
      if (k < 19) {
        const float* wr = &W[k * 512 + c8];
        #pragma unroll
        for (int j = 0; j < 8; j++) acc[i] += f[j] * wr[j];
      }
    }
  }
  for (int i = 0; i < 5; i++) {
    int k = kg * 5 + i;
    if (k < 19) out[((size_t)(b * 19 + k) * 64 + y) * 64 + x] = acc[i];
  }
}

extern "C" void kernel_launch(void* const* d_in, const int* in_sizes, int n_in,
                              void* d_out, int out_size, void* d_ws, size_t ws_size,
                              hipStream_t stream) {
  (void)in_sizes; (void)n_in; (void)out_size;
  const float* M1 = (const float*)d_in[0];
  const float* F  = (const float*)d_in[1];
  const float* Iin= (const float*)d_in[2];
  const float* R  = (const float*)d_in[3];
  const float* w1 = (const float*)d_in[4];
  const float* w2 = (const float*)d_in[5];
  const float* fw = (const float*)d_in[6];
  const float* fb = (const float*)d_in[7];
  const float* qw = (const float*)d_in[8];
  const float* qb = (const float*)d_in[9];
  const float* kw = (const float*)d_in[10];
  const float* kb = (const float*)d_in[11];
  const float* vw = (const float*)d_in[12];
  const float* vb = (const float*)d_in[13];
  const float* c1 = (const float*)d_in[14];
  const float* g1 = (const float*)d_in[15];
  const float* b1 = (const float*)d_in[16];
  const float* c2 = (const float*)d_in[17];
  const float* g2 = (const float*)d_in[18];
  const float* b2 = (const float*)d_in[19];
  const float* c3 = (const float*)d_in[20];
  const float* g3 = (const float*)d_in[21];
  const float* b3 = (const float*)d_in[22];
  const float* dw = (const float*)d_in[23];

  char* ws = (char*)d_ws;
  bool fast = ws_size >= (size_t)137363456ULL;

  bf16*  qwb  = (bf16*)(ws + 0);           //   262,144
  bf16*  kwb  = (bf16*)(ws + 262144);      //   262,144
  bf16*  w2b  = (bf16*)(ws + 524288);      //   524,288
  bf16*  c1b  = (bf16*)(ws + 1048576);     //   262,144
  bf16*  WT2  = (bf16*)(ws + 0);           //  4,718,592 (after conv1)
  bf16*  WT3  = (bf16*)(ws + 4718592);     // 23,592,960
  bf16*  FS   = (bf16*)(ws + 28311552);    //  8,388,608  NHWC (C=256)
  bf16*  FO1  = (bf16*)(ws + 36700160);    // 16,777,216  NHWC (C=512)
  bf16*  X2   = (bf16*)(ws + 53477376);    // 16,777,216  NHWC (C=512)
  bf16*  M1bf = fast ? (bf16*)(ws + 70254592) : nullptr;  // 67,108,864 NHWC
  bf16*  X3   = (bf16*)(ws + 28311552);    // overlay FS+FO1 (dead by then)
  bf16*  FP    = (bf16*) (ws + 53477376);  // X2 region
  float* QUERY = (float*)(ws + 70254592);  // 16,777,216
  float* FL0   = (float*)(ws + 87031808);  //  9,961,472
  bf16*  Hb    = (bf16*) (ws + 96993280);  //  4,980,736
  bf16*  FLb   = (bf16*) (ws + 101974016); //  4,980,736
  float* KEY   = (float*)(ws + 106954752); //  4,980,736
  float* VAL   = (float*)(ws + 111935488); //     77,824
  float* FL    = FL0;

  k_cast<<<128, 256, 0, stream>>>(qw, qwb, 32768);
  k_cast<<<128, 256, 0, stream>>>(kw, kwb, 32768);
  k_cast<<<256, 256, 0, stream>>>(w2, w2b, 65536);
  k_cast<<<128, 256, 0, stream>>>(c1, c1b, 32768);
  k_fp2<<<256, 256, 0, stream>>>(F, FP);
  k_flocal2<<<256, 256, 0, stream>>>(Iin, R, FP, FL0);
  k_lg1<<<dim3(38, 4), 256, 0, stream>>>(FL0, w1, Hb);
  k_gmm<1><<<dim3(38, 4), 256, 0, stream>>>(Hb, w2b, nullptr, FL, FLb, 512, 512,
                                            nullptr, nullptr, nullptr, nullptr);
  k_fusev<<<76, 256, 0, stream>>>(FL, fw, fb, vw, vb, VAL);
  k_gmm<0><<<dim3(38, 2), 256, 0, stream>>>(FLb, kwb, kb, KEY, nullptr, 256, 512,
                                            nullptr, nullptr, nullptr, nullptr);
  k_gmm<0><<<dim3(128, 2), 256, 0, stream>>>(FP, qwb, qb, QUERY, nullptr, 256, 512,
                                             nullptr, nullptr, nullptr, nullptr);
  k_attn<<<256, 256, 0, stream>>>(QUERY, KEY, VAL, FS);
  if (fast) k_m1t<<<dim3(256, 32), 256, 0, stream>>>(M1, M1bf);
  k_gmm<2><<<dim3(4, 128), 256, 0, stream>>>(c1b, FS, nullptr, nullptr, nullptr,
                                             16384, 256, g1, b1, F, FO1);
  k_wtr<<<dim3(512, 4),  256, 0, stream>>>(c2, WT2, 512);
  k_wtr<<<dim3(512, 20), 256, 0, stream>>>(c3, WT3, 2560);
  k_conv3<<<dim3(64, 4), 256, 0, stream>>>(FO1, 512, nullptr, nullptr, 0,
                                           WT2, g2, b2, X2, 512);
  k_conv3<<<dim3(64, 4), 256, 0, stream>>>(X2, 512, M1bf, M1, 2048,
                                           WT3, g3, b3, X3, 512);
  k_final<<<256, 256, 0, stream>>>(X3, dw, (float*)d_out);
}

// Round 8
// 990.842 us; speedup vs baseline: 7.0102x; 1.0282x over previous
//
#include <hip/hip_runtime.h>
#include <hip/hip_bf16.h>

typedef __hip_bfloat16 bf16;
using short8 = __attribute__((ext_vector_type(8))) short;
using f32x4  = __attribute__((ext_vector_type(4))) float;

__device__ __forceinline__ float b2f(bf16 v){ return __bfloat162float(v); }
__device__ __forceinline__ bf16  f2b(float v){ return __float2bfloat16(v); }

#define EPSV 1e-5f

// async global->LDS, 16B/lane, dest = wave-uniform base + lane*16
__device__ __forceinline__ void gload16(const void* g, void* l) {
  __builtin_amdgcn_global_load_lds(
      (const __attribute__((address_space(1))) unsigned int*)g,
      (__attribute__((address_space(3))) unsigned int*)l, 16, 0, 0);
}

// ===== f32 -> bf16 flat cast (n4 = count/4) ================================
__global__ __launch_bounds__(256) void k_cast(const float* __restrict__ in,
                                              bf16* __restrict__ out, int n4) {
  int i = blockIdx.x * 256 + threadIdx.x;
  if (i < n4) {
    float4 v = ((const float4*)in)[i];
    union { ushort4 u; bf16 h[4]; } o;
    o.h[0] = f2b(v.x); o.h[1] = f2b(v.y); o.h[2] = f2b(v.z); o.h[3] = f2b(v.w);
    ((ushort4*)out)[i] = o.u;
  }
}

// ===== weight reshape: w [OC=512][CI][3][3] f32 -> WT [9][512][CI] bf16 ====
__global__ __launch_bounds__(256) void k_wtr(const float* __restrict__ w,
                                             bf16* __restrict__ wt, int CI) {
  int oc = blockIdx.x, c0 = blockIdx.y * 128;
  __shared__ float ld[128 * 9];
  const float* src = w + ((size_t)oc * CI + c0) * 9;
  for (int i = threadIdx.x; i < 128 * 9; i += 256) ld[i] = src[i];
  __syncthreads();
  for (int i = threadIdx.x; i < 128 * 9; i += 256) {
    int k9 = i / 128, t = i - k9 * 128;
    wt[((size_t)k9 * 512 + oc) * CI + c0 + t] = f2b(ld[t * 9 + k9]);
  }
}

// ===== M1 NCHW f32 -> NHWC bf16 [4][64][64][2048] (fast path only) =========
__global__ __launch_bounds__(256) void k_m1t(const float* __restrict__ M1,
                                             bf16* __restrict__ M1b) {
  int b = blockIdx.x >> 6, y = blockIdx.x & 63;
  int c0 = blockIdx.y * 64;
  __shared__ float t[64][65];
  for (int i = threadIdx.x; i < 4096; i += 256) {
    int cc = i >> 6, x = i & 63;
    t[x][cc] = M1[((size_t)(b * 2048 + c0 + cc) * 64 + y) * 64 + x];
  }
  __syncthreads();
  for (int i = threadIdx.x; i < 4096; i += 256) {
    int x = i >> 6, cc = i & 63;
    M1b[((size_t)((b * 64 + y) * 64 + x)) * 2048 + c0 + cc] = f2b(t[x][cc]);
  }
}

// ===== F (NCHW f32) -> FP (b,p,n,c) bf16 via LDS transpose =================
__global__ __launch_bounds__(256) void k_fp2(const float* __restrict__ F,
                                             bf16* __restrict__ FP) {
  int b = blockIdx.x >> 6, y = blockIdx.x & 63;
  int tid = threadIdx.x;
  __shared__ float t[256][65];
  int p_hi = (y >> 3) << 3, n_hi = (y & 7) << 3;
  for (int half = 0; half < 2; half++) {
    int c0 = half << 8;
    for (int i = tid; i < 256 * 64; i += 256) {
      int cc = i >> 6, x = i & 63;
      t[cc][x] = F[((size_t)(b * 512 + c0 + cc) * 64 + y) * 64 + x];
    }
    __syncthreads();
    for (int x = 0; x < 64; x++) {
      int p = p_hi + (x >> 3), n = n_hi + (x & 7);
      FP[((size_t)(b * 64 + p)) * 32768 + n * 512 + c0 + tid] = f2b(t[tid][x]);
    }
    __syncthreads();
  }
}

// ===== softmax(I); FL0 = (bc*pix) @ FP  with FP slice in LDS ===============
__global__ __launch_bounds__(256) void k_flocal2(const float* __restrict__ I,
        const float* __restrict__ R, const bf16* __restrict__ FP,
        float* __restrict__ FL0) {
  int bp = blockIdx.x, b = bp >> 6, p = bp & 63;
  int tid = threadIdx.x, w = tid >> 6, lane = tid & 63;
  __shared__ __align__(16) bf16 fps[64 * 512];   // 64 KB
  __shared__ float pix[19][64];
  __shared__ float bc[19];
  {
    const bf16* src = FP + (size_t)bp * 32768 + lane * 8;
    #pragma unroll
    for (int t = 0; t < 16; t++) {
      int chunk = w + t * 4;
      gload16(src + chunk * 512, (char*)fps + chunk * 1024);
    }
  }
  int py = (p >> 3) * 8, px = (p & 7) * 8;
  for (int i = tid; i < 19 * 64; i += 256) {
    int k = i >> 6, n = i & 63;
    int y = py + (n >> 3), x = px + (n & 7);
    pix[k][n] = I[((size_t)(b * 19 + k) * 64 + y) * 64 + x];
  }
  if (tid < 19) bc[tid] = R[(size_t)(b * 19 + tid) * 64 + p];
  __syncthreads();
  if (tid < 19) {
    float mx = -1e30f;
    for (int n = 0; n < 64; n++) mx = fmaxf(mx, pix[tid][n]);
    float s = 0.f;
    for (int n = 0; n < 64; n++) { float e = __expf(pix[tid][n] - mx); pix[tid][n] = e; s += e; }
    float sc = bc[tid] / s;
    for (int n = 0; n < 64; n++) pix[tid][n] *= sc;
  }
  __syncthreads();
  for (int task = tid; task < 19 * 64; task += 256) {
    int k = task >> 6, c8 = (task & 63) << 3;
    float acc[8] = {};
    for (int n = 0; n < 64; n++) {
      float pv = pix[k][n];
      union { short8 s; bf16 h[8]; } v;
      v.s = *(const short8*)&fps[n * 512 + c8];
      #pragma unroll
      for (int j = 0; j < 8; j++) acc[j] += pv * b2f(v.h[j]);
    }
    float* dst = FL0 + ((size_t)(b * 64 + p) * 19 + k) * 512 + c8;
    #pragma unroll
    for (int j = 0; j < 8; j++) dst[j] = acc[j];
  }
}

// ===== LG part 1 (emits bf16 H) ============================================
__global__ __launch_bounds__(256) void k_lg1(const float* __restrict__ FL0,
        const float* __restrict__ w1, bf16* __restrict__ Hb) {
  int tid = threadIdx.x;
  int b = blockIdx.y;
  int n0 = blockIdx.x * 256;
  __shared__ float W[64][64];
  __shared__ float Xs[16][256];
  for (int i = tid; i < 4096; i += 256) W[i >> 6][i & 63] = w1[i];
  float acc[64];
  #pragma unroll
  for (int po = 0; po < 64; po++) acc[po] = 0.f;
  for (int q0 = 0; q0 < 64; q0 += 16) {
    __syncthreads();
    for (int i = tid; i < 4096; i += 256) {
      int q = i >> 8, j = i & 255;
      Xs[q][j] = FL0[(size_t)(b * 64 + q0 + q) * 9728 + n0 + j];
    }
    __syncthreads();
    for (int q = 0; q < 16; q++) {
      float xv = Xs[q][tid];
      #pragma unroll
      for (int po = 0; po < 64; po++) acc[po] += W[po][q0 + q] * xv;
    }
  }
  for (int po = 0; po < 64; po++) {
    float r = acc[po] + FL0[(size_t)(b * 64 + po) * 9728 + n0 + tid];
    Hb[(size_t)(b * 64 + po) * 9728 + n0 + tid] = f2b(fmaxf(r, 0.f));
  }
}

// ===== generic MFMA GEMM C[m][n] = sum_k A[m][k]*B[n][k] ===================
template<int MODE>
__global__ __launch_bounds__(256) void k_gmm(
    const bf16* __restrict__ A, const bf16* __restrict__ B,
    const float* __restrict__ bias, float* __restrict__ C,
    bf16* __restrict__ Cb, int N, int K,
    const float* __restrict__ g, const float* __restrict__ bb,
    const float* __restrict__ Fres, bf16* __restrict__ outb) {
  int tid = threadIdx.x;
  int m0 = blockIdx.x * 128, n0 = blockIdx.y * 128;
  int w = tid >> 6, lane = tid & 63, ln = lane & 15, qd = lane >> 4;
  int wm = w & 1, wn = w >> 1;
  __shared__ __align__(16) char smem[34816]; // staging 2x16KB | EP 128*136*2

  f32x4 acc[4][4];
  #pragma unroll
  for (int i = 0; i < 4; i++)
    #pragma unroll
    for (int j = 0; j < 4; j++) acc[i][j] = (f32x4){0.f, 0.f, 0.f, 0.f};

  int rsub = lane >> 2, ch = lane & 3;
  auto stage = [&](int p) {
    char* base = smem + (p & 1) * 16384;
    int k0 = p << 5;
    #pragma unroll
    for (int t = 0; t < 2; t++) {
      int ii = w + t * 4;
      int r = ii * 16 + rsub;
      int sw = (ch ^ ((r >> 1) & 3)) << 3;
      gload16(A + (size_t)(m0 + r) * K + k0 + sw, base + ii * 1024);
      gload16(B + (size_t)(n0 + r) * K + k0 + sw, base + 8192 + ii * 1024);
    }
  };
  auto compute = [&](int p) {
    const char* base = smem + (p & 1) * 16384;
    short8 af[4], bv[4];
    #pragma unroll
    for (int mi = 0; mi < 4; mi++) {
      int r = wm * 64 + mi * 16 + ln;
      af[mi] = *(const short8*)(base + r * 64 + ((qd ^ ((r >> 1) & 3)) << 4));
    }
    #pragma unroll
    for (int ni = 0; ni < 4; ni++) {
      int r = wn * 64 + ni * 16 + ln;
      bv[ni] = *(const short8*)(base + 8192 + r * 64 + ((qd ^ ((r >> 1) & 3)) << 4));
    }
    #pragma unroll
    for (int mi = 0; mi < 4; mi++)
      #pragma unroll
      for (int ni = 0; ni < 4; ni++)
        acc[mi][ni] = __builtin_amdgcn_mfma_f32_16x16x32_bf16(
            af[mi], bv[ni], acc[mi][ni], 0, 0, 0);
  };

  int KT = K >> 5;
  stage(0);
  __syncthreads();
  for (int p = 0; p < KT; p++) {
    if (p + 1 < KT) stage(p + 1);
    compute(p);
    __syncthreads();
  }

  if (MODE <= 1) {
    #pragma unroll
    for (int mi = 0; mi < 4; mi++) {
      #pragma unroll
      for (int r = 0; r < 4; r++) {
        int m = m0 + wm * 64 + mi * 16 + qd * 4 + r;
        #pragma unroll
        for (int ni = 0; ni < 4; ni++) {
          int n = n0 + wn * 64 + ni * 16 + ln;
          float v = acc[mi][ni][r];
          if (bias) v += bias[n];
          C[(size_t)m * N + n] = v;
          if (MODE == 1) Cb[(size_t)m * N + n] = f2b(v);
        }
      }
    }
  } else {
    bf16* EP = (bf16*)smem;  // [128 pix][136 oc-padded]
    int b = n0 >> 12;
    #pragma unroll
    for (int mi = 0; mi < 4; mi++) {
      #pragma unroll
      for (int r = 0; r < 4; r++) {
        int ml = wm * 64 + mi * 16 + qd * 4 + r;
        int oc = m0 + ml;
        float sc = g[oc] * rsqrtf(1.f + EPSV);
        float bt = bb[oc];
        #pragma unroll
        for (int ni = 0; ni < 4; ni++) {
          int nl = wn * 64 + ni * 16 + ln;
          int pix = n0 + nl;
          int y = (pix >> 6) & 63, x = pix & 63;
          float v = fmaxf(acc[mi][ni][r] * sc + bt, 0.f)
                  + Fres[((size_t)(b * 512 + oc) * 64 + y) * 64 + x];
          EP[nl * 136 + ml] = f2b(v);
        }
      }
    }
    __syncthreads();
    int pl = tid >> 1, half = tid & 1;
    size_t gb = (size_t)(n0 + pl) * 512 + m0 + half * 64;
    const bf16* row = &EP[pl * 136 + half * 64];
    #pragma unroll
    for (int j2 = 0; j2 < 8; j2++)
      *(short8*)(outb + gb + j2 * 8) = *(const short8*)(row + j2 * 8);
  }
}

// ===== fuse + value (float4 vw/fg) =========================================
__global__ __launch_bounds__(256) void k_fusev(const float* __restrict__ FL,
        const float* __restrict__ fw, const float* __restrict__ fbv,
        const float* __restrict__ vw, const float* __restrict__ vb,
        float* __restrict__ VAL) {
  int tid = threadIdx.x;
  int bk = blockIdx.x, b = bk / 19, k = bk % 19;
  __shared__ float fwl[64];
  __shared__ __align__(16) float fg[512];
  if (tid < 64) fwl[tid] = fw[tid];
  __syncthreads();
  float fbias = fbv[0];
  for (int c = tid; c < 512; c += 256) {
    float s = 0.f;
    for (int p = 0; p < 64; p++)
      s += fwl[p] * FL[((size_t)(b * 64 + p) * 19 + k) * 512 + c];
    fg[c] = s + fbias;
  }
  __syncthreads();
  int d = tid;
  float s = vb[d];
  const float4* vr = (const float4*)(vw + (size_t)d * 512);
  const float4* fr = (const float4*)fg;
  for (int c4 = 0; c4 < 128; c4++) {
    float4 wv = vr[c4], f = fr[c4];
    s += f.x * wv.x + f.y * wv.y + f.z * wv.z + f.w * wv.w;
  }
  VAL[(size_t)bk * 256 + d] = s;
}

// ===== per-patch attention -> FS NHWC bf16 (C=256), coalesced stores =======
__global__ __launch_bounds__(256) void k_attn(const float* __restrict__ Q,
        const float* __restrict__ KEY, const float* __restrict__ VAL,
        bf16* __restrict__ FS) {
  int tid = threadIdx.x;
  int bp = blockIdx.x, b = bp >> 6, p = bp & 63;
  __shared__ __align__(16) float ks[19][256];
  __shared__ __align__(16) float vs[19][256];
  __shared__ float Ss[64][20];
  __shared__ bf16 ot[64][256];
  for (int i = tid; i < 19 * 256; i += 256) {
    ks[i >> 8][i & 255] = KEY[(size_t)bp * 19 * 256 + i];
    vs[i >> 8][i & 255] = VAL[(size_t)b * 19 * 256 + i];
  }
  __syncthreads();
  {
    int n = tid >> 2, kq = tid & 3;
    const float4* qrow = (const float4*)(Q + ((size_t)bp * 64 + n) * 256);
    for (int k = kq; k < 19; k += 4) {
      const float4* kr = (const float4*)&ks[k][0];
      float s = 0.f;
      for (int d4 = 0; d4 < 64; d4++) {
        float4 qv = qrow[d4], kv = kr[d4];
        s += qv.x * kv.x + qv.y * kv.y + qv.z * kv.z + qv.w * kv.w;
      }
      Ss[n][k] = s;
    }
  }
  __syncthreads();
  if (tid < 64) {
    float mx = -1e30f;
    for (int k = 0; k < 19; k++) mx = fmaxf(mx, Ss[tid][k]);
    float sum = 0.f;
    for (int k = 0; k < 19; k++) { float e = __expf(Ss[tid][k] - mx); Ss[tid][k] = e; sum += e; }
    float inv = 1.f / sum;
    for (int k = 0; k < 19; k++) Ss[tid][k] *= inv;
  }
  __syncthreads();
  {
    int d = tid;
    for (int nn = 0; nn < 64; nn++) {
      float s = 0.f;
      #pragma unroll
      for (int k = 0; k < 19; k++) s += Ss[nn][k] * vs[k][d];
      ot[nn][d] = f2b(s);
    }
  }
  __syncthreads();
  {
    int py = (p >> 3) * 8, px = (p & 7) * 8;
    int nn = tid >> 2, q = tid & 3;
    int y = py + (nn >> 3), x = px + (nn & 7);
    size_t gb = (((size_t)(b * 64 + y) * 64) + x) * 256 + q * 64;
    const bf16* row = &ot[nn][q * 64];
    #pragma unroll
    for (int j = 0; j < 8; j++)
      *(short8*)(FS + gb + j * 8) = *(const short8*)(row + j * 8);
  }
}

// ===== MFMA conv3x3 pad1, NHWC in/out; 8 waves (2/SIMD), counted vmcnt =====
// block = 512 thr = 8 waves (2ocg x 4y), wave = 64oc x 64x (4x4 frags).
// A dbuf [2][3][128][32], B dbuf [2][6][66][32]; stage issues exactly 3
// gload16/wave (A) and 3/wave (B, OOB->dump) so vmcnt(N) is exact.
// 2 waves/SIMD hide ds_read->MFMA dependency stalls (R6 ran 1 wave/SIMD).
__global__ __launch_bounds__(512) void k_conv3(
    const bf16* __restrict__ Xin, int Cin,
    const bf16* __restrict__ M1b, const float* __restrict__ M1f, int C2,
    const bf16* __restrict__ WT,
    const float* __restrict__ g, const float* __restrict__ bb,
    bf16* __restrict__ out, int Cos) {
  int tid = threadIdx.x;
  int b = blockIdx.x >> 4, y0 = (blockIdx.x & 15) * 4;
  int oc0 = blockIdx.y * 128;
  int w = tid >> 6, lane = tid & 63, ln = lane & 15, qd = lane >> 4;
  int wocg = w & 1, wyp = w >> 1;      // wyp in 0..3 (y row)
  int Ct = Cin + C2;

  __shared__ __align__(16) char smem[100864];
  char* smA  = smem;                    // A[2][3][128][32] bf16 (2x24576)
  char* smB  = smem + 49152;            // B[2][6][66][32] bf16 (2x25344)
  char* dump = smem + 99840;            // 1KB shared dummy sink

  // zero halos in BOTH B buffers (stage never writes them)
  for (int bufi = 0; bufi < 2; bufi++) {
    char* bbuf = smB + bufi * 25344;
    for (int i = tid; i < 6 * 2 * 32; i += 512) {
      int rl = i >> 6, hh = (i >> 5) & 1, kk = i & 31;
      *(bf16*)(bbuf + (rl * 66 + (hh ? 65 : 0)) * 64 + kk * 2) = f2b(0.f);
    }
    if (y0 == 0)
      for (int i = tid; i < 66 * 16; i += 512) ((float*)bbuf)[i] = 0.f;
    if (y0 == 60)
      for (int i = tid; i < 66 * 16; i += 512)
        ((float*)(bbuf + 5 * 66 * 64))[i] = 0.f;
  }

  f32x4 acc[4][4];
  #pragma unroll
  for (int i = 0; i < 4; i++)
    #pragma unroll
    for (int j = 0; j < 4; j++) acc[i][j] = (f32x4){0.f, 0.f, 0.f, 0.f};

  int NPH = (Ct >> 5) * 3;

  auto stageA = [&](int p) {   // exactly 3 gload16 per wave
    int c0 = (p / 3) << 5, ky = p % 3;
    char* base = smA + (p & 1) * 24576;
    #pragma unroll
    for (int t = 0; t < 3; t++) {
      int j = w + t * 8;                 // 0..23
      int kx = j >> 3, i8 = j & 7;
      int ocl = i8 * 16 + (lane >> 2);
      const bf16* src = WT + ((size_t)((ky * 3 + kx) * 512 + oc0 + ocl) * Ct + c0)
                      + (((lane & 3) ^ ((ocl >> 1) & 3)) << 3);
      gload16(src, base + (kx * 128 + i8 * 16) * 64);
    }
  };
  auto stageB = [&](int gi) {  // fast path: exactly 3 gload16 per wave
    int c0 = gi << 5;
    char* bbuf = smB + (gi & 1) * 25344;
    if (c0 < Cin || M1b != nullptr) {
      const bf16* T; int Cs, cb;
      if (c0 < Cin) { T = Xin; Cs = Cin; cb = c0; }
      else          { T = M1b; Cs = C2;  cb = c0 - Cin; }
      #pragma unroll
      for (int t = 0; t < 3; t++) {
        int j = w + t * 8;               // 0..23
        int rl = j >> 2, q = j & 3;
        int yy = y0 + rl - 1;
        bool ok = (unsigned)yy < 64u;
        int yc = ok ? yy : y0;
        int xx = q * 16 + (lane >> 2), xr = xx + 1;
        const bf16* src = T + ((size_t)((b * 64 + yc) * 64 + xx) * Cs + cb)
                        + (((lane & 3) ^ ((xr >> 1) & 3)) << 3);
        char* dst = ok ? (bbuf + (rl * 66 + 1 + q * 16) * 64) : dump;
        gload16(src, dst);
      }
    } else {
      // slow fallback: transpose M1 f32 NCHW in-register (ws too small)
      if (w < 6) {
        int rl = w, yy = y0 + rl - 1;
        if ((unsigned)yy < 64u) {
          int xx = lane, xr = xx + 1;
          const float* mp = M1f + ((size_t)(b * 2048 + (c0 - Cin)) * 64 + yy) * 64 + xx;
          #pragma unroll
          for (int q = 0; q < 8; q++) {
            union { ushort4 u; bf16 h[4]; } pk;
            #pragma unroll
            for (int jj = 0; jj < 4; jj++) pk.h[jj] = f2b(mp[(size_t)(q * 4 + jj) * 4096]);
            *(ushort4*)(bbuf + (rl * 66 + xr) * 64
                        + ((((q >> 1) ^ ((xr >> 1) & 3)) << 4) | ((q & 1) << 3))) = pk.u;
          }
        }
      }
    }
  };
  auto computeP = [&](int p) {
    int ky = p % 3;
    const char* base = smA + (p & 1) * 24576;
    const char* bB   = smB + ((p / 3) & 1) * 25344;
    int rl = wyp + ky;                    // 0..5
    #pragma unroll
    for (int kx = 0; kx < 3; kx++) {
      short8 af[4], bv[4];
      #pragma unroll
      for (int mi = 0; mi < 4; mi++) {
        int ocl = wocg * 64 + mi * 16 + ln;
        af[mi] = *(const short8*)(base + (kx * 128 + ocl) * 64
                                  + ((qd ^ ((ocl >> 1) & 3)) << 4));
      }
      #pragma unroll
      for (int ni = 0; ni < 4; ni++) {
        int xr = ni * 16 + ln + kx;
        bv[ni] = *(const short8*)(bB + (rl * 66 + xr) * 64
                                  + ((qd ^ ((xr >> 1) & 3)) << 4));
      }
      #pragma unroll
      for (int mi = 0; mi < 4; mi++)
        #pragma unroll
        for (int ni = 0; ni < 4; ni++)
          acc[mi][ni] = __builtin_amdgcn_mfma_f32_16x16x32_bf16(
              af[mi], bv[ni], acc[mi][ni], 0, 0, 0);
    }
  };

  // prologue
  stageB(0);
  stageA(0);
  asm volatile("s_waitcnt vmcnt(0)" ::: "memory");
  __syncthreads();

  for (int p = 0; p < NPH; p++) {
    int pn = p + 1;
    bool hasA = pn < NPH;
    bool hasB = hasA && (pn % 3 == 0);
    bool bfast = false;
    if (hasA) stageA(pn);
    if (hasB) {
      int gi = pn / 3;
      bfast = ((gi << 5) < Cin) || (M1b != nullptr);
      stageB(gi);
    }
    __builtin_amdgcn_sched_barrier(0);
    if (!hasA)              asm volatile("s_waitcnt vmcnt(0)" ::: "memory");
    else if (hasB && bfast) asm volatile("s_waitcnt vmcnt(6)" ::: "memory");
    else                    asm volatile("s_waitcnt vmcnt(3)" ::: "memory");
    __builtin_amdgcn_s_barrier();
    __builtin_amdgcn_sched_barrier(0);
    computeP(p);
    __builtin_amdgcn_sched_barrier(0);
    asm volatile("s_waitcnt lgkmcnt(0)" ::: "memory");
    __builtin_amdgcn_s_barrier();
  }
  __syncthreads();

  // epilogue: BN+ReLU, LDS transpose -> coalesced NHWC stores
  {
    bf16* EP = (bf16*)smem;   // [4y][64x][128 ocl] = 64 KB
    #pragma unroll
    for (int mi = 0; mi < 4; mi++) {
      int oclb = wocg * 64 + mi * 16 + qd * 4;
      float sc[4], bt[4];
      #pragma unroll
      for (int r = 0; r < 4; r++) {
        int oc = oc0 + oclb + r;
        sc[r] = g[oc] * rsqrtf(1.f + EPSV);
        bt[r] = bb[oc];
      }
      #pragma unroll
      for (int ni = 0; ni < 4; ni++) {
        int x = ni * 16 + ln;
        union { ushort4 u; bf16 h[4]; } pk;
        #pragma unroll
        for (int r = 0; r < 4; r++)
          pk.h[r] = f2b(fmaxf(acc[mi][ni][r] * sc[r] + bt[r], 0.f));
        *(ushort4*)&EP[(wyp * 64 + x) * 128 + oclb] = pk.u;
      }
    }
    __syncthreads();
    int pixl = tid >> 1, hh = tid & 1;
    int yloc = pixl >> 6, x = pixl & 63;
    size_t gb = ((size_t)((b * 64 + y0 + yloc) * 64 + x)) * Cos + oc0 + hh * 64;
    const bf16* row = &EP[pixl * 128 + hh * 64];
    #pragma unroll
    for (int k = 0; k < 8; k++)
      *(short8*)(out + gb + k * 8) = *(const short8*)(row + k * 8);
  }
}

// ===== final 1x1 (512->19) from NHWC X3 ====================================
__global__ __launch_bounds__(256) void k_final(const bf16* __restrict__ X3,
        const float* __restrict__ dw, float* __restrict__ out) {
  int tid = threadIdx.x;
  int b = blockIdx.x >> 6, y = blockIdx.x & 63;
  __shared__ float W[19 * 512];
  for (int i = tid; i < 19 * 512; i += 256) W[i] = dw[i];
  __syncthreads();
  int x = tid & 63, kg = tid >> 6;
  const bf16* px = X3 + (((size_t)(b * 64 + y) * 64) + x) * 512;
  float acc[5] = {0.f, 0.f, 0.f, 0.f, 0.f};
  for (int c8 = 0; c8 < 512; c8 += 8) {
    union { short8 s; bf16 h[8]; } v;
    v.s = *(const short8*)(px + c8);
    float f[8];
    #pragma unroll
    for (int j = 0; j < 8; j++) f[j] = b2f(v.h[j]);
    #pragma unroll
    for (int i = 0; i < 5; i++) {
      int k = kg * 5 + i;
      if (k < 19) {
        const float* wr = &W[k * 512 + c8];
        #pragma unroll
        for (int j = 0; j < 8; j++) acc[i] += f[j] * wr[j];
      }
    }
  }
  for (int i = 0; i < 5; i++) {
    int k = kg * 5 + i;
    if (k < 19) out[((size_t)(b * 19 + k) * 64 + y) * 64 + x] = acc[i];
  }
}

extern "C" void kernel_launch(void* const* d_in, const int* in_sizes, int n_in,
                              void* d_out, int out_size, void* d_ws, size_t ws_size,
                              hipStream_t stream) {
  (void)in_sizes; (void)n_in; (void)out_size;
  const float* M1 = (const float*)d_in[0];
  const float* F  = (const float*)d_in[1];
  const float* Iin= (const float*)d_in[2];
  const float* R  = (const float*)d_in[3];
  const float* w1 = (const float*)d_in[4];
  const float* w2 = (const float*)d_in[5];
  const float* fw = (const float*)d_in[6];
  const float* fb = (const float*)d_in[7];
  const float* qw = (const float*)d_in[8];
  const float* qb = (const float*)d_in[9];
  const float* kw = (const float*)d_in[10];
  const float* kb = (const float*)d_in[11];
  const float* vw = (const float*)d_in[12];
  const float* vb = (const float*)d_in[13];
  const float* c1 = (const float*)d_in[14];
  const float* g1 = (const float*)d_in[15];
  const float* b1 = (const float*)d_in[16];
  const float* c2 = (const float*)d_in[17];
  const float* g2 = (const float*)d_in[18];
  const float* b2 = (const float*)d_in[19];
  const float* c3 = (const float*)d_in[20];
  const float* g3 = (const float*)d_in[21];
  const float* b3 = (const float*)d_in[22];
  const float* dw = (const float*)d_in[23];

  char* ws = (char*)d_ws;
  bool fast = ws_size >= (size_t)137363456ULL;

  bf16*  qwb  = (bf16*)(ws + 0);           //   262,144
  bf16*  kwb  = (bf16*)(ws + 262144);      //   262,144
  bf16*  w2b  = (bf16*)(ws + 524288);      //   524,288
  bf16*  c1b  = (bf16*)(ws + 1048576);     //   262,144
  bf16*  WT2  = (bf16*)(ws + 0);           //  4,718,592 (after conv1)
  bf16*  WT3  = (bf16*)(ws + 4718592);     // 23,592,960
  bf16*  FS   = (bf16*)(ws + 28311552);    //  8,388,608  NHWC (C=256)
  bf16*  FO1  = (bf16*)(ws + 36700160);    // 16,777,216  NHWC (C=512)
  bf16*  X2   = (bf16*)(ws + 53477376);    // 16,777,216  NHWC (C=512)
  bf16*  M1bf = fast ? (bf16*)(ws + 70254592) : nullptr;  // 67,108,864 NHWC
  bf16*  X3   = (bf16*)(ws + 28311552);    // overlay FS+FO1 (dead by then)
  bf16*  FP    = (bf16*) (ws + 53477376);  // X2 region
  float* QUERY = (float*)(ws + 70254592);  // 16,777,216
  float* FL0   = (float*)(ws + 87031808);  //  9,961,472
  bf16*  Hb    = (bf16*) (ws + 96993280);  //  4,980,736
  bf16*  FLb   = (bf16*) (ws + 101974016); //  4,980,736
  float* KEY   = (float*)(ws + 106954752); //  4,980,736
  float* VAL   = (float*)(ws + 111935488); //     77,824
  float* FL    = FL0;

  k_cast<<<128, 256, 0, stream>>>(qw, qwb, 32768);
  k_cast<<<128, 256, 0, stream>>>(kw, kwb, 32768);
  k_cast<<<256, 256, 0, stream>>>(w2, w2b, 65536);
  k_cast<<<128, 256, 0, stream>>>(c1, c1b, 32768);
  k_fp2<<<256, 256, 0, stream>>>(F, FP);
  k_flocal2<<<256, 256, 0, stream>>>(Iin, R, FP, FL0);
  k_lg1<<<dim3(38, 4), 256, 0, stream>>>(FL0, w1, Hb);
  k_gmm<1><<<dim3(38, 4), 256, 0, stream>>>(Hb, w2b, nullptr, FL, FLb, 512, 512,
                                            nullptr, nullptr, nullptr, nullptr);
  k_fusev<<<76, 256, 0, stream>>>(FL, fw, fb, vw, vb, VAL);
  k_gmm<0><<<dim3(38, 2), 256, 0, stream>>>(FLb, kwb, kb, KEY, nullptr, 256, 512,
                                            nullptr, nullptr, nullptr, nullptr);
  k_gmm<0><<<dim3(128, 2), 256, 0, stream>>>(FP, qwb, qb, QUERY, nullptr, 256, 512,
                                             nullptr, nullptr, nullptr, nullptr);
  k_attn<<<256, 256, 0, stream>>>(QUERY, KEY, VAL, FS);
  if (fast) k_m1t<<<dim3(256, 32), 256, 0, stream>>>(M1, M1bf);
  k_gmm<2><<<dim3(4, 128), 256, 0, stream>>>(c1b, FS, nullptr, nullptr, nullptr,
                                             16384, 256, g1, b1, F, FO1);
  k_wtr<<<dim3(512, 4),  256, 0, stream>>>(c2, WT2, 512);
  k_wtr<<<dim3(512, 20), 256, 0, stream>>>(c3, WT3, 2560);
  k_conv3<<<dim3(64, 4), 512, 0, stream>>>(FO1, 512, nullptr, nullptr, 0,
                                           WT2, g2, b2, X2, 512);
  k_conv3<<<dim3(64, 4), 512, 0, stream>>>(X2, 512, M1bf, M1, 2048,
                                           WT3, g3, b3, X3, 512);
  k_final<<<256, 256, 0, stream>>>(X3, dw, (float*)d_out);
}

// Round 9
// 972.009 us; speedup vs baseline: 7.1460x; 1.0194x over previous
//
#include <hip/hip_runtime.h>
#include <hip/hip_bf16.h>

typedef __hip_bfloat16 bf16;
using short8 = __attribute__((ext_vector_type(8))) short;
using f32x4  = __attribute__((ext_vector_type(4))) float;

__device__ __forceinline__ float b2f(bf16 v){ return __bfloat162float(v); }
__device__ __forceinline__ bf16  f2b(float v){ return __float2bfloat16(v); }

#define EPSV 1e-5f

// async global->LDS, 16B/lane, dest = wave-uniform base + lane*16
__device__ __forceinline__ void gload16(const void* g, void* l) {
  __builtin_amdgcn_global_load_lds(
      (const __attribute__((address_space(1))) unsigned int*)g,
      (__attribute__((address_space(3))) unsigned int*)l, 16, 0, 0);
}

// ===== fused f32 -> bf16 casts (qw,kw: 32768 f4; w2: 65536; c1: 32768) =====
__global__ __launch_bounds__(256) void k_cast4(
    const float* __restrict__ a, bf16* __restrict__ ao,
    const float* __restrict__ b, bf16* __restrict__ bo,
    const float* __restrict__ c, bf16* __restrict__ co,
    const float* __restrict__ d, bf16* __restrict__ dd) {
  int i = blockIdx.x * 256 + threadIdx.x;     // grid 640 -> 163840 exact
  const float* src; bf16* dst; int off;
  if (i < 32768)       { src = a; dst = ao; off = i; }
  else if (i < 65536)  { src = b; dst = bo; off = i - 32768; }
  else if (i < 131072) { src = c; dst = co; off = i - 65536; }
  else                 { src = d; dst = dd; off = i - 131072; }
  float4 v = ((const float4*)src)[off];
  union { ushort4 u; bf16 h[4]; } o;
  o.h[0] = f2b(v.x); o.h[1] = f2b(v.y); o.h[2] = f2b(v.z); o.h[3] = f2b(v.w);
  ((ushort4*)dst)[off] = o.u;
}

// ===== fused weight reshape for c2 (CI=512) and c3 (CI=2560) ==============
__global__ __launch_bounds__(256) void k_wtr2(
    const float* __restrict__ wa, bf16* __restrict__ wta,
    const float* __restrict__ wb, bf16* __restrict__ wtb) {
  int oc = blockIdx.x, yy = blockIdx.y;
  const float* w; bf16* wt; int CI, c0;
  if (yy < 4) { w = wa; wt = wta; CI = 512;  c0 = yy * 128; }
  else        { w = wb; wt = wtb; CI = 2560; c0 = (yy - 4) * 128; }
  __shared__ float ld[128 * 9];
  const float* src = w + ((size_t)oc * CI + c0) * 9;
  for (int i = threadIdx.x; i < 128 * 9; i += 256) ld[i] = src[i];
  __syncthreads();
  for (int i = threadIdx.x; i < 128 * 9; i += 256) {
    int k9 = i / 128, t = i - k9 * 128;
    wt[((size_t)k9 * 512 + oc) * CI + c0 + t] = f2b(ld[t * 9 + k9]);
  }
}

// ===== M1 NCHW f32 -> NHWC bf16 [4][64][64][2048] (fast path only) =========
__global__ __launch_bounds__(256) void k_m1t(const float* __restrict__ M1,
                                             bf16* __restrict__ M1b) {
  int b = blockIdx.x >> 6, y = blockIdx.x & 63;
  int c0 = blockIdx.y * 64;
  __shared__ float t[64][65];
  for (int i = threadIdx.x; i < 4096; i += 256) {
    int cc = i >> 6, x = i & 63;
    t[x][cc] = M1[((size_t)(b * 2048 + c0 + cc) * 64 + y) * 64 + x];
  }
  __syncthreads();
  for (int i = threadIdx.x; i < 4096; i += 256) {
    int x = i >> 6, cc = i & 63;
    M1b[((size_t)((b * 64 + y) * 64 + x)) * 2048 + c0 + cc] = f2b(t[x][cc]);
  }
}

// ===== F (NCHW f32) -> FP (b,p,n,c) bf16 via LDS transpose =================
__global__ __launch_bounds__(256) void k_fp2(const float* __restrict__ F,
                                             bf16* __restrict__ FP) {
  int b = blockIdx.x >> 6, y = blockIdx.x & 63;
  int tid = threadIdx.x;
  __shared__ float t[256][65];
  int p_hi = (y >> 3) << 3, n_hi = (y & 7) << 3;
  for (int half = 0; half < 2; half++) {
    int c0 = half << 8;
    for (int i = tid; i < 256 * 64; i += 256) {
      int cc = i >> 6, x = i & 63;
      t[cc][x] = F[((size_t)(b * 512 + c0 + cc) * 64 + y) * 64 + x];
    }
    __syncthreads();
    for (int x = 0; x < 64; x++) {
      int p = p_hi + (x >> 3), n = n_hi + (x & 7);
      FP[((size_t)(b * 64 + p)) * 32768 + n * 512 + c0 + tid] = f2b(t[tid][x]);
    }
    __syncthreads();
  }
}

// ===== softmax(I); FL0 = (bc*pix) @ FP  with FP slice in LDS ===============
__global__ __launch_bounds__(256) void k_flocal2(const float* __restrict__ I,
        const float* __restrict__ R, const bf16* __restrict__ FP,
        float* __restrict__ FL0) {
  int bp = blockIdx.x, b = bp >> 6, p = bp & 63;
  int tid = threadIdx.x, w = tid >> 6, lane = tid & 63;
  __shared__ __align__(16) bf16 fps[64 * 512];   // 64 KB
  __shared__ float pix[19][64];
  __shared__ float bc[19];
  {
    const bf16* src = FP + (size_t)bp * 32768 + lane * 8;
    #pragma unroll
    for (int t = 0; t < 16; t++) {
      int chunk = w + t * 4;
      gload16(src + chunk * 512, (char*)fps + chunk * 1024);
    }
  }
  int py = (p >> 3) * 8, px = (p & 7) * 8;
  for (int i = tid; i < 19 * 64; i += 256) {
    int k = i >> 6, n = i & 63;
    int y = py + (n >> 3), x = px + (n & 7);
    pix[k][n] = I[((size_t)(b * 19 + k) * 64 + y) * 64 + x];
  }
  if (tid < 19) bc[tid] = R[(size_t)(b * 19 + tid) * 64 + p];
  __syncthreads();
  if (tid < 19) {
    float mx = -1e30f;
    for (int n = 0; n < 64; n++) mx = fmaxf(mx, pix[tid][n]);
    float s = 0.f;
    for (int n = 0; n < 64; n++) { float e = __expf(pix[tid][n] - mx); pix[tid][n] = e; s += e; }
    float sc = bc[tid] / s;
    for (int n = 0; n < 64; n++) pix[tid][n] *= sc;
  }
  __syncthreads();
  for (int task = tid; task < 19 * 64; task += 256) {
    int k = task >> 6, c8 = (task & 63) << 3;
    float acc[8] = {};
    for (int n = 0; n < 64; n++) {
      float pv = pix[k][n];
      union { short8 s; bf16 h[8]; } v;
      v.s = *(const short8*)&fps[n * 512 + c8];
      #pragma unroll
      for (int j = 0; j < 8; j++) acc[j] += pv * b2f(v.h[j]);
    }
    float* dst = FL0 + ((size_t)(b * 64 + p) * 19 + k) * 512 + c8;
    #pragma unroll
    for (int j = 0; j < 8; j++) dst[j] = acc[j];
  }
}

// ===== LG part 1 (emits bf16 H) ============================================
__global__ __launch_bounds__(256) void k_lg1(const float* __restrict__ FL0,
        const float* __restrict__ w1, bf16* __restrict__ Hb) {
  int tid = threadIdx.x;
  int b = blockIdx.y;
  int n0 = blockIdx.x * 256;
  __shared__ float W[64][64];
  __shared__ float Xs[16][256];
  for (int i = tid; i < 4096; i += 256) W[i >> 6][i & 63] = w1[i];
  float acc[64];
  #pragma unroll
  for (int po = 0; po < 64; po++) acc[po] = 0.f;
  for (int q0 = 0; q0 < 64; q0 += 16) {
    __syncthreads();
    for (int i = tid; i < 4096; i += 256) {
      int q = i >> 8, j = i & 255;
      Xs[q][j] = FL0[(size_t)(b * 64 + q0 + q) * 9728 + n0 + j];
    }
    __syncthreads();
    for (int q = 0; q < 16; q++) {
      float xv = Xs[q][tid];
      #pragma unroll
      for (int po = 0; po < 64; po++) acc[po] += W[po][q0 + q] * xv;
    }
  }
  for (int po = 0; po < 64; po++) {
    float r = acc[po] + FL0[(size_t)(b * 64 + po) * 9728 + n0 + tid];
    Hb[(size_t)(b * 64 + po) * 9728 + n0 + tid] = f2b(fmaxf(r, 0.f));
  }
}

// ===== generic MFMA GEMM C[m][n] = sum_k A[m][k]*B[n][k] ===================
template<int MODE>
__global__ __launch_bounds__(256) void k_gmm(
    const bf16* __restrict__ A, const bf16* __restrict__ B,
    const float* __restrict__ bias, float* __restrict__ C,
    bf16* __restrict__ Cb, int N, int K,
    const float* __restrict__ g, const float* __restrict__ bb,
    const float* __restrict__ Fres, bf16* __restrict__ outb) {
  int tid = threadIdx.x;
  int m0 = blockIdx.x * 128, n0 = blockIdx.y * 128;
  int w = tid >> 6, lane = tid & 63, ln = lane & 15, qd = lane >> 4;
  int wm = w & 1, wn = w >> 1;
  __shared__ __align__(16) char smem[34816]; // staging 2x16KB | EP 128*136*2

  f32x4 acc[4][4];
  #pragma unroll
  for (int i = 0; i < 4; i++)
    #pragma unroll
    for (int j = 0; j < 4; j++) acc[i][j] = (f32x4){0.f, 0.f, 0.f, 0.f};

  int rsub = lane >> 2, ch = lane & 3;
  auto stage = [&](int p) {
    char* base = smem + (p & 1) * 16384;
    int k0 = p << 5;
    #pragma unroll
    for (int t = 0; t < 2; t++) {
      int ii = w + t * 4;
      int r = ii * 16 + rsub;
      int sw = (ch ^ ((r >> 1) & 3)) << 3;
      gload16(A + (size_t)(m0 + r) * K + k0 + sw, base + ii * 1024);
      gload16(B + (size_t)(n0 + r) * K + k0 + sw, base + 8192 + ii * 1024);
    }
  };
  auto compute = [&](int p) {
    const char* base = smem + (p & 1) * 16384;
    short8 af[4], bv[4];
    #pragma unroll
    for (int mi = 0; mi < 4; mi++) {
      int r = wm * 64 + mi * 16 + ln;
      af[mi] = *(const short8*)(base + r * 64 + ((qd ^ ((r >> 1) & 3)) << 4));
    }
    #pragma unroll
    for (int ni = 0; ni < 4; ni++) {
      int r = wn * 64 + ni * 16 + ln;
      bv[ni] = *(const short8*)(base + 8192 + r * 64 + ((qd ^ ((r >> 1) & 3)) << 4));
    }
    #pragma unroll
    for (int mi = 0; mi < 4; mi++)
      #pragma unroll
      for (int ni = 0; ni < 4; ni++)
        acc[mi][ni] = __builtin_amdgcn_mfma_f32_16x16x32_bf16(
            af[mi], bv[ni], acc[mi][ni], 0, 0, 0);
  };

  int KT = K >> 5;
  stage(0);
  __syncthreads();
  for (int p = 0; p < KT; p++) {
    if (p + 1 < KT) stage(p + 1);
    compute(p);
    __syncthreads();
  }

  if (MODE <= 1) {
    #pragma unroll
    for (int mi = 0; mi < 4; mi++) {
      #pragma unroll
      for (int r = 0; r < 4; r++) {
        int m = m0 + wm * 64 + mi * 16 + qd * 4 + r;
        #pragma unroll
        for (int ni = 0; ni < 4; ni++) {
          int n = n0 + wn * 64 + ni * 16 + ln;
          float v = acc[mi][ni][r];
          if (bias) v += bias[n];
          C[(size_t)m * N + n] = v;
          if (MODE == 1) Cb[(size_t)m * N + n] = f2b(v);
        }
      }
    }
  } else {
    bf16* EP = (bf16*)smem;  // [128 pix][136 oc-padded]
    int b = n0 >> 12;
    #pragma unroll
    for (int mi = 0; mi < 4; mi++) {
      #pragma unroll
      for (int r = 0; r < 4; r++) {
        int ml = wm * 64 + mi * 16 + qd * 4 + r;
        int oc = m0 + ml;
        float sc = g[oc] * rsqrtf(1.f + EPSV);
        float bt = bb[oc];
        #pragma unroll
        for (int ni = 0; ni < 4; ni++) {
          int nl = wn * 64 + ni * 16 + ln;
          int pix = n0 + nl;
          int y = (pix >> 6) & 63, x = pix & 63;
          float v = fmaxf(acc[mi][ni][r] * sc + bt, 0.f)
                  + Fres[((size_t)(b * 512 + oc) * 64 + y) * 64 + x];
          EP[nl * 136 + ml] = f2b(v);
        }
      }
    }
    __syncthreads();
    int pl = tid >> 1, half = tid & 1;
    size_t gb = (size_t)(n0 + pl) * 512 + m0 + half * 64;
    const bf16* row = &EP[pl * 136 + half * 64];
    #pragma unroll
    for (int j2 = 0; j2 < 8; j2++)
      *(short8*)(outb + gb + j2 * 8) = *(const short8*)(row + j2 * 8);
  }
}

// ===== fuse + value (float4 vw/fg) =========================================
__global__ __launch_bounds__(256) void k_fusev(const float* __restrict__ FL,
        const float* __restrict__ fw, const float* __restrict__ fbv,
        const float* __restrict__ vw, const float* __restrict__ vb,
        float* __restrict__ VAL) {
  int tid = threadIdx.x;
  int bk = blockIdx.x, b = bk / 19, k = bk % 19;
  __shared__ float fwl[64];
  __shared__ __align__(16) float fg[512];
  if (tid < 64) fwl[tid] = fw[tid];
  __syncthreads();
  float fbias = fbv[0];
  for (int c = tid; c < 512; c += 256) {
    float s = 0.f;
    for (int p = 0; p < 64; p++)
      s += fwl[p] * FL[((size_t)(b * 64 + p) * 19 + k) * 512 + c];
    fg[c] = s + fbias;
  }
  __syncthreads();
  int d = tid;
  float s = vb[d];
  const float4* vr = (const float4*)(vw + (size_t)d * 512);
  const float4* fr = (const float4*)fg;
  for (int c4 = 0; c4 < 128; c4++) {
    float4 wv = vr[c4], f = fr[c4];
    s += f.x * wv.x + f.y * wv.y + f.z * wv.z + f.w * wv.w;
  }
  VAL[(size_t)bk * 256 + d] = s;
}

// ===== per-patch attention -> FS NHWC bf16 (C=256), coalesced stores =======
__global__ __launch_bounds__(256) void k_attn(const float* __restrict__ Q,
        const float* __restrict__ KEY, const float* __restrict__ VAL,
        bf16* __restrict__ FS) {
  int tid = threadIdx.x;
  int bp = blockIdx.x, b = bp >> 6, p = bp & 63;
  __shared__ __align__(16) float ks[19][256];
  __shared__ __align__(16) float vs[19][256];
  __shared__ float Ss[64][20];
  __shared__ bf16 ot[64][256];
  for (int i = tid; i < 19 * 256; i += 256) {
    ks[i >> 8][i & 255] = KEY[(size_t)bp * 19 * 256 + i];
    vs[i >> 8][i & 255] = VAL[(size_t)b * 19 * 256 + i];
  }
  __syncthreads();
  {
    int n = tid >> 2, kq = tid & 3;
    const float4* qrow = (const float4*)(Q + ((size_t)bp * 64 + n) * 256);
    for (int k = kq; k < 19; k += 4) {
      const float4* kr = (const float4*)&ks[k][0];
      float s = 0.f;
      for (int d4 = 0; d4 < 64; d4++) {
        float4 qv = qrow[d4], kv = kr[d4];
        s += qv.x * kv.x + qv.y * kv.y + qv.z * kv.z + qv.w * kv.w;
      }
      Ss[n][k] = s;
    }
  }
  __syncthreads();
  if (tid < 64) {
    float mx = -1e30f;
    for (int k = 0; k < 19; k++) mx = fmaxf(mx, Ss[tid][k]);
    float sum = 0.f;
    for (int k = 0; k < 19; k++) { float e = __expf(Ss[tid][k] - mx); Ss[tid][k] = e; sum += e; }
    float inv = 1.f / sum;
    for (int k = 0; k < 19; k++) Ss[tid][k] *= inv;
  }
  __syncthreads();
  {
    int d = tid;
    for (int nn = 0; nn < 64; nn++) {
      float s = 0.f;
      #pragma unroll
      for (int k = 0; k < 19; k++) s += Ss[nn][k] * vs[k][d];
      ot[nn][d] = f2b(s);
    }
  }
  __syncthreads();
  {
    int py = (p >> 3) * 8, px = (p & 7) * 8;
    int nn = tid >> 2, q = tid & 3;
    int y = py + (nn >> 3), x = px + (nn & 7);
    size_t gb = (((size_t)(b * 64 + y) * 64) + x) * 256 + q * 64;
    const bf16* row = &ot[nn][q * 64];
    #pragma unroll
    for (int j = 0; j < 8; j++)
      *(short8*)(FS + gb + j * 8) = *(const short8*)(row + j * 8);
  }
}

// ===== MFMA conv3x3; 8 waves, A[3]-deep, SINGLE barrier/phase ==============
// Loop: barrier -> issue stageA(p+2) [+stageB at p%3==1] -> vmcnt(N) ->
// setprio(1) MFMA setprio(0).  No per-phase lgkm drain.
// WAR safety: barrier(p) implies all waves finished compute(p-1); writer at
// iter p touches A[(p+2)%3], live readers {p,p+1} -> disjoint mod 3.
// B[2] with >=2-barrier writer/reader spacing.  vmcnt N (FIFO, per wave):
// 3*[A(p+1)] + 3*[A(p+2)] + 3*[B pending] in {0,3,6,9} (exact, OOB->dump).
__global__ __launch_bounds__(512) void k_conv3(
    const bf16* __restrict__ Xin, int Cin,
    const bf16* __restrict__ M1b, const float* __restrict__ M1f, int C2,
    const bf16* __restrict__ WT,
    const float* __restrict__ g, const float* __restrict__ bb,
    bf16* __restrict__ out, int Cos) {
  int tid = threadIdx.x;
  int b = blockIdx.x >> 4, y0 = (blockIdx.x & 15) * 4;
  int oc0 = blockIdx.y * 128;
  int w = tid >> 6, lane = tid & 63, ln = lane & 15, qd = lane >> 4;
  int wocg = w & 1, wyp = w >> 1;      // wyp in 0..3 (y row)
  int Ct = Cin + C2;

  __shared__ __align__(16) char smem[125440];
  char* smA  = smem;                    // A[3][3][128][32] bf16 (3x24576)
  char* smB  = smem + 73728;            // B[2][6][66][32] bf16 (2x25344)
  char* dump = smem + 124416;           // 1KB dummy-load sink

  // zero halos in BOTH B buffers (stage never writes them)
  for (int bufi = 0; bufi < 2; bufi++) {
    char* bbuf = smB + bufi * 25344;
    for (int i = tid; i < 6 * 2 * 32; i += 512) {
      int rl = i >> 6, hh = (i >> 5) & 1, kk = i & 31;
      *(bf16*)(bbuf + (rl * 66 + (hh ? 65 : 0)) * 64 + kk * 2) = f2b(0.f);
    }
    if (y0 == 0)
      for (int i = tid; i < 66 * 16; i += 512) ((float*)bbuf)[i] = 0.f;
    if (y0 == 60)
      for (int i = tid; i < 66 * 16; i += 512)
        ((float*)(bbuf + 5 * 66 * 64))[i] = 0.f;
  }

  f32x4 acc[4][4];
  #pragma unroll
  for (int i = 0; i < 4; i++)
    #pragma unroll
    for (int j = 0; j < 4; j++) acc[i][j] = (f32x4){0.f, 0.f, 0.f, 0.f};

  int ngroups = Ct >> 5;
  int NPH = ngroups * 3;

  auto stageA = [&](int p) {   // exactly 3 gload16 per wave
    int c0 = (p / 3) << 5, ky = p % 3;
    char* base = smA + (p % 3 == p - (p / 3) * 3 ? 0 : 0) ;  // placeholder
    base = smA + (p % 3) * 0;  // (computed below properly)
    base = smA + ((p % 3) == 0 ? 0 : 0);
    // NOTE: buffer select is (p mod 3); ky is also p mod 3 by construction of
    // the phase ordering, so they coincide — use it directly.
    base = smA + ky * 0;
    base = smA + (p % 3) * 24576;
    #pragma unroll
    for (int t = 0; t < 3; t++) {
      int j = w + t * 8;                 // 0..23
      int kx = j >> 3, i8 = j & 7;
      int ocl = i8 * 16 + (lane >> 2);
      const bf16* src = WT + ((size_t)((ky * 3 + kx) * 512 + oc0 + ocl) * Ct + c0)
                      + (((lane & 3) ^ ((ocl >> 1) & 3)) << 3);
      gload16(src, base + (kx * 128 + i8 * 16) * 64);
    }
  };
  auto stageB = [&](int gi) {  // fast path: exactly 3 gload16 per wave
    int c0 = gi << 5;
    char* bbuf = smB + (gi & 1) * 25344;
    if (c0 < Cin || M1b != nullptr) {
      const bf16* T; int Cs, cb;
      if (c0 < Cin) { T = Xin; Cs = Cin; cb = c0; }
      else          { T = M1b; Cs = C2;  cb = c0 - Cin; }
      #pragma unroll
      for (int t = 0; t < 3; t++) {
        int j = w + t * 8;               // 0..23
        int rl = j >> 2, q = j & 3;
        int yy = y0 + rl - 1;
        bool ok = (unsigned)yy < 64u;
        int yc = ok ? yy : y0;
        int xx = q * 16 + (lane >> 2), xr = xx + 1;
        const bf16* src = T + ((size_t)((b * 64 + yc) * 64 + xx) * Cs + cb)
                        + (((lane & 3) ^ ((xr >> 1) & 3)) << 3);
        char* dst = ok ? (bbuf + (rl * 66 + 1 + q * 16) * 64) : dump;
        gload16(src, dst);
      }
    } else {
      // slow fallback: transpose M1 f32 NCHW in-register (ws too small);
      // ds_writes must drain before next barrier for cross-wave visibility.
      if (w < 6) {
        int rl = w, yy = y0 + rl - 1;
        if ((unsigned)yy < 64u) {
          int xx = lane, xr = xx + 1;
          const float* mp = M1f + ((size_t)(b * 2048 + (c0 - Cin)) * 64 + yy) * 64 + xx;
          #pragma unroll
          for (int q = 0; q < 8; q++) {
            union { ushort4 u; bf16 h[4]; } pk;
            #pragma unroll
            for (int jj = 0; jj < 4; jj++) pk.h[jj] = f2b(mp[(size_t)(q * 4 + jj) * 4096]);
            *(ushort4*)(bbuf + (rl * 66 + xr) * 64
                        + ((((q >> 1) ^ ((xr >> 1) & 3)) << 4) | ((q & 1) << 3))) = pk.u;
          }
        }
      }
      asm volatile("s_waitcnt lgkmcnt(0)" ::: "memory");
    }
  };
  auto computeP = [&](int p) {
    int ky = p % 3;
    const char* base = smA + (p % 3) * 24576;
    const char* bB   = smB + ((p / 3) & 1) * 25344;
    int rl = wyp + ky;                    // 0..5
    #pragma unroll
    for (int kx = 0; kx < 3; kx++) {
      short8 af[4], bv[4];
      #pragma unroll
      for (int mi = 0; mi < 4; mi++) {
        int ocl = wocg * 64 + mi * 16 + ln;
        af[mi] = *(const short8*)(base + (kx * 128 + ocl) * 64
                                  + ((qd ^ ((ocl >> 1) & 3)) << 4));
      }
      #pragma unroll
      for (int ni = 0; ni < 4; ni++) {
        int xr = ni * 16 + ln + kx;
        bv[ni] = *(const short8*)(bB + (rl * 66 + xr) * 64
                                  + ((qd ^ ((xr >> 1) & 3)) << 4));
      }
      #pragma unroll
      for (int mi = 0; mi < 4; mi++)
        #pragma unroll
        for (int ni = 0; ni < 4; ni++)
          acc[mi][ni] = __builtin_amdgcn_mfma_f32_16x16x32_bf16(
              af[mi], bv[ni], acc[mi][ni], 0, 0, 0);
    }
  };

  // prologue: B(0), A(0), A(1) in flight; drain halo-zero ds_writes
  stageB(0);
  stageA(0);
  stageA(1);
  asm volatile("s_waitcnt lgkmcnt(0)" ::: "memory");

  for (int p = 0; p < NPH; p++) {
    __builtin_amdgcn_s_barrier();
    __builtin_amdgcn_sched_barrier(0);
    if (p + 2 < NPH) stageA(p + 2);
    int pm3 = p % 3;
    int gn = p / 3 + 1;
    bool bValid = gn < ngroups;
    bool bFastN = bValid && (((gn << 5) < Cin) || (M1b != nullptr));
    if (pm3 == 1 && bValid) stageB(gn);
    __builtin_amdgcn_sched_barrier(0);
    int N = (p + 1 < NPH ? 3 : 0) + (p + 2 < NPH ? 3 : 0)
          + ((pm3 != 0 && bFastN) ? 3 : 0);
    if (N == 9)      asm volatile("s_waitcnt vmcnt(9)" ::: "memory");
    else if (N == 6) asm volatile("s_waitcnt vmcnt(6)" ::: "memory");
    else if (N == 3) asm volatile("s_waitcnt vmcnt(3)" ::: "memory");
    else             asm volatile("s_waitcnt vmcnt(0)" ::: "memory");
    __builtin_amdgcn_sched_barrier(0);
    __builtin_amdgcn_s_setprio(1);
    computeP(p);
    __builtin_amdgcn_s_setprio(0);
  }
  __syncthreads();

  // epilogue: BN+ReLU, LDS transpose -> coalesced NHWC stores
  {
    bf16* EP = (bf16*)smem;   // [4y][64x][128 ocl] = 64 KB
    #pragma unroll
    for (int mi = 0; mi < 4; mi++) {
      int oclb = wocg * 64 + mi * 16 + qd * 4;
      float sc[4], bt[4];
      #pragma unroll
      for (int r = 0; r < 4; r++) {
        int oc = oc0 + oclb + r;
        sc[r] = g[oc] * rsqrtf(1.f + EPSV);
        bt[r] = bb[oc];
      }
      #pragma unroll
      for (int ni = 0; ni < 4; ni++) {
        int x = ni * 16 + ln;
        union { ushort4 u; bf16 h[4]; } pk;
        #pragma unroll
        for (int r = 0; r < 4; r++)
          pk.h[r] = f2b(fmaxf(acc[mi][ni][r] * sc[r] + bt[r], 0.f));
        *(ushort4*)&EP[(wyp * 64 + x) * 128 + oclb] = pk.u;
      }
    }
    __syncthreads();
    int pixl = tid >> 1, hh = tid & 1;
    int yloc = pixl >> 6, x = pixl & 63;
    size_t gb = ((size_t)((b * 64 + y0 + yloc) * 64 + x)) * Cos + oc0 + hh * 64;
    const bf16* row = &EP[pixl * 128 + hh * 64];
    #pragma unroll
    for (int k = 0; k < 8; k++)
      *(short8*)(out + gb + k * 8) = *(const short8*)(row + k * 8);
  }
}

// ===== final 1x1 (512->19) from NHWC X3 ====================================
__global__ __launch_bounds__(256) void k_final(const bf16* __restrict__ X3,
        const float* __restrict__ dw, float* __restrict__ out) {
  int tid = threadIdx.x;
  int b = blockIdx.x >> 6, y = blockIdx.x & 63;
  __shared__ float W[19 * 512];
  for (int i = tid; i < 19 * 512; i += 256) W[i] = dw[i];
  __syncthreads();
  int x = tid & 63, kg = tid >> 6;
  const bf16* px = X3 + (((size_t)(b * 64 + y) * 64) + x) * 512;
  float acc[5] = {0.f, 0.f, 0.f, 0.f, 0.f};
  for (int c8 = 0; c8 < 512; c8 += 8) {
    union { short8 s; bf16 h[8]; } v;
    v.s = *(const short8*)(px + c8);
    float f[8];
    #pragma unroll
    for (int j = 0; j < 8; j++) f[j] = b2f(v.h[j]);
    #pragma unroll
    for (int i = 0; i < 5; i++) {
      int k = kg * 5 + i;
      if (k < 19) {
        const float* wr = &W[k * 512 + c8];
        #pragma unroll
        for (int j = 0; j < 8; j++) acc[i] += f[j] * wr[j];
      }
    }
  }
  for (int i = 0; i < 5; i++) {
    int k = kg * 5 + i;
    if (k < 19) out[((size_t)(b * 19 + k) * 64 + y) * 64 + x] = acc[i];
  }
}

extern "C" void kernel_launch(void* const* d_in, const int* in_sizes, int n_in,
                              void* d_out, int out_size, void* d_ws, size_t ws_size,
                              hipStream_t stream) {
  (void)in_sizes; (void)n_in; (void)out_size;
  const float* M1 = (const float*)d_in[0];
  const float* F  = (const float*)d_in[1];
  const float* Iin= (const float*)d_in[2];
  const float* R  = (const float*)d_in[3];
  const float* w1 = (const float*)d_in[4];
  const float* w2 = (const float*)d_in[5];
  const float* fw = (const float*)d_in[6];
  const float* fb = (const float*)d_in[7];
  const float* qw = (const float*)d_in[8];
  const float* qb = (const float*)d_in[9];
  const float* kw = (const float*)d_in[10];
  const float* kb = (const float*)d_in[11];
  const float* vw = (const float*)d_in[12];
  const float* vb = (const float*)d_in[13];
  const float* c1 = (const float*)d_in[14];
  const float* g1 = (const float*)d_in[15];
  const float* b1 = (const float*)d_in[16];
  const float* c2 = (const float*)d_in[17];
  const float* g2 = (const float*)d_in[18];
  const float* b2 = (const float*)d_in[19];
  const float* c3 = (const float*)d_in[20];
  const float* g3 = (const float*)d_in[21];
  const float* b3 = (const float*)d_in[22];
  const float* dw = (const float*)d_in[23];

  char* ws = (char*)d_ws;
  bool fast = ws_size >= (size_t)137363456ULL;

  bf16*  qwb  = (bf16*)(ws + 0);           //   262,144
  bf16*  kwb  = (bf16*)(ws + 262144);      //   262,144
  bf16*  w2b  = (bf16*)(ws + 524288);      //   524,288
  bf16*  c1b  = (bf16*)(ws + 1048576);     //   262,144
  bf16*  WT2  = (bf16*)(ws + 0);           //  4,718,592 (after conv1)
  bf16*  WT3  = (bf16*)(ws + 4718592);     // 23,592,960
  bf16*  FS   = (bf16*)(ws + 28311552);    //  8,388,608  NHWC (C=256)
  bf16*  FO1  = (bf16*)(ws + 36700160);    // 16,777,216  NHWC (C=512)
  bf16*  X2   = (bf16*)(ws + 53477376);    // 16,777,216  NHWC (C=512)
  bf16*  M1bf = fast ? (bf16*)(ws + 70254592) : nullptr;  // 67,108,864 NHWC
  bf16*  X3   = (bf16*)(ws + 28311552);    // overlay FS+FO1 (dead by then)
  bf16*  FP    = (bf16*) (ws + 53477376);  // X2 region
  float* QUERY = (float*)(ws + 70254592);  // 16,777,216
  float* FL0   = (float*)(ws + 87031808);  //  9,961,472
  bf16*  Hb    = (bf16*) (ws + 96993280);  //  4,980,736
  bf16*  FLb   = (bf16*) (ws + 101974016); //  4,980,736
  float* KEY   = (float*)(ws + 106954752); //  4,980,736
  float* VAL   = (float*)(ws + 111935488); //     77,824
  float* FL    = FL0;

  k_cast4<<<640, 256, 0, stream>>>(qw, qwb, kw, kwb, w2, w2b, c1, c1b);
  k_fp2<<<256, 256, 0, stream>>>(F, FP);
  k_flocal2<<<256, 256, 0, stream>>>(Iin, R, FP, FL0);
  k_lg1<<<dim3(38, 4), 256, 0, stream>>>(FL0, w1, Hb);
  k_gmm<1><<<dim3(38, 4), 256, 0, stream>>>(Hb, w2b, nullptr, FL, FLb, 512, 512,
                                            nullptr, nullptr, nullptr, nullptr);
  k_fusev<<<76, 256, 0, stream>>>(FL, fw, fb, vw, vb, VAL);
  k_gmm<0><<<dim3(38, 2), 256, 0, stream>>>(FLb, kwb, kb, KEY, nullptr, 256, 512,
                                            nullptr, nullptr, nullptr, nullptr);
  k_gmm<0><<<dim3(128, 2), 256, 0, stream>>>(FP, qwb, qb, QUERY, nullptr, 256, 512,
                                             nullptr, nullptr, nullptr, nullptr);
  k_attn<<<256, 256, 0, stream>>>(QUERY, KEY, VAL, FS);
  if (fast) k_m1t<<<dim3(256, 32), 256, 0, stream>>>(M1, M1bf);
  k_gmm<2><<<dim3(4, 128), 256, 0, stream>>>(c1b, FS, nullptr, nullptr, nullptr,
                                             16384, 256, g1, b1, F, FO1);
  k_wtr2<<<dim3(512, 24), 256, 0, stream>>>(c2, WT2, c3, WT3);
  k_conv3<<<dim3(64, 4), 512, 0, stream>>>(FO1, 512, nullptr, nullptr, 0,
                                           WT2, g2, b2, X2, 512);
  k_conv3<<<dim3(64, 4), 512, 0, stream>>>(X2, 512, M1bf, M1, 2048,
                                           WT3, g3, b3, X3, 512);
  k_final<<<256, 256, 0, stream>>>(X3, dw, (float*)d_out);
}